// Round 3
// baseline (9124.094 us; speedup 1.0000x reference)
//
#include <hip/hip_runtime.h>
#include <math.h>

// Problem dims
#define NB    32
#define NC    3
#define NIMG  (NB*NC)      // 96 image-channels
#define NS    384
#define HWSZ  (NS*NS)      // 147456
#define C1OUT 64
#define C1DIM 192
#define PDIM  96
#define PHW   (PDIM*PDIM)  // 9216
#define C2OUT 128
#define KWH   193          // stored half-spectrum width (kw = 0..192)
#define PI_F  3.14159265358979323846f

// ---- workspace layout (bytes) ----
// T: float2[384][384] twiddle table        =  1,179,648
// B: float [96][384][384] shifted log-mag  = 56,623,104   (natural [c][h'][w'])
// S: scratch, reused:                      = 18,874,368
//      A chunk: float2[24][384][193] = 14,229,504
//      D chunk: float [8][64][96][96] = 18,874,368
// smalls: rgbsum[96] stats[192] freqacc[4096] rgbmean[96] ss[192]
// peak = 76,695,808 bytes (~73 MB)
static const size_t OFF_T     = 0;
static const size_t OFF_B     = 1179648;
static const size_t OFF_S     = 57802752;
static const size_t OFF_SMALL = 76677120;

__device__ __forceinline__ float wave_sum(float v){
  #pragma unroll
  for (int off = 32; off; off >>= 1) v += __shfl_down(v, off);
  return v;
}

// proper mod-384 for v in [0, 768): NOT "& 383" — 384 is not a power of two,
// 383 lacks bit 7, so &383 clears bit 7 (that was the round-1/2 bug).
__device__ __forceinline__ int mod384(int v){ return v >= NS ? v - NS : v; }

// Twiddle table: T[k][n] = exp(-2*pi*i*(k*n mod 384)/384). Exact int reduction.
__global__ void k_twiddle(float2* __restrict__ T){
  int idx = blockIdx.x*256 + (int)threadIdx.x;
  if (idx >= NS*NS) return;
  int k = idx / NS, n = idx - k*NS;
  int m = (k*n) % NS;
  float ang = -2.0f*PI_F*(float)m/(float)NS;
  T[idx] = make_float2(cosf(ang), sinf(ang));
}

// Row DFT (along W, real input): A[bc][h][kw] = sum_w x[bc][h][w]*T[w][kw],
// kw in [0,192] stored (conjugate symmetry). 4 rows per block. Also rgb sums.
__global__ __launch_bounds__(192) void k_dft_rows(const float* __restrict__ x,
    const float2* __restrict__ T, float2* __restrict__ A,
    float* __restrict__ rgbsum, int bc0){
  __shared__ float xr[4*NS];
  __shared__ float rs[3];
  int blk = blockIdx.x;
  int bcl = blk / 96, rg = blk % 96;       // local channel, row group
  int bc = bc0 + bcl;                      // global channel
  int t = threadIdx.x;
  const float* xp = x + (size_t)bc*HWSZ + (size_t)rg*4*NS;
  float lsum = 0.f;
  #pragma unroll
  for (int i = 0; i < 8; ++i){
    int lin = i*192 + t;
    float v = xp[lin];
    xr[lin] = v;
    lsum += v;
  }
  float ws = wave_sum(lsum);
  if ((t & 63) == 0) rs[t >> 6] = ws;
  __syncthreads();
  if (t == 0) atomicAdd(&rgbsum[bc], rs[0] + rs[1] + rs[2]);

  float2 acc0[4], acc1[4];
  #pragma unroll
  for (int r = 0; r < 4; ++r){ acc0[r] = make_float2(0.f,0.f); acc1[r] = make_float2(0.f,0.f); }
  for (int n = 0; n < NS; ++n){
    float2 t0 = T[n*NS + t];
    float2 t1 = T[n*NS + t + 192];
    #pragma unroll
    for (int r = 0; r < 4; ++r){
      float xv = xr[r*NS + n];
      acc0[r].x = fmaf(xv, t0.x, acc0[r].x);
      acc0[r].y = fmaf(xv, t0.y, acc0[r].y);
      acc1[r].x = fmaf(xv, t1.x, acc1[r].x);
      acc1[r].y = fmaf(xv, t1.y, acc1[r].y);
    }
  }
  #pragma unroll
  for (int r = 0; r < 4; ++r){
    size_t base = ((size_t)bcl*NS + rg*4 + r)*KWH;
    A[base + t] = acc0[r];                 // kw = t in [0,192)
    if (t == 0) A[base + 192] = acc1[r];   // kw = 192 (Nyquist)
  }
}

// Column DFT (along H) for kw in [0,192], then |.|, log1p, fftshift, mirror
// to kw in (192,384) via conjugate symmetry. Natural write B[c][h'][w'].
__global__ __launch_bounds__(192) void k_dft_cols(const float2* __restrict__ A,
    const float2* __restrict__ T, float* __restrict__ Bm,
    float* __restrict__ stats, int bc0){
  __shared__ float2 tile[NS][5];           // 4 cols + pad
  __shared__ float rs[6];
  int blk = blockIdx.x;
  int bcl = blk / 49, cg = blk % 49;
  int bc = bc0 + bcl;
  int kw0 = cg*4;
  int cols = (cg == 48) ? 1 : 4;
  int t = threadIdx.x;
  const float2* Al = A + (size_t)bcl*NS*KWH;
  if (cols == 4){
    for (int lin = t; lin < NS*4; lin += 192){
      int h = lin >> 2, c = lin & 3;
      tile[h][c] = Al[(size_t)h*KWH + kw0 + c];
    }
  } else {
    for (int lin = t; lin < NS; lin += 192)
      tile[lin][0] = Al[(size_t)lin*KWH + kw0];
  }
  __syncthreads();
  float2 acc[4][2];
  #pragma unroll
  for (int c = 0; c < 4; ++c){ acc[c][0] = make_float2(0.f,0.f); acc[c][1] = make_float2(0.f,0.f); }
  for (int h = 0; h < NS; ++h){
    float2 t0 = T[h*NS + t];
    float2 t1 = T[h*NS + t + 192];
    #pragma unroll
    for (int c = 0; c < 4; ++c){
      if (c < cols){
        float2 a = tile[h][c];
        acc[c][0].x = fmaf(a.x, t0.x, fmaf(-a.y, t0.y, acc[c][0].x));
        acc[c][0].y = fmaf(a.x, t0.y, fmaf( a.y, t0.x, acc[c][0].y));
        acc[c][1].x = fmaf(a.x, t1.x, fmaf(-a.y, t1.y, acc[c][1].x));
        acc[c][1].y = fmaf(a.x, t1.y, fmaf( a.y, t1.x, acc[c][1].y));
      }
    }
  }
  float s1 = 0.f, s2 = 0.f;
  float* Bbc = Bm + (size_t)bc*HWSZ;
  #pragma unroll
  for (int c = 0; c < 4; ++c){
    if (c < cols){
      int kw = kw0 + c;
      #pragma unroll
      for (int kk = 0; kk < 2; ++kk){
        int kh = t + kk*192;
        float2 X = acc[c][kk];
        float mag = logf(sqrtf(X.x*X.x + X.y*X.y) + 1.f);
        int u = mod384(kh + 192);          // shifted H index
        int v = mod384(kw + 192);          // shifted W index
        Bbc[(size_t)u*NS + v] = mag;
        s1 += mag; s2 += mag*mag;
        if (kw >= 1 && kw <= 191){         // conj mirror -> kw2 in [193,383]
          int kh2 = mod384(NS - kh);
          int u2 = mod384(kh2 + 192);
          int v2 = mod384(NS - kw + 192);  // = 192 - kw
          Bbc[(size_t)u2*NS + v2] = mag;
          s1 += mag; s2 += mag*mag;
        }
      }
    }
  }
  float w1s = wave_sum(s1), w2s = wave_sum(s2);
  if ((t & 63) == 0){ rs[t >> 6] = w1s; rs[3 + (t >> 6)] = w2s; }
  __syncthreads();
  if (t == 0){
    atomicAdd(&stats[bc*2],     rs[0] + rs[1] + rs[2]);
    atomicAdd(&stats[bc*2 + 1], rs[3] + rs[4] + rs[5]);
  }
}

__global__ void k_finalize(const float* __restrict__ stats, const float* __restrict__ rgbsum,
                           float* __restrict__ ss, float* __restrict__ rgbmean){
  int t = threadIdx.x;
  if (t < NIMG){
    const float inv_n = 1.f / 147456.f;
    float mean = stats[t*2] * inv_n;
    float var  = fmaxf(stats[t*2 + 1] * inv_n - mean*mean, 0.f);
    float inv  = 1.f / (sqrtf(var) + 1e-8f);
    ss[t*2]     = inv;          // normalized = mag*inv + (-mean*inv)
    ss[t*2 + 1] = -mean * inv;
    rgbmean[t]  = rgbsum[t] * inv_n;
  }
}

// conv1(7x7,s2,p3)+BN+ReLU fused with maxpool(3,s2,p1). Natural layout:
// input B[c][h][w], output D[b][oc][oh][ow]. Thread minor index = ow (coalesced).
__global__ __launch_bounds__(256) void k_conv1pool(const float* __restrict__ Bm,
    const float* __restrict__ ss, const float* __restrict__ w1, const float* __restrict__ b1,
    const float* __restrict__ g1, const float* __restrict__ bb1, float* __restrict__ D,
    int b0){
  int blk = blockIdx.x;
  int bl = blk / 36, tile = blk % 36;      // local b, output tile
  int b = b0 + bl;
  int pos = tile*256 + (int)threadIdx.x;
  int oh = pos / PDIM, ow = pos - oh*PDIM;
  float sc[3], sh[3];
  #pragma unroll
  for (int ic = 0; ic < 3; ++ic){ sc[ic] = ss[(b*3 + ic)*2]; sh[ic] = ss[(b*3 + ic)*2 + 1]; }
  const float bneps = rsqrtf(1.f + 1e-5f);
  const float* Bb = Bm + (size_t)b*3*HWSZ;
  #pragma unroll 1
  for (int g = 0; g < 4; ++g){             // 16 out-channels per group
    float acc[16];
    #pragma unroll
    for (int o = 0; o < 16; ++o) acc[o] = -1e30f;
    #pragma unroll 1
    for (int e = 0; e < 9; ++e){           // 3x3 maxpool window
      int ph = 2*oh - 1 + e/3;             // conv output coords
      int pw = 2*ow - 1 + e%3;
      if ((unsigned)ph >= (unsigned)C1DIM || (unsigned)pw >= (unsigned)C1DIM) continue;
      int hb = 2*ph - 3, wb = 2*pw - 3;    // conv input window base
      float win[147];
      #pragma unroll
      for (int ic = 0; ic < 3; ++ic){
        #pragma unroll
        for (int kh = 0; kh < 7; ++kh){
          int h = hb + kh;
          bool vh = (unsigned)h < (unsigned)NS;
          #pragma unroll
          for (int kw = 0; kw < 7; ++kw){
            int w = wb + kw;
            bool v = vh && ((unsigned)w < (unsigned)NS);
            float raw = v ? Bb[(size_t)ic*HWSZ + (size_t)h*NS + w] : 0.f;
            win[(ic*7 + kh)*7 + kw] = v ? fmaf(raw, sc[ic], sh[ic]) : 0.f;
          }
        }
      }
      #pragma unroll
      for (int o = 0; o < 16; ++o){
        int oc = g*16 + o;
        const float* wp = w1 + oc*147;     // wave-uniform -> s_load
        float s = b1[oc];
        #pragma unroll
        for (int tt = 0; tt < 147; ++tt) s = fmaf(wp[tt], win[tt], s);
        float val = fmaxf(fmaf(s, g1[oc]*bneps, bb1[oc]), 0.f);
        acc[o] = fmaxf(acc[o], val);
      }
    }
    #pragma unroll
    for (int o = 0; o < 16; ++o){
      int oc = g*16 + o;
      D[(((size_t)bl*C1OUT + oc)*PDIM + oh)*PDIM + ow] = acc[o];
    }
  }
}

// conv2(3x3,p1)+BN+ReLU fused with global-average-pool -> freq_acc[b][128]
__global__ __launch_bounds__(256) void k_conv2pool(const float* __restrict__ D,
    const float* __restrict__ w2, const float* __restrict__ b2,
    const float* __restrict__ g2, const float* __restrict__ bb2,
    float* __restrict__ freq_acc, int b0){
  __shared__ float red[32*256];
  __shared__ float red2[256];
  int blk = blockIdx.x;
  int bl = blk / 36, tile = blk % 36;
  int b = b0 + bl;
  int t = threadIdx.x;
  int pos = tile*256 + t;
  int oh = pos / PDIM, ow = pos - oh*PDIM;
  const float bneps = rsqrtf(1.f + 1e-5f);
  const float* Db = D + (size_t)bl*C1OUT*PHW;
  #pragma unroll 1
  for (int g = 0; g < 4; ++g){             // 32 out-channels per group
    float acc[32];
    #pragma unroll
    for (int o = 0; o < 32; ++o) acc[o] = 0.f;
    #pragma unroll 1
    for (int icc = 0; icc < 8; ++icc){     // 8 input channels per chunk
      float win[72];
      #pragma unroll
      for (int i = 0; i < 8; ++i){
        int ic = icc*8 + i;
        const float* Dp = Db + (size_t)ic*PHW;
        #pragma unroll
        for (int kh = 0; kh < 3; ++kh){
          int h = oh - 1 + kh;
          bool vh = (unsigned)h < (unsigned)PDIM;
          #pragma unroll
          for (int kw = 0; kw < 3; ++kw){
            int w = ow - 1 + kw;
            bool v = vh && ((unsigned)w < (unsigned)PDIM);
            win[(i*3 + kh)*3 + kw] = v ? Dp[(size_t)h*PDIM + w] : 0.f;
          }
        }
      }
      #pragma unroll
      for (int o = 0; o < 32; ++o){
        int oc = g*32 + o;
        const float* wp = w2 + (size_t)oc*576 + icc*72;   // uniform -> s_load
        float s = acc[o];
        #pragma unroll
        for (int jj = 0; jj < 72; ++jj) s = fmaf(wp[jj], win[jj], s);
        acc[o] = s;
      }
    }
    #pragma unroll
    for (int o = 0; o < 32; ++o){
      float val = fmaxf(fmaf(acc[o] + b2[g*32 + o], g2[g*32 + o]*bneps, bb2[g*32 + o]), 0.f);
      red[o*256 + t] = val;
    }
    __syncthreads();
    { int oc = t >> 3, l = t & 7;
      float s = 0.f;
      #pragma unroll
      for (int i = 0; i < 32; ++i) s += red[oc*256 + l + 8*i];
      red2[t] = s; }
    __syncthreads();
    if (t < 32){
      float s = 0.f;
      #pragma unroll
      for (int l = 0; l < 8; ++l) s += red2[t*8 + l];
      atomicAdd(&freq_acc[b*C2OUT + g*32 + t], s);
    }
    __syncthreads();
  }
}

// RGB head + concat + 3-layer MLP, one block per batch sample.
__global__ __launch_bounds__(256) void k_mlp(const float* __restrict__ rgbmean,
    const float* __restrict__ freq_acc, const float* __restrict__ w_rgb,
    const float* __restrict__ b_rgb, const float* __restrict__ fc1w,
    const float* __restrict__ fc1b, const float* __restrict__ fc2w,
    const float* __restrict__ fc2b, const float* __restrict__ fc3w,
    const float* __restrict__ fc3b, float* __restrict__ out){
  __shared__ float z[130], z1[256], z2[128];
  int b = blockIdx.x, t = threadIdx.x;
  if (t < 2){
    float s = b_rgb[t];
    #pragma unroll
    for (int c = 0; c < 3; ++c) s += rgbmean[b*3 + c] * w_rgb[c*2 + t];
    z[t] = s;
  }
  if (t < 128) z[2 + t] = freq_acc[b*C2OUT + t] * (1.f/9216.f);
  __syncthreads();
  { float s = fc1b[t];
    for (int k = 0; k < 130; ++k) s = fmaf(z[k], fc1w[k*256 + t], s);
    z1[t] = fmaxf(s, 0.f); }
  __syncthreads();
  if (t < 128){
    float s = fc2b[t];
    for (int k = 0; k < 256; ++k) s = fmaf(z1[k], fc2w[k*128 + t], s);
    z2[t] = fmaxf(s, 0.f); }
  __syncthreads();
  if (t < 2){
    float s = fc3b[t];
    for (int k = 0; k < 128; ++k) s = fmaf(z2[k], fc3w[k*2 + t], s);
    out[b*2 + t] = s; }
}

extern "C" void kernel_launch(void* const* d_in, const int* in_sizes, int n_in,
                              void* d_out, int out_size, void* d_ws, size_t ws_size,
                              hipStream_t stream){
  const float* x     = (const float*)d_in[0];
  const float* w_rgb = (const float*)d_in[1];
  const float* b_rgb = (const float*)d_in[2];
  const float* w1    = (const float*)d_in[3];
  const float* b1    = (const float*)d_in[4];
  const float* g1    = (const float*)d_in[5];
  const float* bb1   = (const float*)d_in[6];
  const float* w2    = (const float*)d_in[7];
  const float* b2    = (const float*)d_in[8];
  const float* g2    = (const float*)d_in[9];
  const float* bb2   = (const float*)d_in[10];
  const float* fc1w  = (const float*)d_in[11];
  const float* fc1b  = (const float*)d_in[12];
  const float* fc2w  = (const float*)d_in[13];
  const float* fc2b  = (const float*)d_in[14];
  const float* fc3w  = (const float*)d_in[15];
  const float* fc3b  = (const float*)d_in[16];

  char* ws = (char*)d_ws;
  float2* T  = (float2*)(ws + OFF_T);
  float*  Bm = (float*)(ws + OFF_B);
  float2* A  = (float2*)(ws + OFF_S);      // scratch: A chunk / D chunk (time-shared)
  float*  D  = (float*)(ws + OFF_S);
  float*  sm = (float*)(ws + OFF_SMALL);
  float* rgbsum = sm;            // 96
  float* stats  = sm + 96;       // 192
  float* freqa  = sm + 288;      // 4096
  float* rgbm   = sm + 4384;     // 96
  float* ssb    = sm + 4480;     // 192

  hipMemsetAsync(sm, 0, 4672*sizeof(float), stream);
  k_twiddle<<<(NS*NS + 255)/256, 256, 0, stream>>>(T);
  for (int c = 0; c < 4; ++c){             // 24 channels per chunk
    k_dft_rows<<<24*96, 192, 0, stream>>>(x, T, A, rgbsum, c*24);
    k_dft_cols<<<24*49, 192, 0, stream>>>(A, T, Bm, stats, c*24);
  }
  k_finalize<<<1, 128, 0, stream>>>(stats, rgbsum, ssb, rgbm);
  for (int c = 0; c < 4; ++c){             // 8 images per chunk
    k_conv1pool<<<8*36, 256, 0, stream>>>(Bm, ssb, w1, b1, g1, bb1, D, c*8);
    k_conv2pool<<<8*36, 256, 0, stream>>>(D, w2, b2, g2, bb2, freqa, c*8);
  }
  k_mlp<<<NB, 256, 0, stream>>>(rgbm, freqa, w_rgb, b_rgb, fc1w, fc1b,
                                fc2w, fc2b, fc3w, fc3b, (float*)d_out);
}

// Round 4
// 4131.465 us; speedup vs baseline: 2.2084x; 2.2084x over previous
//
#include <hip/hip_runtime.h>
#include <math.h>

// Problem dims
#define NB    32
#define NC    3
#define NIMG  (NB*NC)      // 96 image-channels
#define NS    384
#define HWSZ  (NS*NS)      // 147456
#define C1OUT 64
#define C1DIM 192
#define PDIM  96
#define PHW   (PDIM*PDIM)  // 9216
#define C2OUT 128
#define KWH   193          // stored half-spectrum width (kw = 0..192)
#define PI_F  3.14159265358979323846f

// ---- workspace layout (bytes) ----
// T: float2[384][384] twiddle table        =  1,179,648  @ 0
// B: float [96][384][384] shifted log-mag  = 56,623,104  @ OFF_B
// S: scratch (time-shared):                              @ OFF_S
//    full   : A float2[96][384][193] = 56,918,016  then D float[32][64][96][96] = 75,497,472
//    chunked: A float2[24][384][193] = 14,229,504  then D float[8][64][96][96]  = 18,874,368
// smalls: rgbsum[96] stats[192] freqacc[4096] rgbmean[96] ss[192] = 18,688 B
// peak: full = 133,318,912  /  chunked = 76,695,808 (round-3 verified)
static const size_t OFF_T    = 0;
static const size_t OFF_B    = 1179648;
static const size_t OFF_S    = 57802752;
static const size_t OFF_SM_F = 133300224;
static const size_t OFF_SM_C = 76677120;
static const size_t NEED_F   = 133318912;

__device__ __forceinline__ float wave_sum(float v){
  #pragma unroll
  for (int off = 32; off; off >>= 1) v += __shfl_down(v, off);
  return v;
}

// proper mod-384 for v in [0, 768): NOT "& 383" (384 not a power of two).
__device__ __forceinline__ int mod384(int v){ return v >= NS ? v - NS : v; }

// Twiddle table: T[k][n] = exp(-2*pi*i*(k*n mod 384)/384). Exact int reduction.
__global__ void k_twiddle(float2* __restrict__ T){
  int idx = blockIdx.x*256 + (int)threadIdx.x;
  if (idx >= NS*NS) return;
  int k = idx / NS, n = idx - k*NS;
  int m = (k*n) % NS;
  float ang = -2.0f*PI_F*(float)m/(float)NS;
  T[idx] = make_float2(cosf(ang), sinf(ang));
}

// Row DFT (along W, real input): A[bc][h][kw] = sum_w x[bc][h][w]*T[w][kw],
// kw in [0,192] stored (conjugate symmetry). 8 rows per block; Nyquist (kw=192)
// via alternating sum (twiddle = (-1)^n, real). Also rgb pixel sums.
__global__ __launch_bounds__(192) void k_dft_rows(const float* __restrict__ x,
    const float2* __restrict__ T, float2* __restrict__ A,
    float* __restrict__ rgbsum, int bc0){
  __shared__ float xr[8*NS];
  __shared__ float rs[3];
  int blk = blockIdx.x;
  int bcl = blk / 48, rg = blk % 48;       // local channel, 8-row group
  int bc = bc0 + bcl;
  int t = threadIdx.x;
  const float* xp = x + (size_t)bc*HWSZ + (size_t)rg*8*NS;
  float lsum = 0.f;
  #pragma unroll
  for (int i = 0; i < 16; ++i){
    int lin = i*192 + t;
    float v = xp[lin];
    xr[lin] = v;
    lsum += v;
  }
  float ws = wave_sum(lsum);
  if ((t & 63) == 0) rs[t >> 6] = ws;
  __syncthreads();
  if (t == 0) atomicAdd(&rgbsum[bc], rs[0] + rs[1] + rs[2]);

  float2 acc[8];
  float ny[8];
  #pragma unroll
  for (int r = 0; r < 8; ++r){ acc[r] = make_float2(0.f,0.f); ny[r] = 0.f; }
  for (int n = 0; n < NS; ++n){
    float2 tw = T[n*NS + t];
    float sg = (n & 1) ? -1.f : 1.f;
    #pragma unroll
    for (int r = 0; r < 8; ++r){
      float xv = xr[r*NS + n];
      acc[r].x = fmaf(xv, tw.x, acc[r].x);
      acc[r].y = fmaf(xv, tw.y, acc[r].y);
      ny[r]    = fmaf(xv, sg,   ny[r]);
    }
  }
  #pragma unroll
  for (int r = 0; r < 8; ++r){
    size_t base = ((size_t)bcl*NS + rg*8 + r)*KWH;
    A[base + t] = acc[r];                  // kw = t in [0,192)
    if (t == 0) A[base + 192] = make_float2(ny[r], 0.f);
  }
}

// Column DFT (along H) for kw in [0,192] (8 cols/block), then |.|, log1p,
// fftshift, mirror to kw in (192,384) via conjugate symmetry.
__global__ __launch_bounds__(192) void k_dft_cols(const float2* __restrict__ A,
    const float2* __restrict__ T, float* __restrict__ Bm,
    float* __restrict__ stats, int bc0){
  __shared__ float2 tile[NS][9];           // 8 cols + pad
  __shared__ float rs[6];
  int blk = blockIdx.x;
  int bcl = blk / 25, cg = blk % 25;
  int bc = bc0 + bcl;
  int kw0 = cg*8;
  int cols = (cg == 24) ? 1 : 8;           // 193 = 24*8 + 1
  int t = threadIdx.x;
  const float2* Al = A + (size_t)bcl*NS*KWH;
  if (cols == 8){
    #pragma unroll
    for (int i = 0; i < 16; ++i){
      int lin = i*192 + t;
      int h = lin >> 3, c = lin & 7;
      tile[h][c] = Al[(size_t)h*KWH + kw0 + c];
    }
  } else {
    for (int lin = t; lin < NS; lin += 192)
      tile[lin][0] = Al[(size_t)lin*KWH + kw0];
  }
  __syncthreads();
  float2 acc[8][2];
  #pragma unroll
  for (int c = 0; c < 8; ++c){ acc[c][0] = make_float2(0.f,0.f); acc[c][1] = make_float2(0.f,0.f); }
  for (int h = 0; h < NS; ++h){
    float2 t0 = T[h*NS + t];
    float2 t1 = T[h*NS + t + 192];
    #pragma unroll
    for (int c = 0; c < 8; ++c){
      if (c < cols){
        float2 a = tile[h][c];
        acc[c][0].x = fmaf(a.x, t0.x, fmaf(-a.y, t0.y, acc[c][0].x));
        acc[c][0].y = fmaf(a.x, t0.y, fmaf( a.y, t0.x, acc[c][0].y));
        acc[c][1].x = fmaf(a.x, t1.x, fmaf(-a.y, t1.y, acc[c][1].x));
        acc[c][1].y = fmaf(a.x, t1.y, fmaf( a.y, t1.x, acc[c][1].y));
      }
    }
  }
  float s1 = 0.f, s2 = 0.f;
  float* Bbc = Bm + (size_t)bc*HWSZ;
  #pragma unroll
  for (int c = 0; c < 8; ++c){
    if (c < cols){
      int kw = kw0 + c;
      #pragma unroll
      for (int kk = 0; kk < 2; ++kk){
        int kh = t + kk*192;
        float2 X = acc[c][kk];
        float mag = logf(sqrtf(X.x*X.x + X.y*X.y) + 1.f);
        int u = mod384(kh + 192);          // shifted H index
        int v = mod384(kw + 192);          // shifted W index
        Bbc[(size_t)u*NS + v] = mag;
        s1 += mag; s2 += mag*mag;
        if (kw >= 1 && kw <= 191){         // conj mirror -> kw2 in [193,383]
          int kh2 = mod384(NS - kh);
          int u2 = mod384(kh2 + 192);
          int v2 = mod384(NS - kw + 192);  // = 192 - kw
          Bbc[(size_t)u2*NS + v2] = mag;
          s1 += mag; s2 += mag*mag;
        }
      }
    }
  }
  float w1s = wave_sum(s1), w2s = wave_sum(s2);
  if ((t & 63) == 0){ rs[t >> 6] = w1s; rs[3 + (t >> 6)] = w2s; }
  __syncthreads();
  if (t == 0){
    atomicAdd(&stats[bc*2],     rs[0] + rs[1] + rs[2]);
    atomicAdd(&stats[bc*2 + 1], rs[3] + rs[4] + rs[5]);
  }
}

__global__ void k_finalize(const float* __restrict__ stats, const float* __restrict__ rgbsum,
                           float* __restrict__ ss, float* __restrict__ rgbmean){
  int t = threadIdx.x;
  if (t < NIMG){
    const float inv_n = 1.f / 147456.f;
    float mean = stats[t*2] * inv_n;
    float var  = fmaxf(stats[t*2 + 1] * inv_n - mean*mean, 0.f);
    float inv  = 1.f / (sqrtf(var) + 1e-8f);
    ss[t*2]     = inv;          // normalized = mag*inv + (-mean*inv)
    ss[t*2 + 1] = -mean * inv;
    rgbmean[t]  = rgbsum[t] * inv_n;
  }
}

// conv1(7x7,s2,p3)+BN+ReLU fused with maxpool(3,s2,p1). oc-group (16) in GRID
// (4x more blocks -> latency hiding); per-ic win[49] keeps VGPR low.
__global__ __launch_bounds__(256) void k_conv1pool(const float* __restrict__ Bm,
    const float* __restrict__ ss, const float* __restrict__ w1, const float* __restrict__ b1,
    const float* __restrict__ g1, const float* __restrict__ bb1, float* __restrict__ D,
    int b0){
  int blk = blockIdx.x;
  int bl = blk / 144;                      // local image
  int rem = blk - bl*144;
  int tile = rem >> 2, g = rem & 3;        // g: 16-oc group
  int b = b0 + bl;
  int pos = tile*256 + (int)threadIdx.x;
  int oh = pos / PDIM, ow = pos - oh*PDIM;
  float sc[3], sh[3];
  #pragma unroll
  for (int ic = 0; ic < 3; ++ic){ sc[ic] = ss[(b*3 + ic)*2]; sh[ic] = ss[(b*3 + ic)*2 + 1]; }
  const float bneps = rsqrtf(1.f + 1e-5f);
  const float* Bb = Bm + (size_t)b*3*HWSZ;
  float acc[16];
  #pragma unroll
  for (int o = 0; o < 16; ++o) acc[o] = -1e30f;
  #pragma unroll 1
  for (int e = 0; e < 9; ++e){             // 3x3 maxpool window
    int ph = 2*oh - 1 + e/3;               // conv output coords
    int pw = 2*ow - 1 + e%3;
    if ((unsigned)ph >= (unsigned)C1DIM || (unsigned)pw >= (unsigned)C1DIM) continue;
    int hb = 2*ph - 3, wb = 2*pw - 3;      // conv input window base
    float se[16];
    #pragma unroll
    for (int o = 0; o < 16; ++o) se[o] = b1[g*16 + o];
    #pragma unroll 1
    for (int ic = 0; ic < 3; ++ic){
      float win[49];
      #pragma unroll
      for (int kh = 0; kh < 7; ++kh){
        int h = hb + kh;
        bool vh = (unsigned)h < (unsigned)NS;
        #pragma unroll
        for (int kw = 0; kw < 7; ++kw){
          int w = wb + kw;
          bool v = vh && ((unsigned)w < (unsigned)NS);
          float raw = v ? Bb[(size_t)ic*HWSZ + (size_t)h*NS + w] : 0.f;
          win[kh*7 + kw] = v ? fmaf(raw, sc[ic], sh[ic]) : 0.f;
        }
      }
      #pragma unroll
      for (int o = 0; o < 16; ++o){
        const float* wp = w1 + (g*16 + o)*147 + ic*49;   // wave-uniform -> s_load
        float s = se[o];
        #pragma unroll
        for (int tt = 0; tt < 49; ++tt) s = fmaf(wp[tt], win[tt], s);
        se[o] = s;
      }
    }
    #pragma unroll
    for (int o = 0; o < 16; ++o){
      int oc = g*16 + o;
      float val = fmaxf(fmaf(se[o], g1[oc]*bneps, bb1[oc]), 0.f);
      acc[o] = fmaxf(acc[o], val);
    }
  }
  #pragma unroll
  for (int o = 0; o < 16; ++o){
    int oc = g*16 + o;
    D[(((size_t)bl*C1OUT + oc)*PDIM + oh)*PDIM + ow] = acc[o];
  }
}

// conv2(3x3,p1)+BN+ReLU fused with global-average-pool. oc-group (32) in GRID;
// per-4ic win[36]; reduce LDS padded to stride 257 (bank-conflict fix).
__global__ __launch_bounds__(256) void k_conv2pool(const float* __restrict__ D,
    const float* __restrict__ w2, const float* __restrict__ b2,
    const float* __restrict__ g2, const float* __restrict__ bb2,
    float* __restrict__ freq_acc, int b0){
  __shared__ float red[32*257];
  __shared__ float red2[256];
  int blk = blockIdx.x;
  int bl = blk / 144;
  int rem = blk - bl*144;
  int tile = rem >> 2, g = rem & 3;        // g: 32-oc group
  int b = b0 + bl;
  int t = threadIdx.x;
  int pos = tile*256 + t;
  int oh = pos / PDIM, ow = pos - oh*PDIM;
  const float bneps = rsqrtf(1.f + 1e-5f);
  const float* Db = D + (size_t)bl*C1OUT*PHW;
  float acc[32];
  #pragma unroll
  for (int o = 0; o < 32; ++o) acc[o] = 0.f;
  #pragma unroll 1
  for (int icc = 0; icc < 16; ++icc){      // 4 input channels per chunk
    float win[36];
    #pragma unroll
    for (int i = 0; i < 4; ++i){
      int ic = icc*4 + i;
      const float* Dp = Db + (size_t)ic*PHW;
      #pragma unroll
      for (int kh = 0; kh < 3; ++kh){
        int h = oh - 1 + kh;
        bool vh = (unsigned)h < (unsigned)PDIM;
        #pragma unroll
        for (int kw = 0; kw < 3; ++kw){
          int w = ow - 1 + kw;
          bool v = vh && ((unsigned)w < (unsigned)PDIM);
          win[(i*3 + kh)*3 + kw] = v ? Dp[(size_t)h*PDIM + w] : 0.f;
        }
      }
    }
    #pragma unroll
    for (int o = 0; o < 32; ++o){
      const float* wp = w2 + (size_t)(g*32 + o)*576 + icc*36;   // uniform -> s_load
      float s = acc[o];
      #pragma unroll
      for (int jj = 0; jj < 36; ++jj) s = fmaf(wp[jj], win[jj], s);
      acc[o] = s;
    }
  }
  #pragma unroll
  for (int o = 0; o < 32; ++o){
    int oc = g*32 + o;
    float val = fmaxf(fmaf(acc[o] + b2[oc], g2[oc]*bneps, bb2[oc]), 0.f);
    red[o*257 + t] = val;
  }
  __syncthreads();
  { int oc = t >> 3, l = t & 7;
    float s = 0.f;
    #pragma unroll
    for (int i = 0; i < 32; ++i) s += red[oc*257 + l + 8*i];
    red2[t] = s; }
  __syncthreads();
  if (t < 32){
    float s = 0.f;
    #pragma unroll
    for (int l = 0; l < 8; ++l) s += red2[t*8 + l];
    atomicAdd(&freq_acc[b*C2OUT + g*32 + t], s);
  }
}

// RGB head + concat + 3-layer MLP, one block per batch sample.
__global__ __launch_bounds__(256) void k_mlp(const float* __restrict__ rgbmean,
    const float* __restrict__ freq_acc, const float* __restrict__ w_rgb,
    const float* __restrict__ b_rgb, const float* __restrict__ fc1w,
    const float* __restrict__ fc1b, const float* __restrict__ fc2w,
    const float* __restrict__ fc2b, const float* __restrict__ fc3w,
    const float* __restrict__ fc3b, float* __restrict__ out){
  __shared__ float z[130], z1[256], z2[128];
  int b = blockIdx.x, t = threadIdx.x;
  if (t < 2){
    float s = b_rgb[t];
    #pragma unroll
    for (int c = 0; c < 3; ++c) s += rgbmean[b*3 + c] * w_rgb[c*2 + t];
    z[t] = s;
  }
  if (t < 128) z[2 + t] = freq_acc[b*C2OUT + t] * (1.f/9216.f);
  __syncthreads();
  { float s = fc1b[t];
    for (int k = 0; k < 130; ++k) s = fmaf(z[k], fc1w[k*256 + t], s);
    z1[t] = fmaxf(s, 0.f); }
  __syncthreads();
  if (t < 128){
    float s = fc2b[t];
    for (int k = 0; k < 256; ++k) s = fmaf(z1[k], fc2w[k*128 + t], s);
    z2[t] = fmaxf(s, 0.f); }
  __syncthreads();
  if (t < 2){
    float s = fc3b[t];
    for (int k = 0; k < 128; ++k) s = fmaf(z2[k], fc3w[k*2 + t], s);
    out[b*2 + t] = s; }
}

extern "C" void kernel_launch(void* const* d_in, const int* in_sizes, int n_in,
                              void* d_out, int out_size, void* d_ws, size_t ws_size,
                              hipStream_t stream){
  const float* x     = (const float*)d_in[0];
  const float* w_rgb = (const float*)d_in[1];
  const float* b_rgb = (const float*)d_in[2];
  const float* w1    = (const float*)d_in[3];
  const float* b1    = (const float*)d_in[4];
  const float* g1    = (const float*)d_in[5];
  const float* bb1   = (const float*)d_in[6];
  const float* w2    = (const float*)d_in[7];
  const float* b2    = (const float*)d_in[8];
  const float* g2    = (const float*)d_in[9];
  const float* bb2   = (const float*)d_in[10];
  const float* fc1w  = (const float*)d_in[11];
  const float* fc1b  = (const float*)d_in[12];
  const float* fc2w  = (const float*)d_in[13];
  const float* fc2b  = (const float*)d_in[14];
  const float* fc3w  = (const float*)d_in[15];
  const float* fc3b  = (const float*)d_in[16];

  const bool full = (ws_size >= NEED_F);
  const int nloop = full ? 1 : 4;
  const int dftCH = full ? 96 : 24;        // channels per dft pass
  const int convB = full ? 32 : 8;         // images per conv pass

  char* ws = (char*)d_ws;
  float2* T  = (float2*)(ws + OFF_T);
  float*  Bm = (float*)(ws + OFF_B);
  float2* A  = (float2*)(ws + OFF_S);      // scratch: A then D (time-shared)
  float*  D  = (float*)(ws + OFF_S);
  float*  sm = (float*)(ws + (full ? OFF_SM_F : OFF_SM_C));
  float* rgbsum = sm;            // 96
  float* stats  = sm + 96;       // 192
  float* freqa  = sm + 288;      // 4096
  float* rgbm   = sm + 4384;     // 96
  float* ssb    = sm + 4480;     // 192

  hipMemsetAsync(sm, 0, 4672*sizeof(float), stream);
  k_twiddle<<<(NS*NS + 255)/256, 256, 0, stream>>>(T);
  for (int c = 0; c < nloop; ++c){
    k_dft_rows<<<dftCH*48, 192, 0, stream>>>(x, T, A, rgbsum, c*dftCH);
    k_dft_cols<<<dftCH*25, 192, 0, stream>>>(A, T, Bm, stats, c*dftCH);
  }
  k_finalize<<<1, 128, 0, stream>>>(stats, rgbsum, ssb, rgbm);
  for (int c = 0; c < nloop; ++c){
    k_conv1pool<<<convB*144, 256, 0, stream>>>(Bm, ssb, w1, b1, g1, bb1, D, c*convB);
    k_conv2pool<<<convB*144, 256, 0, stream>>>(D, w2, b2, g2, bb2, freqa, c*convB);
  }
  k_mlp<<<NB, 256, 0, stream>>>(rgbm, freqa, w_rgb, b_rgb, fc1w, fc1b,
                                fc2w, fc2b, fc3w, fc3b, (float*)d_out);
}

// Round 5
// 2897.860 us; speedup vs baseline: 3.1486x; 1.4257x over previous
//
#include <hip/hip_runtime.h>
#include <math.h>

// Problem dims
#define NB    32
#define NC    3
#define NIMG  (NB*NC)      // 96 image-channels
#define NS    384
#define HWSZ  (NS*NS)      // 147456
#define C1OUT 64
#define C1DIM 192
#define PDIM  96
#define PHW   (PDIM*PDIM)  // 9216
#define C2OUT 128
#define KWH   193          // stored half-spectrum width (kw = 0..192)
#define PI_F  3.14159265358979323846f

// ---- workspace layout (bytes) ----
// T: float2[384][384] twiddle table        =  1,179,648  @ 0
// B: float [96][384][384] shifted log-mag  = 56,623,104  @ OFF_B
// S: scratch (time-shared):                              @ OFF_S
//    full   : A float2[96][384][193] = 56,918,016  then D float[32][64][96][96] = 75,497,472
//    chunked: A float2[24][384][193] = 14,229,504  then D float[8][64][96][96]  = 18,874,368
// smalls: rgbsum[96] stats[192] freqacc[4096] rgbmean[96] ss[192] = 18,688 B
static const size_t OFF_T    = 0;
static const size_t OFF_B    = 1179648;
static const size_t OFF_S    = 57802752;
static const size_t OFF_SM_F = 133300224;
static const size_t OFF_SM_C = 76677120;
static const size_t NEED_F   = 133318912;

__device__ __forceinline__ float wave_sum(float v){
  #pragma unroll
  for (int off = 32; off; off >>= 1) v += __shfl_down(v, off);
  return v;
}

// proper mod-384 for v in [0, 768): NOT "& 383" (384 not a power of two).
__device__ __forceinline__ int mod384(int v){ return v >= NS ? v - NS : v; }

// Twiddle table: T[k][n] = exp(-2*pi*i*(k*n mod 384)/384). Exact int reduction.
__global__ void k_twiddle(float2* __restrict__ T){
  int idx = blockIdx.x*256 + (int)threadIdx.x;
  if (idx >= NS*NS) return;
  int k = idx / NS, n = idx - k*NS;
  int m = (k*n) % NS;
  float ang = -2.0f*PI_F*(float)m/(float)NS;
  T[idx] = make_float2(cosf(ang), sinf(ang));
}

// Row DFT (along W, real input): A[bc][h][kw] = sum_w x[bc][h][w]*T[w][kw].
// 8 rows per block; Nyquist via alternating sum. Also rgb pixel sums.
__global__ __launch_bounds__(192) void k_dft_rows(const float* __restrict__ x,
    const float2* __restrict__ T, float2* __restrict__ A,
    float* __restrict__ rgbsum, int bc0){
  __shared__ float xr[8*NS];
  __shared__ float rs[3];
  int blk = blockIdx.x;
  int bcl = blk / 48, rg = blk % 48;       // local channel, 8-row group
  int bc = bc0 + bcl;
  int t = threadIdx.x;
  const float* xp = x + (size_t)bc*HWSZ + (size_t)rg*8*NS;
  float lsum = 0.f;
  #pragma unroll
  for (int i = 0; i < 16; ++i){
    int lin = i*192 + t;
    float v = xp[lin];
    xr[lin] = v;
    lsum += v;
  }
  float ws = wave_sum(lsum);
  if ((t & 63) == 0) rs[t >> 6] = ws;
  __syncthreads();
  if (t == 0) atomicAdd(&rgbsum[bc], rs[0] + rs[1] + rs[2]);

  float2 acc[8];
  float ny[8];
  #pragma unroll
  for (int r = 0; r < 8; ++r){ acc[r] = make_float2(0.f,0.f); ny[r] = 0.f; }
  for (int n = 0; n < NS; ++n){
    float2 tw = T[n*NS + t];
    float sg = (n & 1) ? -1.f : 1.f;
    #pragma unroll
    for (int r = 0; r < 8; ++r){
      float xv = xr[r*NS + n];
      acc[r].x = fmaf(xv, tw.x, acc[r].x);
      acc[r].y = fmaf(xv, tw.y, acc[r].y);
      ny[r]    = fmaf(xv, sg,   ny[r]);
    }
  }
  #pragma unroll
  for (int r = 0; r < 8; ++r){
    size_t base = ((size_t)bcl*NS + rg*8 + r)*KWH;
    A[base + t] = acc[r];                  // kw = t in [0,192)
    if (t == 0) A[base + 192] = make_float2(ny[r], 0.f);
  }
}

// Column DFT (along H) for kw in [0,192] (8 cols/block), then |.|, log1p,
// fftshift, mirror to kw in (192,384) via conjugate symmetry.
__global__ __launch_bounds__(192) void k_dft_cols(const float2* __restrict__ A,
    const float2* __restrict__ T, float* __restrict__ Bm,
    float* __restrict__ stats, int bc0){
  __shared__ float2 tile[NS][9];           // 8 cols + pad
  __shared__ float rs[6];
  int blk = blockIdx.x;
  int bcl = blk / 25, cg = blk % 25;
  int bc = bc0 + bcl;
  int kw0 = cg*8;
  int cols = (cg == 24) ? 1 : 8;           // 193 = 24*8 + 1
  int t = threadIdx.x;
  const float2* Al = A + (size_t)bcl*NS*KWH;
  if (cols == 8){
    #pragma unroll
    for (int i = 0; i < 16; ++i){
      int lin = i*192 + t;
      int h = lin >> 3, c = lin & 7;
      tile[h][c] = Al[(size_t)h*KWH + kw0 + c];
    }
  } else {
    for (int lin = t; lin < NS; lin += 192)
      tile[lin][0] = Al[(size_t)lin*KWH + kw0];
  }
  __syncthreads();
  float2 acc[8][2];
  #pragma unroll
  for (int c = 0; c < 8; ++c){ acc[c][0] = make_float2(0.f,0.f); acc[c][1] = make_float2(0.f,0.f); }
  for (int h = 0; h < NS; ++h){
    float2 t0 = T[h*NS + t];
    float2 t1 = T[h*NS + t + 192];
    #pragma unroll
    for (int c = 0; c < 8; ++c){
      if (c < cols){
        float2 a = tile[h][c];
        acc[c][0].x = fmaf(a.x, t0.x, fmaf(-a.y, t0.y, acc[c][0].x));
        acc[c][0].y = fmaf(a.x, t0.y, fmaf( a.y, t0.x, acc[c][0].y));
        acc[c][1].x = fmaf(a.x, t1.x, fmaf(-a.y, t1.y, acc[c][1].x));
        acc[c][1].y = fmaf(a.x, t1.y, fmaf( a.y, t1.x, acc[c][1].y));
      }
    }
  }
  float s1 = 0.f, s2 = 0.f;
  float* Bbc = Bm + (size_t)bc*HWSZ;
  #pragma unroll
  for (int c = 0; c < 8; ++c){
    if (c < cols){
      int kw = kw0 + c;
      #pragma unroll
      for (int kk = 0; kk < 2; ++kk){
        int kh = t + kk*192;
        float2 X = acc[c][kk];
        float mag = logf(sqrtf(X.x*X.x + X.y*X.y) + 1.f);
        int u = mod384(kh + 192);          // shifted H index
        int v = mod384(kw + 192);          // shifted W index
        Bbc[(size_t)u*NS + v] = mag;
        s1 += mag; s2 += mag*mag;
        if (kw >= 1 && kw <= 191){         // conj mirror -> kw2 in [193,383]
          int kh2 = mod384(NS - kh);
          int u2 = mod384(kh2 + 192);
          int v2 = mod384(NS - kw + 192);  // = 192 - kw
          Bbc[(size_t)u2*NS + v2] = mag;
          s1 += mag; s2 += mag*mag;
        }
      }
    }
  }
  float w1s = wave_sum(s1), w2s = wave_sum(s2);
  if ((t & 63) == 0){ rs[t >> 6] = w1s; rs[3 + (t >> 6)] = w2s; }
  __syncthreads();
  if (t == 0){
    atomicAdd(&stats[bc*2],     rs[0] + rs[1] + rs[2]);
    atomicAdd(&stats[bc*2 + 1], rs[3] + rs[4] + rs[5]);
  }
}

__global__ void k_finalize(const float* __restrict__ stats, const float* __restrict__ rgbsum,
                           float* __restrict__ ss, float* __restrict__ rgbmean){
  int t = threadIdx.x;
  if (t < NIMG){
    const float inv_n = 1.f / 147456.f;
    float mean = stats[t*2] * inv_n;
    float var  = fmaxf(stats[t*2 + 1] * inv_n - mean*mean, 0.f);
    float inv  = 1.f / (sqrtf(var) + 1e-8f);
    ss[t*2]     = inv;          // normalized = mag*inv + (-mean*inv)
    ss[t*2 + 1] = -mean * inv;
    rgbmean[t]  = rgbsum[t] * inv_n;
  }
}

// conv1(7x7,s2,p3)+BN+ReLU fused with maxpool(3,s2,p1).
// Block = one 16x16 pooled tile x 16 oc. Entire input patch [3][71][71]
// staged (normalized, zero-padded) in LDS once -> all window reads are ds_read.
// HBM traffic: 4608 blocks x 60KB = 276 MB (vs 1.245 GB measured in round 4).
__global__ __launch_bounds__(256) void k_conv1pool(const float* __restrict__ Bm,
    const float* __restrict__ ss, const float* __restrict__ w1, const float* __restrict__ b1,
    const float* __restrict__ g1, const float* __restrict__ bb1, float* __restrict__ D,
    int b0){
  __shared__ float sB[3][71][73];          // 62,196 B (stride 73; 8-way bank pattern accepted)
  int blk = blockIdx.x;
  int bl = blk / 144;                      // local image
  int rem = blk - bl*144;
  int tile = rem >> 2, g = rem & 3;        // g: 16-oc group
  int b = b0 + bl;
  int oh0 = (tile / 6) * 16, ow0 = (tile % 6) * 16;
  int t = threadIdx.x;
  float sc[3], sh[3];
  #pragma unroll
  for (int ic = 0; ic < 3; ++ic){ sc[ic] = ss[(b*3 + ic)*2]; sh[ic] = ss[(b*3 + ic)*2 + 1]; }
  const int hb0 = 4*oh0 - 5, wb0 = 4*ow0 - 5;
  const float* Bb = Bm + (size_t)b*3*HWSZ;
  for (int lin = t; lin < 3*71*71; lin += 256){
    int ic = lin / 5041; int r = lin - ic*5041;
    int h = r / 71, w = r - h*71;
    int hg = hb0 + h, wg = wb0 + w;
    bool v = ((unsigned)hg < (unsigned)NS) && ((unsigned)wg < (unsigned)NS);
    float raw = v ? Bb[(size_t)ic*HWSZ + (size_t)hg*NS + wg] : 0.f;
    sB[ic][h][w] = v ? fmaf(raw, sc[ic], sh[ic]) : 0.f;   // conv zero-pad AFTER normalize
  }
  __syncthreads();

  int ol = t >> 4, wl = t & 15;
  const float bneps = rsqrtf(1.f + 1e-5f);
  float acc[16];
  #pragma unroll
  for (int o = 0; o < 16; ++o) acc[o] = -1e30f;
  #pragma unroll 1
  for (int e = 0; e < 9; ++e){             // 3x3 maxpool window
    int dh = e/3, dw = e%3;
    int ph = 2*(oh0 + ol) - 1 + dh;        // global conv-output coords
    int pw = 2*(ow0 + wl) - 1 + dw;
    if (ph < 0 || pw < 0) continue;        // pool -inf padding (ph,pw <= 191 always)
    float se[16];
    #pragma unroll
    for (int o = 0; o < 16; ++o) se[o] = b1[g*16 + o];
    #pragma unroll 1
    for (int ic = 0; ic < 3; ++ic){
      #pragma unroll
      for (int kh = 0; kh < 7; ++kh){
        const float* row = &sB[ic][4*ol + 2*dh + kh][4*wl + 2*dw];
        float r0=row[0], r1=row[1], r2=row[2], r3=row[3], r4=row[4], r5=row[5], r6=row[6];
        const float* wp = w1 + (g*16)*147 + ic*49 + kh*7;  // wave-uniform
        #pragma unroll
        for (int o = 0; o < 16; ++o){
          const float* w8 = wp + o*147;
          float s = se[o];
          s = fmaf(w8[0], r0, s); s = fmaf(w8[1], r1, s);
          s = fmaf(w8[2], r2, s); s = fmaf(w8[3], r3, s);
          s = fmaf(w8[4], r4, s); s = fmaf(w8[5], r5, s);
          s = fmaf(w8[6], r6, s);
          se[o] = s;
        }
      }
    }
    #pragma unroll
    for (int o = 0; o < 16; ++o){
      int oc = g*16 + o;
      float val = fmaxf(fmaf(se[o], g1[oc]*bneps, bb1[oc]), 0.f);
      acc[o] = fmaxf(acc[o], val);
    }
  }
  #pragma unroll
  for (int o = 0; o < 16; ++o){
    int oc = g*16 + o;
    D[(((size_t)bl*C1OUT + oc)*PDIM + (oh0 + ol))*PDIM + (ow0 + wl)] = acc[o];
  }
}

// conv2(3x3,p1)+BN+ReLU fused with global-average-pool.
// Block = 16x16 output tile x 32 oc; input staged in 4 chunks of 16 ic
// ([16][18][19] = 21.9 KB). Reduction via wave shuffles (no big LDS buffer).
__global__ __launch_bounds__(256) void k_conv2pool(const float* __restrict__ D,
    const float* __restrict__ w2, const float* __restrict__ b2,
    const float* __restrict__ g2, const float* __restrict__ bb2,
    float* __restrict__ freq_acc, int b0){
  __shared__ float sD[16][18][19];         // 21,888 B
  __shared__ float pr[4][32];
  int blk = blockIdx.x;
  int bl = blk / 144;
  int rem = blk - bl*144;
  int tile = rem >> 2, g = rem & 3;        // g: 32-oc group
  int b = b0 + bl;
  int oh0 = (tile / 6) * 16, ow0 = (tile % 6) * 16;
  int t = threadIdx.x;
  int ol = t >> 4, wl = t & 15;
  const float* Db = D + (size_t)bl*C1OUT*PHW;
  float acc[32];
  #pragma unroll
  for (int o = 0; o < 32; ++o) acc[o] = 0.f;
  #pragma unroll 1
  for (int icc = 0; icc < 4; ++icc){       // 16 input channels per chunk
    __syncthreads();                       // previous chunk fully consumed
    for (int lin = t; lin < 16*18*18; lin += 256){
      int ic = lin / 324; int r = lin - ic*324;
      int h = r / 18, w = r - h*18;
      int hg = oh0 - 1 + h, wg = ow0 - 1 + w;
      bool v = ((unsigned)hg < (unsigned)PDIM) && ((unsigned)wg < (unsigned)PDIM);
      sD[ic][h][w] = v ? Db[(size_t)(icc*16 + ic)*PHW + (size_t)hg*PDIM + wg] : 0.f;
    }
    __syncthreads();
    #pragma unroll 1
    for (int i = 0; i < 16; ++i){
      #pragma unroll
      for (int kh = 0; kh < 3; ++kh){
        const float* row = &sD[i][ol + kh][wl];
        float r0 = row[0], r1 = row[1], r2 = row[2];
        const float* wp = w2 + (size_t)(g*32)*576 + (icc*16 + i)*9 + kh*3;  // uniform
        #pragma unroll
        for (int o = 0; o < 32; ++o){
          const float* w3 = wp + o*576;
          acc[o] = fmaf(w3[0], r0, fmaf(w3[1], r1, fmaf(w3[2], r2, acc[o])));
        }
      }
    }
  }
  const float bneps = rsqrtf(1.f + 1e-5f);
  int wv = t >> 6;
  #pragma unroll
  for (int o = 0; o < 32; ++o){
    int oc = g*32 + o;
    float val = fmaxf(fmaf(acc[o] + b2[oc], g2[oc]*bneps, bb2[oc]), 0.f);
    float s = wave_sum(val);
    if ((t & 63) == 0) pr[wv][o] = s;
  }
  __syncthreads();
  if (t < 32){
    float s = pr[0][t] + pr[1][t] + pr[2][t] + pr[3][t];
    atomicAdd(&freq_acc[b*C2OUT + g*32 + t], s);
  }
}

// RGB head + concat + 3-layer MLP, one block per batch sample.
__global__ __launch_bounds__(256) void k_mlp(const float* __restrict__ rgbmean,
    const float* __restrict__ freq_acc, const float* __restrict__ w_rgb,
    const float* __restrict__ b_rgb, const float* __restrict__ fc1w,
    const float* __restrict__ fc1b, const float* __restrict__ fc2w,
    const float* __restrict__ fc2b, const float* __restrict__ fc3w,
    const float* __restrict__ fc3b, float* __restrict__ out){
  __shared__ float z[130], z1[256], z2[128];
  int b = blockIdx.x, t = threadIdx.x;
  if (t < 2){
    float s = b_rgb[t];
    #pragma unroll
    for (int c = 0; c < 3; ++c) s += rgbmean[b*3 + c] * w_rgb[c*2 + t];
    z[t] = s;
  }
  if (t < 128) z[2 + t] = freq_acc[b*C2OUT + t] * (1.f/9216.f);
  __syncthreads();
  { float s = fc1b[t];
    for (int k = 0; k < 130; ++k) s = fmaf(z[k], fc1w[k*256 + t], s);
    z1[t] = fmaxf(s, 0.f); }
  __syncthreads();
  if (t < 128){
    float s = fc2b[t];
    for (int k = 0; k < 256; ++k) s = fmaf(z1[k], fc2w[k*128 + t], s);
    z2[t] = fmaxf(s, 0.f); }
  __syncthreads();
  if (t < 2){
    float s = fc3b[t];
    for (int k = 0; k < 128; ++k) s = fmaf(z2[k], fc3w[k*2 + t], s);
    out[b*2 + t] = s; }
}

extern "C" void kernel_launch(void* const* d_in, const int* in_sizes, int n_in,
                              void* d_out, int out_size, void* d_ws, size_t ws_size,
                              hipStream_t stream){
  const float* x     = (const float*)d_in[0];
  const float* w_rgb = (const float*)d_in[1];
  const float* b_rgb = (const float*)d_in[2];
  const float* w1    = (const float*)d_in[3];
  const float* b1    = (const float*)d_in[4];
  const float* g1    = (const float*)d_in[5];
  const float* bb1   = (const float*)d_in[6];
  const float* w2    = (const float*)d_in[7];
  const float* b2    = (const float*)d_in[8];
  const float* g2    = (const float*)d_in[9];
  const float* bb2   = (const float*)d_in[10];
  const float* fc1w  = (const float*)d_in[11];
  const float* fc1b  = (const float*)d_in[12];
  const float* fc2w  = (const float*)d_in[13];
  const float* fc2b  = (const float*)d_in[14];
  const float* fc3w  = (const float*)d_in[15];
  const float* fc3b  = (const float*)d_in[16];

  const bool full = (ws_size >= NEED_F);
  const int nloop = full ? 1 : 4;
  const int dftCH = full ? 96 : 24;        // channels per dft pass
  const int convB = full ? 32 : 8;         // images per conv pass

  char* ws = (char*)d_ws;
  float2* T  = (float2*)(ws + OFF_T);
  float*  Bm = (float*)(ws + OFF_B);
  float2* A  = (float2*)(ws + OFF_S);      // scratch: A then D (time-shared)
  float*  D  = (float*)(ws + OFF_S);
  float*  sm = (float*)(ws + (full ? OFF_SM_F : OFF_SM_C));
  float* rgbsum = sm;            // 96
  float* stats  = sm + 96;       // 192
  float* freqa  = sm + 288;      // 4096
  float* rgbm   = sm + 4384;     // 96
  float* ssb    = sm + 4480;     // 192

  hipMemsetAsync(sm, 0, 4672*sizeof(float), stream);
  k_twiddle<<<(NS*NS + 255)/256, 256, 0, stream>>>(T);
  for (int c = 0; c < nloop; ++c){
    k_dft_rows<<<dftCH*48, 192, 0, stream>>>(x, T, A, rgbsum, c*dftCH);
    k_dft_cols<<<dftCH*25, 192, 0, stream>>>(A, T, Bm, stats, c*dftCH);
  }
  k_finalize<<<1, 128, 0, stream>>>(stats, rgbsum, ssb, rgbm);
  for (int c = 0; c < nloop; ++c){
    k_conv1pool<<<convB*144, 256, 0, stream>>>(Bm, ssb, w1, b1, g1, bb1, D, c*convB);
    k_conv2pool<<<convB*144, 256, 0, stream>>>(D, w2, b2, g2, bb2, freqa, c*convB);
  }
  k_mlp<<<NB, 256, 0, stream>>>(rgbm, freqa, w_rgb, b_rgb, fc1w, fc1b,
                                fc2w, fc2b, fc3w, fc3b, (float*)d_out);
}

// Round 6
// 2552.342 us; speedup vs baseline: 3.5748x; 1.1354x over previous
//
#include <hip/hip_runtime.h>
#include <math.h>

// Problem dims
#define NB    32
#define NC    3
#define NIMG  (NB*NC)      // 96 image-channels
#define NS    384
#define HWSZ  (NS*NS)      // 147456
#define C1OUT 64
#define C1DIM 192
#define PDIM  96
#define PHW   (PDIM*PDIM)  // 9216
#define C2OUT 128
#define KWH   193          // stored half-spectrum width (kw = 0..192)
#define PI_F  3.14159265358979323846f

// ---- workspace layout (bytes) ----
// T: float2[384][384] twiddle table        =  1,179,648  @ 0
// B: float [96][384][384] shifted log-mag  = 56,623,104  @ OFF_B
// S: scratch (time-shared):                              @ OFF_S
//    full   : A float2[96][384][193] = 56,918,016  then D float[32][64][96][96] = 75,497,472
//    chunked: A float2[24][384][193] = 14,229,504  then D float[8][64][96][96]  = 18,874,368
// smalls: rgbsum[96] stats[192] freqacc[4096] rgbmean[96] ss[192] = 18,688 B
static const size_t OFF_T    = 0;
static const size_t OFF_B    = 1179648;
static const size_t OFF_S    = 57802752;
static const size_t OFF_SM_F = 133300224;
static const size_t OFF_SM_C = 76677120;
static const size_t NEED_F   = 133318912;

__device__ __forceinline__ float wave_sum(float v){
  #pragma unroll
  for (int off = 32; off; off >>= 1) v += __shfl_down(v, off);
  return v;
}

// proper mod-384 for v in [0, 768): NOT "& 383" (384 not a power of two).
__device__ __forceinline__ int mod384(int v){ return v >= NS ? v - NS : v; }

// Twiddle table: T[k][n] = exp(-2*pi*i*(k*n mod 384)/384). Exact int reduction.
__global__ void k_twiddle(float2* __restrict__ T){
  int idx = blockIdx.x*256 + (int)threadIdx.x;
  if (idx >= NS*NS) return;
  int k = idx / NS, n = idx - k*NS;
  int m = (k*n) % NS;
  float ang = -2.0f*PI_F*(float)m/(float)NS;
  T[idx] = make_float2(cosf(ang), sinf(ang));
}

// Row DFT (along W, real input): A[bc][h][kw] = sum_w x[bc][h][w]*T[w][kw].
// 8 rows per block; Nyquist via alternating sum. Also rgb pixel sums.
__global__ __launch_bounds__(192) void k_dft_rows(const float* __restrict__ x,
    const float2* __restrict__ T, float2* __restrict__ A,
    float* __restrict__ rgbsum, int bc0){
  __shared__ float xr[8*NS];
  __shared__ float rs[3];
  int blk = blockIdx.x;
  int bcl = blk / 48, rg = blk % 48;       // local channel, 8-row group
  int bc = bc0 + bcl;
  int t = threadIdx.x;
  const float* xp = x + (size_t)bc*HWSZ + (size_t)rg*8*NS;
  float lsum = 0.f;
  #pragma unroll
  for (int i = 0; i < 16; ++i){
    int lin = i*192 + t;
    float v = xp[lin];
    xr[lin] = v;
    lsum += v;
  }
  float ws = wave_sum(lsum);
  if ((t & 63) == 0) rs[t >> 6] = ws;
  __syncthreads();
  if (t == 0) atomicAdd(&rgbsum[bc], rs[0] + rs[1] + rs[2]);

  float2 acc[8];
  float ny[8];
  #pragma unroll
  for (int r = 0; r < 8; ++r){ acc[r] = make_float2(0.f,0.f); ny[r] = 0.f; }
  for (int n = 0; n < NS; ++n){
    float2 tw = T[n*NS + t];
    float sg = (n & 1) ? -1.f : 1.f;
    #pragma unroll
    for (int r = 0; r < 8; ++r){
      float xv = xr[r*NS + n];
      acc[r].x = fmaf(xv, tw.x, acc[r].x);
      acc[r].y = fmaf(xv, tw.y, acc[r].y);
      ny[r]    = fmaf(xv, sg,   ny[r]);
    }
  }
  #pragma unroll
  for (int r = 0; r < 8; ++r){
    size_t base = ((size_t)bcl*NS + rg*8 + r)*KWH;
    A[base + t] = acc[r];                  // kw = t in [0,192)
    if (t == 0) A[base + 192] = make_float2(ny[r], 0.f);
  }
}

// Column DFT (along H) for kw in [0,192] (8 cols/block), then |.|, log1p,
// fftshift, mirror to kw in (192,384) via conjugate symmetry.
__global__ __launch_bounds__(192) void k_dft_cols(const float2* __restrict__ A,
    const float2* __restrict__ T, float* __restrict__ Bm,
    float* __restrict__ stats, int bc0){
  __shared__ float2 tile[NS][9];           // 8 cols + pad
  __shared__ float rs[6];
  int blk = blockIdx.x;
  int bcl = blk / 25, cg = blk % 25;
  int bc = bc0 + bcl;
  int kw0 = cg*8;
  int cols = (cg == 24) ? 1 : 8;           // 193 = 24*8 + 1
  int t = threadIdx.x;
  const float2* Al = A + (size_t)bcl*NS*KWH;
  if (cols == 8){
    #pragma unroll
    for (int i = 0; i < 16; ++i){
      int lin = i*192 + t;
      int h = lin >> 3, c = lin & 7;
      tile[h][c] = Al[(size_t)h*KWH + kw0 + c];
    }
  } else {
    for (int lin = t; lin < NS; lin += 192)
      tile[lin][0] = Al[(size_t)lin*KWH + kw0];
  }
  __syncthreads();
  float2 acc[8][2];
  #pragma unroll
  for (int c = 0; c < 8; ++c){ acc[c][0] = make_float2(0.f,0.f); acc[c][1] = make_float2(0.f,0.f); }
  for (int h = 0; h < NS; ++h){
    float2 t0 = T[h*NS + t];
    float2 t1 = T[h*NS + t + 192];
    #pragma unroll
    for (int c = 0; c < 8; ++c){
      if (c < cols){
        float2 a = tile[h][c];
        acc[c][0].x = fmaf(a.x, t0.x, fmaf(-a.y, t0.y, acc[c][0].x));
        acc[c][0].y = fmaf(a.x, t0.y, fmaf( a.y, t0.x, acc[c][0].y));
        acc[c][1].x = fmaf(a.x, t1.x, fmaf(-a.y, t1.y, acc[c][1].x));
        acc[c][1].y = fmaf(a.x, t1.y, fmaf( a.y, t1.x, acc[c][1].y));
      }
    }
  }
  float s1 = 0.f, s2 = 0.f;
  float* Bbc = Bm + (size_t)bc*HWSZ;
  #pragma unroll
  for (int c = 0; c < 8; ++c){
    if (c < cols){
      int kw = kw0 + c;
      #pragma unroll
      for (int kk = 0; kk < 2; ++kk){
        int kh = t + kk*192;
        float2 X = acc[c][kk];
        float mag = logf(sqrtf(X.x*X.x + X.y*X.y) + 1.f);
        int u = mod384(kh + 192);          // shifted H index
        int v = mod384(kw + 192);          // shifted W index
        Bbc[(size_t)u*NS + v] = mag;
        s1 += mag; s2 += mag*mag;
        if (kw >= 1 && kw <= 191){         // conj mirror -> kw2 in [193,383]
          int kh2 = mod384(NS - kh);
          int u2 = mod384(kh2 + 192);
          int v2 = mod384(NS - kw + 192);  // = 192 - kw
          Bbc[(size_t)u2*NS + v2] = mag;
          s1 += mag; s2 += mag*mag;
        }
      }
    }
  }
  float w1s = wave_sum(s1), w2s = wave_sum(s2);
  if ((t & 63) == 0){ rs[t >> 6] = w1s; rs[3 + (t >> 6)] = w2s; }
  __syncthreads();
  if (t == 0){
    atomicAdd(&stats[bc*2],     rs[0] + rs[1] + rs[2]);
    atomicAdd(&stats[bc*2 + 1], rs[3] + rs[4] + rs[5]);
  }
}

__global__ void k_finalize(const float* __restrict__ stats, const float* __restrict__ rgbsum,
                           float* __restrict__ ss, float* __restrict__ rgbmean){
  int t = threadIdx.x;
  if (t < NIMG){
    const float inv_n = 1.f / 147456.f;
    float mean = stats[t*2] * inv_n;
    float var  = fmaxf(stats[t*2 + 1] * inv_n - mean*mean, 0.f);
    float inv  = 1.f / (sqrtf(var) + 1e-8f);
    ss[t*2]     = inv;          // normalized = mag*inv + (-mean*inv)
    ss[t*2 + 1] = -mean * inv;
    rgbmean[t]  = rgbsum[t] * inv_n;
  }
}

// conv1(7x7,s2,p3)+BN+ReLU fused with maxpool(3,s2,p1) — conv-then-pool.
// Block = one 16x16 pooled tile, ALL 64 oc. Input patch [3][71][71] staged
// (normalized, zero-padded) as 4 PARITY SUB-PLANES per ic so every conv-eval
// LDS read is lane-stride-1 (conflict-free; conv s2 would otherwise give
// stride-2/4 -> 4/8-way conflicts, measured 1.47e8 conflict cycles in r5).
// Each conv output computed exactly ONCE (33x33 tile in cv), pooled 3x3/s2.
// Sub-plane offsets within each ic's 5041-float region:
//   (h even,w even): off 0,    stride 36, 36 rows
//   (h even,w odd ): off 1296, stride 35, 36 rows
//   (h odd, w even): off 2556, stride 36, 35 rows
//   (h odd, w odd ): off 3816, stride 35, 35 rows
__global__ __launch_bounds__(256) void k_conv1pool(const float* __restrict__ Bm,
    const float* __restrict__ ss, const float* __restrict__ w1, const float* __restrict__ b1,
    const float* __restrict__ g1, const float* __restrict__ bb1, float* __restrict__ D,
    int b0){
  __shared__ float sP[3*5041];             // 60,492 B
  __shared__ float cv[33*33];              //  4,356 B  (total 64,848 <= 64 KiB)
  int blk = blockIdx.x;
  int bl = blk / 36, tile = blk % 36;
  int b = b0 + bl;
  int oh0 = (tile / 6) * 16, ow0 = (tile % 6) * 16;
  int t = threadIdx.x;
  float sc[3], sh[3];
  #pragma unroll
  for (int ic = 0; ic < 3; ++ic){ sc[ic] = ss[(b*3 + ic)*2]; sh[ic] = ss[(b*3 + ic)*2 + 1]; }
  const int hb0 = 4*oh0 - 5, wb0 = 4*ow0 - 5;   // patch origin in input coords
  const float* Bb = Bm + (size_t)b*3*HWSZ;

  // ---- stage patch into parity sub-planes (global reads coalesced in w) ----
  for (int lin = t; lin < 3*5041; lin += 256){
    int ic = lin / 5041; int r = lin - ic*5041;
    int h = r / 71, w = r - h*71;
    int hg = hb0 + h, wg = wb0 + w;
    bool v = ((unsigned)hg < (unsigned)NS) && ((unsigned)wg < (unsigned)NS);
    float raw = v ? Bb[(size_t)ic*HWSZ + (size_t)hg*NS + wg] : 0.f;
    float val = v ? fmaf(raw, sc[ic], sh[ic]) : 0.f;
    int wodd = w & 1;
    int base = (h & 1) ? (wodd ? 3816 : 2556) : (wodd ? 1296 : 0);
    int str  = wodd ? 35 : 36;
    sP[ic*5041 + base + (h>>1)*str + (w>>1)] = val;
  }
  __syncthreads();

  // ---- per-thread conv positions (33x33 = 1089, 5 passes of 256) ----
  int P[5], Q[5]; bool ACT[5], VAL[5];
  #pragma unroll
  for (int pass = 0; pass < 5; ++pass){
    int lin = pass*256 + t;
    ACT[pass] = (lin < 1089);
    int lc = ACT[pass] ? lin : 0;
    int p = lc / 33, q = lc - 33*p;
    P[pass] = p; Q[pass] = q;
    int phg = 2*oh0 - 1 + p, pwg = 2*ow0 - 1 + q;
    VAL[pass] = ((unsigned)phg < (unsigned)C1DIM) && ((unsigned)pwg < (unsigned)C1DIM);
  }

  const float bneps = rsqrtf(1.f + 1e-5f);
  int ol = t >> 4, wl = t & 15;

  #pragma unroll 1
  for (int ocg = 0; ocg < 8; ++ocg){       // 8 oc at a time in registers
    float bini[8];
    #pragma unroll
    for (int o = 0; o < 8; ++o) bini[o] = b1[ocg*8 + o];
    float r_[5][8];
    #pragma unroll
    for (int pass = 0; pass < 5; ++pass)
      #pragma unroll
      for (int o = 0; o < 8; ++o) r_[pass][o] = bini[o];

    const float* wg0 = w1 + ocg*8*147;     // wave-uniform weight base
    #pragma unroll
    for (int pass = 0; pass < 5; ++pass){
      if (ACT[pass]){
        int p = P[pass], q = Q[pass];
        #pragma unroll 1
        for (int ic = 0; ic < 3; ++ic){
          // plane bases for this conv position (taps add khh*str + kw>>1)
          int bEE = ic*5041 +    0 + p*36 + q;   // kh even, kw even
          int bEO = ic*5041 + 1296 + p*35 + q;   // kh even, kw odd
          int bOE = ic*5041 + 2556 + p*36 + q;   // kh odd,  kw even
          int bOO = ic*5041 + 3816 + p*35 + q;   // kh odd,  kw odd
          const float* wic = wg0 + ic*49;
          #pragma unroll 1
          for (int khh = 0; khh < 3; ++khh){     // kh = 2*khh and 2*khh+1
            // even kh row: input row idx p+khh in (E*) planes
            float e0 = sP[bEE + khh*36    ], e1 = sP[bEE + khh*36 + 1];
            float e2 = sP[bEE + khh*36 + 2], e3 = sP[bEE + khh*36 + 3];
            float d0 = sP[bEO + khh*35    ], d1 = sP[bEO + khh*35 + 1];
            float d2 = sP[bEO + khh*35 + 2];
            const float* wr0 = wic + (2*khh)*7;
            #pragma unroll
            for (int o = 0; o < 8; ++o){
              const float* w8 = wr0 + o*147;
              float s = r_[pass][o];
              s = fmaf(w8[0], e0, s); s = fmaf(w8[1], d0, s);
              s = fmaf(w8[2], e1, s); s = fmaf(w8[3], d1, s);
              s = fmaf(w8[4], e2, s); s = fmaf(w8[5], d2, s);
              s = fmaf(w8[6], e3, s);
              r_[pass][o] = s;
            }
            // odd kh row: input row idx p+khh in (O*) planes
            float f0 = sP[bOE + khh*36    ], f1 = sP[bOE + khh*36 + 1];
            float f2 = sP[bOE + khh*36 + 2], f3 = sP[bOE + khh*36 + 3];
            float g0 = sP[bOO + khh*35    ], g1v = sP[bOO + khh*35 + 1];
            float g2v = sP[bOO + khh*35 + 2];
            const float* wr1 = wic + (2*khh + 1)*7;
            #pragma unroll
            for (int o = 0; o < 8; ++o){
              const float* w8 = wr1 + o*147;
              float s = r_[pass][o];
              s = fmaf(w8[0], f0, s); s = fmaf(w8[1], g0, s);
              s = fmaf(w8[2], f1, s); s = fmaf(w8[3], g1v, s);
              s = fmaf(w8[4], f2, s); s = fmaf(w8[5], g2v, s);
              s = fmaf(w8[6], f3, s);
              r_[pass][o] = s;
            }
          }
          { // tail kh = 6 (even), row idx p+3
            float e0 = sP[bEE + 108], e1 = sP[bEE + 109];
            float e2 = sP[bEE + 110], e3 = sP[bEE + 111];
            float d0 = sP[bEO + 105], d1 = sP[bEO + 106];
            float d2 = sP[bEO + 107];
            const float* wr = wic + 42;
            #pragma unroll
            for (int o = 0; o < 8; ++o){
              const float* w8 = wr + o*147;
              float s = r_[pass][o];
              s = fmaf(w8[0], e0, s); s = fmaf(w8[1], d0, s);
              s = fmaf(w8[2], e1, s); s = fmaf(w8[3], d1, s);
              s = fmaf(w8[4], e2, s); s = fmaf(w8[5], d2, s);
              s = fmaf(w8[6], e3, s);
              r_[pass][o] = s;
            }
          }
        }
      }
    }
    // ---- per-oc: BN+ReLU into cv, pool 3x3/s2, write D ----
    #pragma unroll 1
    for (int o = 0; o < 8; ++o){
      int oc = ocg*8 + o;
      float gsc = g1[oc]*bneps, bbv = bb1[oc];
      __syncthreads();                     // previous pool done with cv
      #pragma unroll
      for (int pass = 0; pass < 5; ++pass){
        if (ACT[pass])
          cv[P[pass]*33 + Q[pass]] = VAL[pass]
              ? fmaxf(fmaf(r_[pass][o], gsc, bbv), 0.f) : 0.f;
      }
      __syncthreads();
      float m = 0.f;                       // all candidates >= 0 (ReLU)
      #pragma unroll
      for (int dh = 0; dh < 3; ++dh)
        #pragma unroll
        for (int dw = 0; dw < 3; ++dw)
          m = fmaxf(m, cv[(2*ol + dh)*33 + 2*wl + dw]);
      D[(((size_t)bl*C1OUT + oc)*PDIM + (oh0 + ol))*PDIM + (ow0 + wl)] = m;
    }
  }
}

// conv2(3x3,p1)+BN+ReLU fused with global-average-pool.
// Block = 16x16 output tile x 32 oc; input staged in 4 chunks of 16 ic
// ([16][18][19] = 21.9 KB). Reduction via wave shuffles (no big LDS buffer).
__global__ __launch_bounds__(256) void k_conv2pool(const float* __restrict__ D,
    const float* __restrict__ w2, const float* __restrict__ b2,
    const float* __restrict__ g2, const float* __restrict__ bb2,
    float* __restrict__ freq_acc, int b0){
  __shared__ float sD[16][18][19];         // 21,888 B
  __shared__ float pr[4][32];
  int blk = blockIdx.x;
  int bl = blk / 144;
  int rem = blk - bl*144;
  int tile = rem >> 2, g = rem & 3;        // g: 32-oc group
  int b = b0 + bl;
  int oh0 = (tile / 6) * 16, ow0 = (tile % 6) * 16;
  int t = threadIdx.x;
  int ol = t >> 4, wl = t & 15;
  const float* Db = D + (size_t)bl*C1OUT*PHW;
  float acc[32];
  #pragma unroll
  for (int o = 0; o < 32; ++o) acc[o] = 0.f;
  #pragma unroll 1
  for (int icc = 0; icc < 4; ++icc){       // 16 input channels per chunk
    __syncthreads();                       // previous chunk fully consumed
    for (int lin = t; lin < 16*18*18; lin += 256){
      int ic = lin / 324; int r = lin - ic*324;
      int h = r / 18, w = r - h*18;
      int hg = oh0 - 1 + h, wg = ow0 - 1 + w;
      bool v = ((unsigned)hg < (unsigned)PDIM) && ((unsigned)wg < (unsigned)PDIM);
      sD[ic][h][w] = v ? Db[(size_t)(icc*16 + ic)*PHW + (size_t)hg*PDIM + wg] : 0.f;
    }
    __syncthreads();
    #pragma unroll 1
    for (int i = 0; i < 16; ++i){
      #pragma unroll
      for (int kh = 0; kh < 3; ++kh){
        const float* row = &sD[i][ol + kh][wl];
        float r0 = row[0], r1 = row[1], r2 = row[2];
        const float* wp = w2 + (size_t)(g*32)*576 + (icc*16 + i)*9 + kh*3;  // uniform
        #pragma unroll
        for (int o = 0; o < 32; ++o){
          const float* w3 = wp + o*576;
          acc[o] = fmaf(w3[0], r0, fmaf(w3[1], r1, fmaf(w3[2], r2, acc[o])));
        }
      }
    }
  }
  const float bneps = rsqrtf(1.f + 1e-5f);
  int wv = t >> 6;
  #pragma unroll
  for (int o = 0; o < 32; ++o){
    int oc = g*32 + o;
    float val = fmaxf(fmaf(acc[o] + b2[oc], g2[oc]*bneps, bb2[oc]), 0.f);
    float s = wave_sum(val);
    if ((t & 63) == 0) pr[wv][o] = s;
  }
  __syncthreads();
  if (t < 32){
    float s = pr[0][t] + pr[1][t] + pr[2][t] + pr[3][t];
    atomicAdd(&freq_acc[b*C2OUT + g*32 + t], s);
  }
}

// RGB head + concat + 3-layer MLP, one block per batch sample.
__global__ __launch_bounds__(256) void k_mlp(const float* __restrict__ rgbmean,
    const float* __restrict__ freq_acc, const float* __restrict__ w_rgb,
    const float* __restrict__ b_rgb, const float* __restrict__ fc1w,
    const float* __restrict__ fc1b, const float* __restrict__ fc2w,
    const float* __restrict__ fc2b, const float* __restrict__ fc3w,
    const float* __restrict__ fc3b, float* __restrict__ out){
  __shared__ float z[130], z1[256], z2[128];
  int b = blockIdx.x, t = threadIdx.x;
  if (t < 2){
    float s = b_rgb[t];
    #pragma unroll
    for (int c = 0; c < 3; ++c) s += rgbmean[b*3 + c] * w_rgb[c*2 + t];
    z[t] = s;
  }
  if (t < 128) z[2 + t] = freq_acc[b*C2OUT + t] * (1.f/9216.f);
  __syncthreads();
  { float s = fc1b[t];
    for (int k = 0; k < 130; ++k) s = fmaf(z[k], fc1w[k*256 + t], s);
    z1[t] = fmaxf(s, 0.f); }
  __syncthreads();
  if (t < 128){
    float s = fc2b[t];
    for (int k = 0; k < 256; ++k) s = fmaf(z1[k], fc2w[k*128 + t], s);
    z2[t] = fmaxf(s, 0.f); }
  __syncthreads();
  if (t < 2){
    float s = fc3b[t];
    for (int k = 0; k < 128; ++k) s = fmaf(z2[k], fc3w[k*2 + t], s);
    out[b*2 + t] = s; }
}

extern "C" void kernel_launch(void* const* d_in, const int* in_sizes, int n_in,
                              void* d_out, int out_size, void* d_ws, size_t ws_size,
                              hipStream_t stream){
  const float* x     = (const float*)d_in[0];
  const float* w_rgb = (const float*)d_in[1];
  const float* b_rgb = (const float*)d_in[2];
  const float* w1    = (const float*)d_in[3];
  const float* b1    = (const float*)d_in[4];
  const float* g1    = (const float*)d_in[5];
  const float* bb1   = (const float*)d_in[6];
  const float* w2    = (const float*)d_in[7];
  const float* b2    = (const float*)d_in[8];
  const float* g2    = (const float*)d_in[9];
  const float* bb2   = (const float*)d_in[10];
  const float* fc1w  = (const float*)d_in[11];
  const float* fc1b  = (const float*)d_in[12];
  const float* fc2w  = (const float*)d_in[13];
  const float* fc2b  = (const float*)d_in[14];
  const float* fc3w  = (const float*)d_in[15];
  const float* fc3b  = (const float*)d_in[16];

  const bool full = (ws_size >= NEED_F);
  const int nloop = full ? 1 : 4;
  const int dftCH = full ? 96 : 24;        // channels per dft pass
  const int convB = full ? 32 : 8;         // images per conv pass

  char* ws = (char*)d_ws;
  float2* T  = (float2*)(ws + OFF_T);
  float*  Bm = (float*)(ws + OFF_B);
  float2* A  = (float2*)(ws + OFF_S);      // scratch: A then D (time-shared)
  float*  D  = (float*)(ws + OFF_S);
  float*  sm = (float*)(ws + (full ? OFF_SM_F : OFF_SM_C));
  float* rgbsum = sm;            // 96
  float* stats  = sm + 96;       // 192
  float* freqa  = sm + 288;      // 4096
  float* rgbm   = sm + 4384;     // 96
  float* ssb    = sm + 4480;     // 192

  hipMemsetAsync(sm, 0, 4672*sizeof(float), stream);
  k_twiddle<<<(NS*NS + 255)/256, 256, 0, stream>>>(T);
  for (int c = 0; c < nloop; ++c){
    k_dft_rows<<<dftCH*48, 192, 0, stream>>>(x, T, A, rgbsum, c*dftCH);
    k_dft_cols<<<dftCH*25, 192, 0, stream>>>(A, T, Bm, stats, c*dftCH);
  }
  k_finalize<<<1, 128, 0, stream>>>(stats, rgbsum, ssb, rgbm);
  for (int c = 0; c < nloop; ++c){
    k_conv1pool<<<convB*36, 256, 0, stream>>>(Bm, ssb, w1, b1, g1, bb1, D, c*convB);
    k_conv2pool<<<convB*144, 256, 0, stream>>>(D, w2, b2, g2, bb2, freqa, c*convB);
  }
  k_mlp<<<NB, 256, 0, stream>>>(rgbm, freqa, w_rgb, b_rgb, fc1w, fc1b,
                                fc2w, fc2b, fc3w, fc3b, (float*)d_out);
}

// Round 7
// 1979.077 us; speedup vs baseline: 4.6103x; 1.2897x over previous
//
#include <hip/hip_runtime.h>
#include <math.h>

// Problem dims
#define NB    32
#define NC    3
#define NIMG  (NB*NC)      // 96 image-channels
#define NS    384
#define HWSZ  (NS*NS)      // 147456
#define C1OUT 64
#define C1DIM 192
#define PDIM  96
#define PHW   (PDIM*PDIM)  // 9216
#define C2OUT 128
#define KWH   193          // stored half-spectrum width (kw = 0..192)
#define PI_F  3.14159265358979323846f

// ---- workspace layout (bytes) ----
// T: float2[384][384] twiddle table        =  1,179,648  @ 0
// B: float [96][384][384] shifted log-mag  = 56,623,104  @ OFF_B
// S: scratch (time-shared):                              @ OFF_S
//   dft phase : A float2[96][384][193] = 56,918,016 (full) / [24] = 14,229,504 (chunked)
//   conv phase: E bf16[8][64][192][192] = 37,748,736 + D f32[8][64][96][96] = 18,874,368 (full)
//               E bf16[2][...] = 9,437,184 + D f32[2][...] = 4,718,592 (chunked)
//   w1p bf16[64][192] = 24,576 placed after A (written post-dft, pre-conv)
// smalls: rgbsum[96] stats[192] freqacc[4096] rgbmean[96] ss[192] = 18,688 B
static const size_t OFF_T    = 0;
static const size_t OFF_B    = 1179648;
static const size_t OFF_S    = 57802752;
static const size_t OFF_SM_F = 133300224;
static const size_t OFF_SM_C = 76677120;
static const size_t NEED_F   = 133318912;
// conv-phase offsets within S:
static const size_t OFF_E    = 0;           // E at S
static const size_t OFF_D_F  = 37748736;    // full: after E8
static const size_t OFF_D_C  = 9437184;     // chunked: after E2
static const size_t OFF_W_F  = 57016320;    // after A-full(56,918,016)
static const size_t OFF_W_C  = 14229504;    // after A-chunk

typedef __attribute__((ext_vector_type(8))) short bf16x8_t;
typedef __attribute__((ext_vector_type(4))) float f32x4_t;
union U16 { unsigned u[4]; uint4 q; bf16x8_t v; };

__device__ __forceinline__ float wave_sum(float v){
  #pragma unroll
  for (int off = 32; off; off >>= 1) v += __shfl_down(v, off);
  return v;
}

// round-to-nearest-even f32 -> bf16
__device__ __forceinline__ unsigned short f2bf(float f){
  unsigned u = __float_as_uint(f);
  u += 0x7FFFu + ((u >> 16) & 1u);
  return (unsigned short)(u >> 16);
}
__device__ __forceinline__ float bf2f(unsigned short h){
  return __uint_as_float(((unsigned)h) << 16);
}

// proper mod-384 for v in [0, 768): NOT "& 383" (384 not a power of two).
__device__ __forceinline__ int mod384(int v){ return v >= NS ? v - NS : v; }

// Twiddle table: T[k][n] = exp(-2*pi*i*(k*n mod 384)/384). Exact int reduction.
__global__ void k_twiddle(float2* __restrict__ T){
  int idx = blockIdx.x*256 + (int)threadIdx.x;
  if (idx >= NS*NS) return;
  int k = idx / NS, n = idx - k*NS;
  int m = (k*n) % NS;
  float ang = -2.0f*PI_F*(float)m/(float)NS;
  T[idx] = make_float2(cosf(ang), sinf(ang));
}

// Row DFT (along W, real input). 8 rows/block; Nyquist via alternating sum.
__global__ __launch_bounds__(192) void k_dft_rows(const float* __restrict__ x,
    const float2* __restrict__ T, float2* __restrict__ A,
    float* __restrict__ rgbsum, int bc0){
  __shared__ float xr[8*NS];
  __shared__ float rs[3];
  int blk = blockIdx.x;
  int bcl = blk / 48, rg = blk % 48;
  int bc = bc0 + bcl;
  int t = threadIdx.x;
  const float* xp = x + (size_t)bc*HWSZ + (size_t)rg*8*NS;
  float lsum = 0.f;
  #pragma unroll
  for (int i = 0; i < 16; ++i){
    int lin = i*192 + t;
    float v = xp[lin];
    xr[lin] = v;
    lsum += v;
  }
  float ws = wave_sum(lsum);
  if ((t & 63) == 0) rs[t >> 6] = ws;
  __syncthreads();
  if (t == 0) atomicAdd(&rgbsum[bc], rs[0] + rs[1] + rs[2]);

  float2 acc[8];
  float ny[8];
  #pragma unroll
  for (int r = 0; r < 8; ++r){ acc[r] = make_float2(0.f,0.f); ny[r] = 0.f; }
  for (int n = 0; n < NS; ++n){
    float2 tw = T[n*NS + t];
    float sg = (n & 1) ? -1.f : 1.f;
    #pragma unroll
    for (int r = 0; r < 8; ++r){
      float xv = xr[r*NS + n];
      acc[r].x = fmaf(xv, tw.x, acc[r].x);
      acc[r].y = fmaf(xv, tw.y, acc[r].y);
      ny[r]    = fmaf(xv, sg,   ny[r]);
    }
  }
  #pragma unroll
  for (int r = 0; r < 8; ++r){
    size_t base = ((size_t)bcl*NS + rg*8 + r)*KWH;
    A[base + t] = acc[r];
    if (t == 0) A[base + 192] = make_float2(ny[r], 0.f);
  }
}

// Column DFT for kw in [0,192] (8 cols/block), |.|, log1p, fftshift + mirror.
__global__ __launch_bounds__(192) void k_dft_cols(const float2* __restrict__ A,
    const float2* __restrict__ T, float* __restrict__ Bm,
    float* __restrict__ stats, int bc0){
  __shared__ float2 tile[NS][9];
  __shared__ float rs[6];
  int blk = blockIdx.x;
  int bcl = blk / 25, cg = blk % 25;
  int bc = bc0 + bcl;
  int kw0 = cg*8;
  int cols = (cg == 24) ? 1 : 8;
  int t = threadIdx.x;
  const float2* Al = A + (size_t)bcl*NS*KWH;
  if (cols == 8){
    #pragma unroll
    for (int i = 0; i < 16; ++i){
      int lin = i*192 + t;
      int h = lin >> 3, c = lin & 7;
      tile[h][c] = Al[(size_t)h*KWH + kw0 + c];
    }
  } else {
    for (int lin = t; lin < NS; lin += 192)
      tile[lin][0] = Al[(size_t)lin*KWH + kw0];
  }
  __syncthreads();
  float2 acc[8][2];
  #pragma unroll
  for (int c = 0; c < 8; ++c){ acc[c][0] = make_float2(0.f,0.f); acc[c][1] = make_float2(0.f,0.f); }
  for (int h = 0; h < NS; ++h){
    float2 t0 = T[h*NS + t];
    float2 t1 = T[h*NS + t + 192];
    #pragma unroll
    for (int c = 0; c < 8; ++c){
      if (c < cols){
        float2 a = tile[h][c];
        acc[c][0].x = fmaf(a.x, t0.x, fmaf(-a.y, t0.y, acc[c][0].x));
        acc[c][0].y = fmaf(a.x, t0.y, fmaf( a.y, t0.x, acc[c][0].y));
        acc[c][1].x = fmaf(a.x, t1.x, fmaf(-a.y, t1.y, acc[c][1].x));
        acc[c][1].y = fmaf(a.x, t1.y, fmaf( a.y, t1.x, acc[c][1].y));
      }
    }
  }
  float s1 = 0.f, s2 = 0.f;
  float* Bbc = Bm + (size_t)bc*HWSZ;
  #pragma unroll
  for (int c = 0; c < 8; ++c){
    if (c < cols){
      int kw = kw0 + c;
      #pragma unroll
      for (int kk = 0; kk < 2; ++kk){
        int kh = t + kk*192;
        float2 X = acc[c][kk];
        float mag = logf(sqrtf(X.x*X.x + X.y*X.y) + 1.f);
        int u = mod384(kh + 192);
        int v = mod384(kw + 192);
        Bbc[(size_t)u*NS + v] = mag;
        s1 += mag; s2 += mag*mag;
        if (kw >= 1 && kw <= 191){
          int kh2 = mod384(NS - kh);
          int u2 = mod384(kh2 + 192);
          int v2 = mod384(NS - kw + 192);
          Bbc[(size_t)u2*NS + v2] = mag;
          s1 += mag; s2 += mag*mag;
        }
      }
    }
  }
  float w1s = wave_sum(s1), w2s = wave_sum(s2);
  if ((t & 63) == 0){ rs[t >> 6] = w1s; rs[3 + (t >> 6)] = w2s; }
  __syncthreads();
  if (t == 0){
    atomicAdd(&stats[bc*2],     rs[0] + rs[1] + rs[2]);
    atomicAdd(&stats[bc*2 + 1], rs[3] + rs[4] + rs[5]);
  }
}

__global__ void k_finalize(const float* __restrict__ stats, const float* __restrict__ rgbsum,
                           float* __restrict__ ss, float* __restrict__ rgbmean){
  int t = threadIdx.x;
  if (t < NIMG){
    const float inv_n = 1.f / 147456.f;
    float mean = stats[t*2] * inv_n;
    float var  = fmaxf(stats[t*2 + 1] * inv_n - mean*mean, 0.f);
    float inv  = 1.f / (sqrtf(var) + 1e-8f);
    ss[t*2]     = inv;
    ss[t*2 + 1] = -mean * inv;
    rgbmean[t]  = rgbsum[t] * inv_n;
  }
}

// Pack conv1 weights to bf16 [64][192]: k' = (ic*7+kh)*8 + kw, kw==7 -> 0,
// k' >= 168 -> 0. 8-tap rows align with the MFMA lane k-slices.
__global__ void k_w1prep(const float* __restrict__ w1, unsigned short* __restrict__ w1p){
  int idx = blockIdx.x*256 + (int)threadIdx.x;
  if (idx >= 64*192) return;
  int oc = idx / 192, k = idx - oc*192;
  int rk = k >> 3, kw = k & 7;
  float val = 0.f;
  if (rk < 21 && kw < 7){
    int ic = rk / 7, kh = rk - 7*ic;
    val = w1[oc*147 + ic*49 + kh*7 + kw];
  }
  w1p[idx] = f2bf(val);
}

// conv1(7x7,s2,p3)+BN+ReLU via MFMA 16x16x32 bf16.
// Block = (image, 16 conv rows, 16 conv cols), 4 waves = 4 oc-tiles of 16.
// A (M=16 positions) from LDS patch; B (N=16 oc) from w1p; K' = 192 = 6 ksteps.
// Patch [3][37][40] bf16 = 8880 B, staged normalized+zero-padded.
__global__ __launch_bounds__(256) void k_conv1mfma(const float* __restrict__ Bm,
    const float* __restrict__ ss, const unsigned short* __restrict__ w1p,
    const float* __restrict__ b1, const float* __restrict__ g1,
    const float* __restrict__ bb1, unsigned short* __restrict__ E, int b0){
  __shared__ unsigned short pt[3*37*40];
  int blk = blockIdx.x;
  int li = blk / 144, rem = blk - li*144;
  int rg = rem / 12, cg = rem - rg*12;
  int r0 = rg*16, c0 = cg*16;
  int b = b0 + li;
  int t = threadIdx.x;
  float sc[3], sh[3];
  #pragma unroll
  for (int ic = 0; ic < 3; ++ic){ sc[ic] = ss[(b*3 + ic)*2]; sh[ic] = ss[(b*3 + ic)*2 + 1]; }
  const int h0 = 2*r0 - 3, w0 = 2*c0 - 3;
  const float* Bb = Bm + (size_t)b*3*HWSZ;
  for (int lin = t; lin < 3*37*40; lin += 256){
    int ic = lin / 1480; int r = lin - ic*1480;
    int hr = r / 40, wc = r - hr*40;
    int hg = h0 + hr, wg = w0 + wc;
    bool v = (wc < 38) && ((unsigned)hg < (unsigned)NS) && ((unsigned)wg < (unsigned)NS);
    float raw = v ? Bb[(size_t)ic*HWSZ + (size_t)hg*NS + wg] : 0.f;
    pt[lin] = v ? f2bf(fmaf(raw, sc[ic], sh[ic])) : (unsigned short)0;
  }
  __syncthreads();

  int wave = t >> 6, lane = t & 63;
  int lm = lane & 15, lg = lane >> 4;
  int oc = wave*16 + lm;
  // preload 6 B fragments (weights), 16B aligned global loads
  U16 bf[6];
  #pragma unroll
  for (int ks = 0; ks < 6; ++ks)
    bf[ks].q = *(const uint4*)(w1p + oc*192 + ks*32 + lg*8);
  // per-kstep patch row descriptors (lane-fixed)
  int cbase[6];
  #pragma unroll
  for (int ks = 0; ks < 6; ++ks){
    int rk = ks*4 + lg;
    if (rk > 20) rk = 20;                  // clamped rows pair with zero weights
    int ic = rk / 7, kh = rk - 7*ic;
    cbase[ks] = ic*1480 + kh*40 + 2*lm;    // + 80*rt per conv row
  }
  const float bneps = rsqrtf(1.f + 1e-5f);
  float bias = b1[oc];
  float gsc = g1[oc]*bneps, bbv = bb1[oc];
  unsigned short* Eb = E + (((size_t)li*C1OUT + oc)*C1DIM + r0)*C1DIM + c0 + lg*4;

  #pragma unroll 1
  for (int rt = 0; rt < 16; ++rt){
    f32x4_t acc = {bias, bias, bias, bias};
    #pragma unroll
    for (int ks = 0; ks < 6; ++ks){
      U16 a;
      const unsigned* pp = (const unsigned*)&pt[cbase[ks] + 80*rt];
      a.u[0] = pp[0]; a.u[1] = pp[1]; a.u[2] = pp[2]; a.u[3] = pp[3];
      acc = __builtin_amdgcn_mfma_f32_16x16x32_bf16(a.v, bf[ks].v, acc, 0, 0, 0);
    }
    ushort4 o;
    o.x = f2bf(fmaxf(fmaf(acc[0], gsc, bbv), 0.f));
    o.y = f2bf(fmaxf(fmaf(acc[1], gsc, bbv), 0.f));
    o.z = f2bf(fmaxf(fmaf(acc[2], gsc, bbv), 0.f));
    o.w = f2bf(fmaxf(fmaf(acc[3], gsc, bbv), 0.f));
    *(ushort4*)(Eb + (size_t)rt*C1DIM) = o;
  }
}

// maxpool 3x3 s2 p1 over E (bf16, >=0) -> D f32 [img][64][96][96]
__global__ __launch_bounds__(256) void k_pool(const unsigned short* __restrict__ E,
    float* __restrict__ D){
  __shared__ unsigned short sE[33][196];
  int blk = blockIdx.x;
  int li = blk / 384, rem = blk - li*384;
  int oc = rem / 6, band = rem - oc*6;
  int r0 = band*16;
  int t = threadIdx.x;
  const unsigned short* Ep = E + ((size_t)li*C1OUT + oc)*C1DIM*C1DIM;
  for (int lin = t; lin < 33*196; lin += 256){
    int rr = lin / 196, cc = lin - rr*196;
    int cr = 2*r0 - 1 + rr, gc = cc - 1;
    bool v = ((unsigned)cr < (unsigned)C1DIM) && ((unsigned)gc < (unsigned)C1DIM) && (cc < 195);
    sE[rr][cc] = v ? Ep[(size_t)cr*C1DIM + gc] : (unsigned short)0;
  }
  __syncthreads();
  float* Dp = D + ((size_t)li*C1OUT + oc)*PHW + (size_t)r0*PDIM;
  #pragma unroll
  for (int ii = 0; ii < 6; ++ii){
    int j = ii*256 + t;
    int pr = j / PDIM, pc = j - pr*PDIM;
    float mx = 0.f;
    #pragma unroll
    for (int dh = 0; dh < 3; ++dh)
      #pragma unroll
      for (int dw = 0; dw < 3; ++dw)
        mx = fmaxf(mx, bf2f(sE[2*pr + dh][2*pc + dw]));
    Dp[(size_t)pr*PDIM + pc] = mx;
  }
}

// conv2(3x3,p1)+BN+ReLU fused with global-average-pool (unchanged fp32 path).
__global__ __launch_bounds__(256) void k_conv2pool(const float* __restrict__ D,
    const float* __restrict__ w2, const float* __restrict__ b2,
    const float* __restrict__ g2, const float* __restrict__ bb2,
    float* __restrict__ freq_acc, int b0){
  __shared__ float sD[16][18][19];
  __shared__ float pr[4][32];
  int blk = blockIdx.x;
  int bl = blk / 144;
  int rem = blk - bl*144;
  int tile = rem >> 2, g = rem & 3;
  int b = b0 + bl;
  int t = threadIdx.x;
  int oh0 = (tile / 6) * 16, ow0 = (tile % 6) * 16;
  int ol = t >> 4, wl = t & 15;
  const float* Db = D + (size_t)bl*C1OUT*PHW;
  float acc[32];
  #pragma unroll
  for (int o = 0; o < 32; ++o) acc[o] = 0.f;
  #pragma unroll 1
  for (int icc = 0; icc < 4; ++icc){
    __syncthreads();
    for (int lin = t; lin < 16*18*18; lin += 256){
      int ic = lin / 324; int r = lin - ic*324;
      int h = r / 18, w = r - h*18;
      int hg = oh0 - 1 + h, wg = ow0 - 1 + w;
      bool v = ((unsigned)hg < (unsigned)PDIM) && ((unsigned)wg < (unsigned)PDIM);
      sD[ic][h][w] = v ? Db[(size_t)(icc*16 + ic)*PHW + (size_t)hg*PDIM + wg] : 0.f;
    }
    __syncthreads();
    #pragma unroll 1
    for (int i = 0; i < 16; ++i){
      #pragma unroll
      for (int kh = 0; kh < 3; ++kh){
        const float* row = &sD[i][ol + kh][wl];
        float r0 = row[0], r1 = row[1], r2 = row[2];
        const float* wp = w2 + (size_t)(g*32)*576 + (icc*16 + i)*9 + kh*3;
        #pragma unroll
        for (int o = 0; o < 32; ++o){
          const float* w3 = wp + o*576;
          acc[o] = fmaf(w3[0], r0, fmaf(w3[1], r1, fmaf(w3[2], r2, acc[o])));
        }
      }
    }
  }
  const float bneps = rsqrtf(1.f + 1e-5f);
  int wv = t >> 6;
  #pragma unroll
  for (int o = 0; o < 32; ++o){
    int oc = g*32 + o;
    float val = fmaxf(fmaf(acc[o] + b2[oc], g2[oc]*bneps, bb2[oc]), 0.f);
    float s = wave_sum(val);
    if ((t & 63) == 0) pr[wv][o] = s;
  }
  __syncthreads();
  if (t < 32){
    float s = pr[0][t] + pr[1][t] + pr[2][t] + pr[3][t];
    atomicAdd(&freq_acc[b*C2OUT + g*32 + t], s);
  }
}

// RGB head + concat + 3-layer MLP, one block per batch sample.
__global__ __launch_bounds__(256) void k_mlp(const float* __restrict__ rgbmean,
    const float* __restrict__ freq_acc, const float* __restrict__ w_rgb,
    const float* __restrict__ b_rgb, const float* __restrict__ fc1w,
    const float* __restrict__ fc1b, const float* __restrict__ fc2w,
    const float* __restrict__ fc2b, const float* __restrict__ fc3w,
    const float* __restrict__ fc3b, float* __restrict__ out){
  __shared__ float z[130], z1[256], z2[128];
  int b = blockIdx.x, t = threadIdx.x;
  if (t < 2){
    float s = b_rgb[t];
    #pragma unroll
    for (int c = 0; c < 3; ++c) s += rgbmean[b*3 + c] * w_rgb[c*2 + t];
    z[t] = s;
  }
  if (t < 128) z[2 + t] = freq_acc[b*C2OUT + t] * (1.f/9216.f);
  __syncthreads();
  { float s = fc1b[t];
    for (int k = 0; k < 130; ++k) s = fmaf(z[k], fc1w[k*256 + t], s);
    z1[t] = fmaxf(s, 0.f); }
  __syncthreads();
  if (t < 128){
    float s = fc2b[t];
    for (int k = 0; k < 256; ++k) s = fmaf(z1[k], fc2w[k*128 + t], s);
    z2[t] = fmaxf(s, 0.f); }
  __syncthreads();
  if (t < 2){
    float s = fc3b[t];
    for (int k = 0; k < 128; ++k) s = fmaf(z2[k], fc3w[k*2 + t], s);
    out[b*2 + t] = s; }
}

extern "C" void kernel_launch(void* const* d_in, const int* in_sizes, int n_in,
                              void* d_out, int out_size, void* d_ws, size_t ws_size,
                              hipStream_t stream){
  const float* x     = (const float*)d_in[0];
  const float* w_rgb = (const float*)d_in[1];
  const float* b_rgb = (const float*)d_in[2];
  const float* w1    = (const float*)d_in[3];
  const float* b1    = (const float*)d_in[4];
  const float* g1    = (const float*)d_in[5];
  const float* bb1   = (const float*)d_in[6];
  const float* w2    = (const float*)d_in[7];
  const float* b2    = (const float*)d_in[8];
  const float* g2    = (const float*)d_in[9];
  const float* bb2   = (const float*)d_in[10];
  const float* fc1w  = (const float*)d_in[11];
  const float* fc1b  = (const float*)d_in[12];
  const float* fc2w  = (const float*)d_in[13];
  const float* fc2b  = (const float*)d_in[14];
  const float* fc3w  = (const float*)d_in[15];
  const float* fc3b  = (const float*)d_in[16];

  const bool full = (ws_size >= NEED_F);
  const int dftloop = full ? 1 : 4;
  const int dftCH   = full ? 96 : 24;
  const int cvloop  = full ? 4 : 16;       // conv chunks
  const int cvB     = full ? 8 : 2;        // images per conv chunk

  char* ws = (char*)d_ws;
  float2* T  = (float2*)(ws + OFF_T);
  float*  Bm = (float*)(ws + OFF_B);
  float2* A  = (float2*)(ws + OFF_S);
  unsigned short* E   = (unsigned short*)(ws + OFF_S + OFF_E);
  float*          D   = (float*)(ws + OFF_S + (full ? OFF_D_F : OFF_D_C));
  unsigned short* w1p = (unsigned short*)(ws + OFF_S + (full ? OFF_W_F : OFF_W_C));
  float*  sm = (float*)(ws + (full ? OFF_SM_F : OFF_SM_C));
  float* rgbsum = sm;            // 96
  float* stats  = sm + 96;       // 192
  float* freqa  = sm + 288;      // 4096
  float* rgbm   = sm + 4384;     // 96
  float* ssb    = sm + 4480;     // 192

  hipMemsetAsync(sm, 0, 4672*sizeof(float), stream);
  k_twiddle<<<(NS*NS + 255)/256, 256, 0, stream>>>(T);
  for (int c = 0; c < dftloop; ++c){
    k_dft_rows<<<dftCH*48, 192, 0, stream>>>(x, T, A, rgbsum, c*dftCH);
    k_dft_cols<<<dftCH*25, 192, 0, stream>>>(A, T, Bm, stats, c*dftCH);
  }
  k_finalize<<<1, 128, 0, stream>>>(stats, rgbsum, ssb, rgbm);
  k_w1prep<<<48, 256, 0, stream>>>(w1, w1p);   // after dft (w1p region overlays A tail)
  for (int c = 0; c < cvloop; ++c){
    k_conv1mfma<<<cvB*144, 256, 0, stream>>>(Bm, ssb, w1p, b1, g1, bb1, E, c*cvB);
    k_pool<<<cvB*384, 256, 0, stream>>>(E, D);
    k_conv2pool<<<cvB*144, 256, 0, stream>>>(D, w2, b2, g2, bb2, freqa, c*cvB);
  }
  k_mlp<<<NB, 256, 0, stream>>>(rgbm, freqa, w_rgb, b_rgb, fc1w, fc1b,
                                fc2w, fc2b, fc3w, fc3b, (float*)d_out);
}

// Round 8
// 1514.468 us; speedup vs baseline: 6.0246x; 1.3068x over previous
//
#include <hip/hip_runtime.h>
#include <math.h>

// Problem dims
#define NB    32
#define NC    3
#define NIMG  (NB*NC)      // 96 image-channels
#define NS    384
#define HWSZ  (NS*NS)      // 147456
#define C1OUT 64
#define C1DIM 192
#define PDIM  96
#define PHW   (PDIM*PDIM)  // 9216
#define C2OUT 128
#define KWH   193          // stored half-spectrum width (kw = 0..192)
#define PI_F  3.14159265358979323846f

// ---- workspace layout (bytes) ----  (identical to round 7)
static const size_t OFF_T    = 0;
static const size_t OFF_B    = 1179648;
static const size_t OFF_S    = 57802752;
static const size_t OFF_SM_F = 133300224;
static const size_t OFF_SM_C = 76677120;
static const size_t NEED_F   = 133318912;
static const size_t OFF_E    = 0;
static const size_t OFF_D_F  = 37748736;
static const size_t OFF_D_C  = 9437184;
static const size_t OFF_W_F  = 57016320;
static const size_t OFF_W_C  = 14229504;

typedef __attribute__((ext_vector_type(8))) short bf16x8_t;
typedef __attribute__((ext_vector_type(4))) float f32x4_t;
union U16 { unsigned u[4]; uint4 q; bf16x8_t v; };

__device__ __forceinline__ float wave_sum(float v){
  #pragma unroll
  for (int off = 32; off; off >>= 1) v += __shfl_down(v, off);
  return v;
}
__device__ __forceinline__ unsigned short f2bf(float f){
  unsigned u = __float_as_uint(f);
  u += 0x7FFFu + ((u >> 16) & 1u);
  return (unsigned short)(u >> 16);
}
__device__ __forceinline__ float bf2f(unsigned short h){
  return __uint_as_float(((unsigned)h) << 16);
}
// proper mod-384 for v in [0, 768): NOT "& 383" (384 not a power of two).
__device__ __forceinline__ int mod384(int v){ return v >= NS ? v - NS : v; }
__device__ __forceinline__ float2 cmul(float2 a, float2 b){
  return make_float2(a.x*b.x - a.y*b.y, a.x*b.y + a.y*b.x);
}

// Twiddle table: T[k][n] = exp(-2*pi*i*(k*n mod 384)/384). Exact int reduction.
// FFT kernels use row k=1 (T+384): W384^m = Trow[m].
__global__ void k_twiddle(float2* __restrict__ T){
  int idx = blockIdx.x*256 + (int)threadIdx.x;
  if (idx >= NS*NS) return;
  int k = idx / NS, n = idx - k*NS;
  int m = (k*n) % NS;
  float ang = -2.0f*PI_F*(float)m/(float)NS;
  T[idx] = make_float2(cosf(ang), sinf(ang));
}

// ---- 384-pt FFT pieces: 384 = 3 x 128.  x[n], n = 3*n1 + r ->
// Y_r = FFT128 of x[3*n1+r] (DIT, bit-reversed input, W128 = W384^3);
// X[k] = Y0[k%128] + W384^k Y1[k%128] + W384^{2k} Y2[k%128].
// (This structure passed the r1-vs-r2 bit-identity forensic check.)

// Row FFT (along W, real input): 8 rows/block as 4 packed complex FFTs.
// Unpack: row even = (Z[k]+conj(Z[-k]))/2, row odd = -i(Z[k]-conj(Z[-k]))/2.
// Writes A[bc][h][kw], kw in [0,192]. Also rgb pixel sums.
__global__ __launch_bounds__(192) void k_dft_rows(const float* __restrict__ x,
    const float2* __restrict__ T, float2* __restrict__ A,
    float* __restrict__ rgbsum, int bc0){
  __shared__ float2 work[4][384];
  __shared__ float rs[3];
  const float2* Trow = T + NS;             // W384^m
  int blk = blockIdx.x;
  int bcl = blk / 48, rg = blk % 48;       // local channel, 8-row group
  int bc = bc0 + bcl;
  int t = threadIdx.x;
  const float* xp = x + (size_t)bc*HWSZ + (size_t)rg*8*NS;
  // scatter indices for n = t and n = t+192
  int nA = t,        rA = nA % 3, iA = (rA*128) + (__brev((unsigned)(nA/3)) >> 25);
  int nB = t + 192,  rB = nB % 3, iB = (rB*128) + (__brev((unsigned)(nB/3)) >> 25);
  float lsum = 0.f;
  #pragma unroll
  for (int c = 0; c < 4; ++c){
    float a0 = xp[(2*c)*NS + nA],   b0 = xp[(2*c+1)*NS + nA];
    float a1 = xp[(2*c)*NS + nB],   b1 = xp[(2*c+1)*NS + nB];
    work[c][iA] = make_float2(a0, b0);
    work[c][iB] = make_float2(a1, b1);
    lsum += a0 + b0 + a1 + b1;
  }
  float ws = wave_sum(lsum);
  if ((t & 63) == 0) rs[t >> 6] = ws;
  __syncthreads();
  if (t == 0) atomicAdd(&rgbsum[bc], rs[0] + rs[1] + rs[2]);

  int sub = t >> 6, j = t & 63;            // 3 sub-FFTs x 64 butterflies
  #pragma unroll
  for (int st = 0; st < 7; ++st){
    int half = 1 << st;
    int pos = j & (half - 1);
    int ia = sub*128 + (((j >> st) << (st + 1)) | pos);
    int ib = ia + half;
    float2 tw = Trow[(192 >> st) * pos];   // W_{2*half}^pos exact
    #pragma unroll
    for (int c = 0; c < 4; ++c){
      float2 a = work[c][ia], b = cmul(work[c][ib], tw);
      work[c][ia] = make_float2(a.x + b.x, a.y + b.y);
      work[c][ib] = make_float2(a.x - b.x, a.y - b.y);
    }
    __syncthreads();
  }
  // combine: X[t] and X[t+192];  W^(k+192) = -W^k, W^(2(k+192)) = W^(2k)
  int k1a = t & 127, k1b = (t + 192) & 127;
  float2 w1 = Trow[t], w2 = Trow[(2*t) % 384];
  float2 Xa[4], Xb[4];
  #pragma unroll
  for (int c = 0; c < 4; ++c){
    float2 p1 = cmul(w1, work[c][128 + k1a]);
    float2 p2 = cmul(w2, work[c][256 + k1a]);
    float2 y0 = work[c][k1a];
    Xa[c] = make_float2(y0.x + p1.x + p2.x, y0.y + p1.y + p2.y);
    float2 q1 = cmul(w1, work[c][128 + k1b]);
    float2 q2 = cmul(w2, work[c][256 + k1b]);
    float2 z0 = work[c][k1b];
    Xb[c] = make_float2(z0.x - q1.x + q2.x, z0.y - q1.y + q2.y);
  }
  __syncthreads();                         // done reading Y
  #pragma unroll
  for (int c = 0; c < 4; ++c){ work[c][t] = Xa[c]; work[c][t + 192] = Xb[c]; }
  __syncthreads();
  // unpack two real rows, write kw in [0,192]
  int tm = (t == 0) ? 0 : (384 - t);
  #pragma unroll
  for (int c = 0; c < 4; ++c){
    float2 Zk = Xa[c];
    float2 Zm = work[c][tm];
    size_t b0r = ((size_t)bcl*NS + rg*8 + 2*c)*KWH;
    size_t b1r = b0r + KWH;
    A[b0r + t] = make_float2(0.5f*(Zk.x + Zm.x), 0.5f*(Zk.y - Zm.y));
    A[b1r + t] = make_float2(0.5f*(Zk.y + Zm.y), 0.5f*(Zm.x - Zk.x));
    if (t == 0){
      float2 Zn = Xb[c];                   // X[192]; conj-sym -> real parts
      A[b0r + 192] = make_float2(Zn.x, 0.f);
      A[b1r + 192] = make_float2(Zn.y, 0.f);
    }
  }
}

// Column FFT (along H) for kw in [0,192], 8 columns/block batched through
// shared butterfly stages. Epilogue (mag/log1p/fftshift/mirror/stats) is
// byte-identical math to the verified round-7 DFT kernel.
__global__ __launch_bounds__(192) void k_dft_cols(const float2* __restrict__ A,
    const float2* __restrict__ T, float* __restrict__ Bm,
    float* __restrict__ stats, int bc0){
  __shared__ float2 work[8][384];
  __shared__ float rs[6];
  const float2* Trow = T + NS;
  int blk = blockIdx.x;
  int bcl = blk / 25, cg = blk % 25;
  int bc = bc0 + bcl;
  int kw0 = cg*8;
  int cols = (cg == 24) ? 1 : 8;           // 193 = 24*8 + 1
  int t = threadIdx.x;
  const float2* Al = A + (size_t)bcl*NS*KWH;
  if (cols == 8){
    #pragma unroll
    for (int i = 0; i < 16; ++i){
      int lin = i*192 + t;
      int h = lin >> 3, c = lin & 7;
      int r = h % 3;
      work[c][r*128 + (__brev((unsigned)(h/3)) >> 25)] = Al[(size_t)h*KWH + kw0 + c];
    }
  } else {
    for (int h = t; h < NS; h += 192){
      int r = h % 3;
      work[0][r*128 + (__brev((unsigned)(h/3)) >> 25)] = Al[(size_t)h*KWH + kw0];
    }
  }
  __syncthreads();
  int sub = t >> 6, j = t & 63;
  #pragma unroll
  for (int st = 0; st < 7; ++st){
    int half = 1 << st;
    int pos = j & (half - 1);
    int ia = sub*128 + (((j >> st) << (st + 1)) | pos);
    int ib = ia + half;
    float2 tw = Trow[(192 >> st) * pos];
    #pragma unroll
    for (int c = 0; c < 8; ++c){
      if (c < cols){
        float2 a = work[c][ia], b = cmul(work[c][ib], tw);
        work[c][ia] = make_float2(a.x + b.x, a.y + b.y);
        work[c][ib] = make_float2(a.x - b.x, a.y - b.y);
      }
    }
    __syncthreads();
  }
  // combine + epilogue per column
  int k1a = t & 127, k1b = (t + 192) & 127;
  float2 w1 = Trow[t], w2 = Trow[(2*t) % 384];
  float s1 = 0.f, s2 = 0.f;
  float* Bbc = Bm + (size_t)bc*HWSZ;
  #pragma unroll
  for (int c = 0; c < 8; ++c){
    if (c < cols){
      float2 p1 = cmul(w1, work[c][128 + k1a]);
      float2 p2 = cmul(w2, work[c][256 + k1a]);
      float2 y0 = work[c][k1a];
      float2 Xa = make_float2(y0.x + p1.x + p2.x, y0.y + p1.y + p2.y);
      float2 q1 = cmul(w1, work[c][128 + k1b]);
      float2 q2 = cmul(w2, work[c][256 + k1b]);
      float2 z0 = work[c][k1b];
      float2 Xb = make_float2(z0.x - q1.x + q2.x, z0.y - q1.y + q2.y);
      int kw = kw0 + c;
      #pragma unroll
      for (int kk = 0; kk < 2; ++kk){
        int kh = t + kk*192;
        float2 X = kk ? Xb : Xa;
        float mag = logf(sqrtf(X.x*X.x + X.y*X.y) + 1.f);
        int u = mod384(kh + 192);          // shifted H index
        int v = mod384(kw + 192);          // shifted W index
        Bbc[(size_t)u*NS + v] = mag;
        s1 += mag; s2 += mag*mag;
        if (kw >= 1 && kw <= 191){         // conj mirror -> kw2 in [193,383]
          int kh2 = mod384(NS - kh);
          int u2 = mod384(kh2 + 192);
          int v2 = mod384(NS - kw + 192);  // = 192 - kw
          Bbc[(size_t)u2*NS + v2] = mag;
          s1 += mag; s2 += mag*mag;
        }
      }
    }
  }
  float w1s = wave_sum(s1), w2s = wave_sum(s2);
  if ((t & 63) == 0){ rs[t >> 6] = w1s; rs[3 + (t >> 6)] = w2s; }
  __syncthreads();
  if (t == 0){
    atomicAdd(&stats[bc*2],     rs[0] + rs[1] + rs[2]);
    atomicAdd(&stats[bc*2 + 1], rs[3] + rs[4] + rs[5]);
  }
}

__global__ void k_finalize(const float* __restrict__ stats, const float* __restrict__ rgbsum,
                           float* __restrict__ ss, float* __restrict__ rgbmean){
  int t = threadIdx.x;
  if (t < NIMG){
    const float inv_n = 1.f / 147456.f;
    float mean = stats[t*2] * inv_n;
    float var  = fmaxf(stats[t*2 + 1] * inv_n - mean*mean, 0.f);
    float inv  = 1.f / (sqrtf(var) + 1e-8f);
    ss[t*2]     = inv;
    ss[t*2 + 1] = -mean * inv;
    rgbmean[t]  = rgbsum[t] * inv_n;
  }
}

// Pack conv1 weights to bf16 [64][192]: k' = (ic*7+kh)*8 + kw, kw==7 -> 0,
// k' >= 168 -> 0.
__global__ void k_w1prep(const float* __restrict__ w1, unsigned short* __restrict__ w1p){
  int idx = blockIdx.x*256 + (int)threadIdx.x;
  if (idx >= 64*192) return;
  int oc = idx / 192, k = idx - oc*192;
  int rk = k >> 3, kw = k & 7;
  float val = 0.f;
  if (rk < 21 && kw < 7){
    int ic = rk / 7, kh = rk - 7*ic;
    val = w1[oc*147 + ic*49 + kh*7 + kw];
  }
  w1p[idx] = f2bf(val);
}

// conv1(7x7,s2,p3)+BN+ReLU via MFMA 16x16x32 bf16 (unchanged from round 7).
__global__ __launch_bounds__(256) void k_conv1mfma(const float* __restrict__ Bm,
    const float* __restrict__ ss, const unsigned short* __restrict__ w1p,
    const float* __restrict__ b1, const float* __restrict__ g1,
    const float* __restrict__ bb1, unsigned short* __restrict__ E, int b0){
  __shared__ unsigned short pt[3*37*40];
  int blk = blockIdx.x;
  int li = blk / 144, rem = blk - li*144;
  int rg = rem / 12, cg = rem - rg*12;
  int r0 = rg*16, c0 = cg*16;
  int b = b0 + li;
  int t = threadIdx.x;
  float sc[3], sh[3];
  #pragma unroll
  for (int ic = 0; ic < 3; ++ic){ sc[ic] = ss[(b*3 + ic)*2]; sh[ic] = ss[(b*3 + ic)*2 + 1]; }
  const int h0 = 2*r0 - 3, w0 = 2*c0 - 3;
  const float* Bb = Bm + (size_t)b*3*HWSZ;
  for (int lin = t; lin < 3*37*40; lin += 256){
    int ic = lin / 1480; int r = lin - ic*1480;
    int hr = r / 40, wc = r - hr*40;
    int hg = h0 + hr, wg = w0 + wc;
    bool v = (wc < 38) && ((unsigned)hg < (unsigned)NS) && ((unsigned)wg < (unsigned)NS);
    float raw = v ? Bb[(size_t)ic*HWSZ + (size_t)hg*NS + wg] : 0.f;
    pt[lin] = v ? f2bf(fmaf(raw, sc[ic], sh[ic])) : (unsigned short)0;
  }
  __syncthreads();

  int wave = t >> 6, lane = t & 63;
  int lm = lane & 15, lg = lane >> 4;
  int oc = wave*16 + lm;
  U16 bf[6];
  #pragma unroll
  for (int ks = 0; ks < 6; ++ks)
    bf[ks].q = *(const uint4*)(w1p + oc*192 + ks*32 + lg*8);
  int cbase[6];
  #pragma unroll
  for (int ks = 0; ks < 6; ++ks){
    int rk = ks*4 + lg;
    if (rk > 20) rk = 20;
    int ic = rk / 7, kh = rk - 7*ic;
    cbase[ks] = ic*1480 + kh*40 + 2*lm;
  }
  const float bneps = rsqrtf(1.f + 1e-5f);
  float bias = b1[oc];
  float gsc = g1[oc]*bneps, bbv = bb1[oc];
  unsigned short* Eb = E + (((size_t)li*C1OUT + oc)*C1DIM + r0)*C1DIM + c0 + lg*4;

  #pragma unroll 1
  for (int rt = 0; rt < 16; ++rt){
    f32x4_t acc = {bias, bias, bias, bias};
    #pragma unroll
    for (int ks = 0; ks < 6; ++ks){
      U16 a;
      const unsigned* pp = (const unsigned*)&pt[cbase[ks] + 80*rt];
      a.u[0] = pp[0]; a.u[1] = pp[1]; a.u[2] = pp[2]; a.u[3] = pp[3];
      acc = __builtin_amdgcn_mfma_f32_16x16x32_bf16(a.v, bf[ks].v, acc, 0, 0, 0);
    }
    ushort4 o;
    o.x = f2bf(fmaxf(fmaf(acc[0], gsc, bbv), 0.f));
    o.y = f2bf(fmaxf(fmaf(acc[1], gsc, bbv), 0.f));
    o.z = f2bf(fmaxf(fmaf(acc[2], gsc, bbv), 0.f));
    o.w = f2bf(fmaxf(fmaf(acc[3], gsc, bbv), 0.f));
    *(ushort4*)(Eb + (size_t)rt*C1DIM) = o;
  }
}

// maxpool 3x3 s2 p1 over E (bf16, >=0) -> D f32
__global__ __launch_bounds__(256) void k_pool(const unsigned short* __restrict__ E,
    float* __restrict__ D){
  __shared__ unsigned short sE[33][196];
  int blk = blockIdx.x;
  int li = blk / 384, rem = blk - li*384;
  int oc = rem / 6, band = rem - oc*6;
  int r0 = band*16;
  int t = threadIdx.x;
  const unsigned short* Ep = E + ((size_t)li*C1OUT + oc)*C1DIM*C1DIM;
  for (int lin = t; lin < 33*196; lin += 256){
    int rr = lin / 196, cc = lin - rr*196;
    int cr = 2*r0 - 1 + rr, gc = cc - 1;
    bool v = ((unsigned)cr < (unsigned)C1DIM) && ((unsigned)gc < (unsigned)C1DIM) && (cc < 195);
    sE[rr][cc] = v ? Ep[(size_t)cr*C1DIM + gc] : (unsigned short)0;
  }
  __syncthreads();
  float* Dp = D + ((size_t)li*C1OUT + oc)*PHW + (size_t)r0*PDIM;
  #pragma unroll
  for (int ii = 0; ii < 6; ++ii){
    int j = ii*256 + t;
    int pr = j / PDIM, pc = j - pr*PDIM;
    float mx = 0.f;
    #pragma unroll
    for (int dh = 0; dh < 3; ++dh)
      #pragma unroll
      for (int dw = 0; dw < 3; ++dw)
        mx = fmaxf(mx, bf2f(sE[2*pr + dh][2*pc + dw]));
    Dp[(size_t)pr*PDIM + pc] = mx;
  }
}

// conv2(3x3,p1)+BN+ReLU fused with global-average-pool (fp32, unchanged).
__global__ __launch_bounds__(256) void k_conv2pool(const float* __restrict__ D,
    const float* __restrict__ w2, const float* __restrict__ b2,
    const float* __restrict__ g2, const float* __restrict__ bb2,
    float* __restrict__ freq_acc, int b0){
  __shared__ float sD[16][18][19];
  __shared__ float pr[4][32];
  int blk = blockIdx.x;
  int bl = blk / 144;
  int rem = blk - bl*144;
  int tile = rem >> 2, g = rem & 3;
  int b = b0 + bl;
  int t = threadIdx.x;
  int oh0 = (tile / 6) * 16, ow0 = (tile % 6) * 16;
  int ol = t >> 4, wl = t & 15;
  const float* Db = D + (size_t)bl*C1OUT*PHW;
  float acc[32];
  #pragma unroll
  for (int o = 0; o < 32; ++o) acc[o] = 0.f;
  #pragma unroll 1
  for (int icc = 0; icc < 4; ++icc){
    __syncthreads();
    for (int lin = t; lin < 16*18*18; lin += 256){
      int ic = lin / 324; int r = lin - ic*324;
      int h = r / 18, w = r - h*18;
      int hg = oh0 - 1 + h, wg = ow0 - 1 + w;
      bool v = ((unsigned)hg < (unsigned)PDIM) && ((unsigned)wg < (unsigned)PDIM);
      sD[ic][h][w] = v ? Db[(size_t)(icc*16 + ic)*PHW + (size_t)hg*PDIM + wg] : 0.f;
    }
    __syncthreads();
    #pragma unroll 1
    for (int i = 0; i < 16; ++i){
      #pragma unroll
      for (int kh = 0; kh < 3; ++kh){
        const float* row = &sD[i][ol + kh][wl];
        float r0 = row[0], r1 = row[1], r2 = row[2];
        const float* wp = w2 + (size_t)(g*32)*576 + (icc*16 + i)*9 + kh*3;
        #pragma unroll
        for (int o = 0; o < 32; ++o){
          const float* w3 = wp + o*576;
          acc[o] = fmaf(w3[0], r0, fmaf(w3[1], r1, fmaf(w3[2], r2, acc[o])));
        }
      }
    }
  }
  const float bneps = rsqrtf(1.f + 1e-5f);
  int wv = t >> 6;
  #pragma unroll
  for (int o = 0; o < 32; ++o){
    int oc = g*32 + o;
    float val = fmaxf(fmaf(acc[o] + b2[oc], g2[oc]*bneps, bb2[oc]), 0.f);
    float s = wave_sum(val);
    if ((t & 63) == 0) pr[wv][o] = s;
  }
  __syncthreads();
  if (t < 32){
    float s = pr[0][t] + pr[1][t] + pr[2][t] + pr[3][t];
    atomicAdd(&freq_acc[b*C2OUT + g*32 + t], s);
  }
}

// RGB head + concat + 3-layer MLP, one block per batch sample.
__global__ __launch_bounds__(256) void k_mlp(const float* __restrict__ rgbmean,
    const float* __restrict__ freq_acc, const float* __restrict__ w_rgb,
    const float* __restrict__ b_rgb, const float* __restrict__ fc1w,
    const float* __restrict__ fc1b, const float* __restrict__ fc2w,
    const float* __restrict__ fc2b, const float* __restrict__ fc3w,
    const float* __restrict__ fc3b, float* __restrict__ out){
  __shared__ float z[130], z1[256], z2[128];
  int b = blockIdx.x, t = threadIdx.x;
  if (t < 2){
    float s = b_rgb[t];
    #pragma unroll
    for (int c = 0; c < 3; ++c) s += rgbmean[b*3 + c] * w_rgb[c*2 + t];
    z[t] = s;
  }
  if (t < 128) z[2 + t] = freq_acc[b*C2OUT + t] * (1.f/9216.f);
  __syncthreads();
  { float s = fc1b[t];
    for (int k = 0; k < 130; ++k) s = fmaf(z[k], fc1w[k*256 + t], s);
    z1[t] = fmaxf(s, 0.f); }
  __syncthreads();
  if (t < 128){
    float s = fc2b[t];
    for (int k = 0; k < 256; ++k) s = fmaf(z1[k], fc2w[k*128 + t], s);
    z2[t] = fmaxf(s, 0.f); }
  __syncthreads();
  if (t < 2){
    float s = fc3b[t];
    for (int k = 0; k < 128; ++k) s = fmaf(z2[k], fc3w[k*2 + t], s);
    out[b*2 + t] = s; }
}

extern "C" void kernel_launch(void* const* d_in, const int* in_sizes, int n_in,
                              void* d_out, int out_size, void* d_ws, size_t ws_size,
                              hipStream_t stream){
  const float* x     = (const float*)d_in[0];
  const float* w_rgb = (const float*)d_in[1];
  const float* b_rgb = (const float*)d_in[2];
  const float* w1    = (const float*)d_in[3];
  const float* b1    = (const float*)d_in[4];
  const float* g1    = (const float*)d_in[5];
  const float* bb1   = (const float*)d_in[6];
  const float* w2    = (const float*)d_in[7];
  const float* b2    = (const float*)d_in[8];
  const float* g2    = (const float*)d_in[9];
  const float* bb2   = (const float*)d_in[10];
  const float* fc1w  = (const float*)d_in[11];
  const float* fc1b  = (const float*)d_in[12];
  const float* fc2w  = (const float*)d_in[13];
  const float* fc2b  = (const float*)d_in[14];
  const float* fc3w  = (const float*)d_in[15];
  const float* fc3b  = (const float*)d_in[16];

  const bool full = (ws_size >= NEED_F);
  const int dftloop = full ? 1 : 4;
  const int dftCH   = full ? 96 : 24;
  const int cvloop  = full ? 4 : 16;
  const int cvB     = full ? 8 : 2;

  char* ws = (char*)d_ws;
  float2* T  = (float2*)(ws + OFF_T);
  float*  Bm = (float*)(ws + OFF_B);
  float2* A  = (float2*)(ws + OFF_S);
  unsigned short* E   = (unsigned short*)(ws + OFF_S + OFF_E);
  float*          D   = (float*)(ws + OFF_S + (full ? OFF_D_F : OFF_D_C));
  unsigned short* w1p = (unsigned short*)(ws + OFF_S + (full ? OFF_W_F : OFF_W_C));
  float*  sm = (float*)(ws + (full ? OFF_SM_F : OFF_SM_C));
  float* rgbsum = sm;            // 96
  float* stats  = sm + 96;       // 192
  float* freqa  = sm + 288;      // 4096
  float* rgbm   = sm + 4384;     // 96
  float* ssb    = sm + 4480;     // 192

  hipMemsetAsync(sm, 0, 4672*sizeof(float), stream);
  k_twiddle<<<(NS*NS + 255)/256, 256, 0, stream>>>(T);
  for (int c = 0; c < dftloop; ++c){
    k_dft_rows<<<dftCH*48, 192, 0, stream>>>(x, T, A, rgbsum, c*dftCH);
    k_dft_cols<<<dftCH*25, 192, 0, stream>>>(A, T, Bm, stats, c*dftCH);
  }
  k_finalize<<<1, 128, 0, stream>>>(stats, rgbsum, ssb, rgbm);
  k_w1prep<<<48, 256, 0, stream>>>(w1, w1p);
  for (int c = 0; c < cvloop; ++c){
    k_conv1mfma<<<cvB*144, 256, 0, stream>>>(Bm, ssb, w1p, b1, g1, bb1, E, c*cvB);
    k_pool<<<cvB*384, 256, 0, stream>>>(E, D);
    k_conv2pool<<<cvB*144, 256, 0, stream>>>(D, w2, b2, g2, bb2, freqa, c*cvB);
  }
  k_mlp<<<NB, 256, 0, stream>>>(rgbm, freqa, w_rgb, b_rgb, fc1w, fc1b,
                                fc2w, fc2b, fc3w, fc3b, (float*)d_out);
}

// Round 9
// 1510.905 us; speedup vs baseline: 6.0388x; 1.0024x over previous
//
#include <hip/hip_runtime.h>
#include <math.h>

// Problem dims
#define NB    32
#define NC    3
#define NIMG  (NB*NC)      // 96 image-channels
#define NS    384
#define HWSZ  (NS*NS)      // 147456
#define C1OUT 64
#define C1DIM 192
#define PDIM  96
#define PHW   (PDIM*PDIM)  // 9216
#define C2OUT 128
#define KWH   193          // stored half-spectrum width (kw = 0..192)
#define PI_F  3.14159265358979323846f

// ---- workspace layout (bytes) ----  (identical to round 7)
static const size_t OFF_T    = 0;
static const size_t OFF_B    = 1179648;
static const size_t OFF_S    = 57802752;
static const size_t OFF_SM_F = 133300224;
static const size_t OFF_SM_C = 76677120;
static const size_t NEED_F   = 133318912;
static const size_t OFF_E    = 0;
static const size_t OFF_D_F  = 37748736;
static const size_t OFF_D_C  = 9437184;
static const size_t OFF_W_F  = 57016320;
static const size_t OFF_W_C  = 14229504;

typedef __attribute__((ext_vector_type(8))) short bf16x8_t;
typedef __attribute__((ext_vector_type(4))) float f32x4_t;
union U16 { unsigned u[4]; uint4 q; bf16x8_t v; };

__device__ __forceinline__ float wave_sum(float v){
  #pragma unroll
  for (int off = 32; off; off >>= 1) v += __shfl_down(v, off);
  return v;
}
__device__ __forceinline__ unsigned short f2bf(float f){
  unsigned u = __float_as_uint(f);
  u += 0x7FFFu + ((u >> 16) & 1u);
  return (unsigned short)(u >> 16);
}
__device__ __forceinline__ float bf2f(unsigned short h){
  return __uint_as_float(((unsigned)h) << 16);
}
// proper mod-384 for v in [0, 768): NOT "& 383" (384 not a power of two).
__device__ __forceinline__ int mod384(int v){ return v >= NS ? v - NS : v; }
__device__ __forceinline__ float2 cmul(float2 a, float2 b){
  return make_float2(a.x*b.x - a.y*b.y, a.x*b.y + a.y*b.x);
}

// Twiddle table: T[k][n] = exp(-2*pi*i*(k*n mod 384)/384). Exact int reduction.
// FFT kernels use row k=1 (T+384): W384^m = Trow[m].
__global__ void k_twiddle(float2* __restrict__ T){
  int idx = blockIdx.x*256 + (int)threadIdx.x;
  if (idx >= NS*NS) return;
  int k = idx / NS, n = idx - k*NS;
  int m = (k*n) % NS;
  float ang = -2.0f*PI_F*(float)m/(float)NS;
  T[idx] = make_float2(cosf(ang), sinf(ang));
}

// ---- 384-pt FFT pieces: 384 = 3 x 128.  x[n], n = 3*n1 + r ->
// Y_r = FFT128 of x[3*n1+r] (DIT, bit-reversed input, W128 = W384^3);
// X[k] = Y0[k%128] + W384^k Y1[k%128] + W384^{2k} Y2[k%128].
// (This structure passed the r1-vs-r2 bit-identity forensic check.)

// Row FFT (along W, real input): 8 rows/block as 4 packed complex FFTs.
// Unpack: row even = (Z[k]+conj(Z[-k]))/2, row odd = -i(Z[k]-conj(Z[-k]))/2.
// Writes A[bc][h][kw], kw in [0,192]. Also rgb pixel sums.
__global__ __launch_bounds__(192) void k_dft_rows(const float* __restrict__ x,
    const float2* __restrict__ T, float2* __restrict__ A,
    float* __restrict__ rgbsum, int bc0){
  __shared__ float2 work[4][384];
  __shared__ float rs[3];
  const float2* Trow = T + NS;             // W384^m
  int blk = blockIdx.x;
  int bcl = blk / 48, rg = blk % 48;       // local channel, 8-row group
  int bc = bc0 + bcl;
  int t = threadIdx.x;
  const float* xp = x + (size_t)bc*HWSZ + (size_t)rg*8*NS;
  // scatter indices for n = t and n = t+192
  int nA = t,        rA = nA % 3, iA = (rA*128) + (__brev((unsigned)(nA/3)) >> 25);
  int nB = t + 192,  rB = nB % 3, iB = (rB*128) + (__brev((unsigned)(nB/3)) >> 25);
  float lsum = 0.f;
  #pragma unroll
  for (int c = 0; c < 4; ++c){
    float a0 = xp[(2*c)*NS + nA],   b0 = xp[(2*c+1)*NS + nA];
    float a1 = xp[(2*c)*NS + nB],   b1 = xp[(2*c+1)*NS + nB];
    work[c][iA] = make_float2(a0, b0);
    work[c][iB] = make_float2(a1, b1);
    lsum += a0 + b0 + a1 + b1;
  }
  float ws = wave_sum(lsum);
  if ((t & 63) == 0) rs[t >> 6] = ws;
  __syncthreads();
  if (t == 0) atomicAdd(&rgbsum[bc], rs[0] + rs[1] + rs[2]);

  int sub = t >> 6, j = t & 63;            // 3 sub-FFTs x 64 butterflies
  #pragma unroll
  for (int st = 0; st < 7; ++st){
    int half = 1 << st;
    int pos = j & (half - 1);
    int ia = sub*128 + (((j >> st) << (st + 1)) | pos);
    int ib = ia + half;
    float2 tw = Trow[(192 >> st) * pos];   // W_{2*half}^pos exact
    #pragma unroll
    for (int c = 0; c < 4; ++c){
      float2 a = work[c][ia], b = cmul(work[c][ib], tw);
      work[c][ia] = make_float2(a.x + b.x, a.y + b.y);
      work[c][ib] = make_float2(a.x - b.x, a.y - b.y);
    }
    __syncthreads();
  }
  // combine: X[t] and X[t+192];  W^(k+192) = -W^k, W^(2(k+192)) = W^(2k)
  int k1a = t & 127, k1b = (t + 192) & 127;
  float2 w1 = Trow[t], w2 = Trow[(2*t) % 384];
  float2 Xa[4], Xb[4];
  #pragma unroll
  for (int c = 0; c < 4; ++c){
    float2 p1 = cmul(w1, work[c][128 + k1a]);
    float2 p2 = cmul(w2, work[c][256 + k1a]);
    float2 y0 = work[c][k1a];
    Xa[c] = make_float2(y0.x + p1.x + p2.x, y0.y + p1.y + p2.y);
    float2 q1 = cmul(w1, work[c][128 + k1b]);
    float2 q2 = cmul(w2, work[c][256 + k1b]);
    float2 z0 = work[c][k1b];
    Xb[c] = make_float2(z0.x - q1.x + q2.x, z0.y - q1.y + q2.y);
  }
  __syncthreads();                         // done reading Y
  #pragma unroll
  for (int c = 0; c < 4; ++c){ work[c][t] = Xa[c]; work[c][t + 192] = Xb[c]; }
  __syncthreads();
  // unpack two real rows, write kw in [0,192]
  int tm = (t == 0) ? 0 : (384 - t);
  #pragma unroll
  for (int c = 0; c < 4; ++c){
    float2 Zk = Xa[c];
    float2 Zm = work[c][tm];
    size_t b0r = ((size_t)bcl*NS + rg*8 + 2*c)*KWH;
    size_t b1r = b0r + KWH;
    A[b0r + t] = make_float2(0.5f*(Zk.x + Zm.x), 0.5f*(Zk.y - Zm.y));
    A[b1r + t] = make_float2(0.5f*(Zk.y + Zm.y), 0.5f*(Zm.x - Zk.x));
    if (t == 0){
      float2 Zn = Xb[c];                   // X[192]; conj-sym -> real parts
      A[b0r + 192] = make_float2(Zn.x, 0.f);
      A[b1r + 192] = make_float2(Zn.y, 0.f);
    }
  }
}

// Column FFT (along H) for kw in [0,192], 8 columns/block batched through
// shared butterfly stages. Epilogue (mag/log1p/fftshift/mirror/stats) is
// byte-identical math to the verified round-7 DFT kernel.
__global__ __launch_bounds__(192) void k_dft_cols(const float2* __restrict__ A,
    const float2* __restrict__ T, float* __restrict__ Bm,
    float* __restrict__ stats, int bc0){
  __shared__ float2 work[8][384];
  __shared__ float rs[6];
  const float2* Trow = T + NS;
  int blk = blockIdx.x;
  int bcl = blk / 25, cg = blk % 25;
  int bc = bc0 + bcl;
  int kw0 = cg*8;
  int cols = (cg == 24) ? 1 : 8;           // 193 = 24*8 + 1
  int t = threadIdx.x;
  const float2* Al = A + (size_t)bcl*NS*KWH;
  if (cols == 8){
    #pragma unroll
    for (int i = 0; i < 16; ++i){
      int lin = i*192 + t;
      int h = lin >> 3, c = lin & 7;
      int r = h % 3;
      work[c][r*128 + (__brev((unsigned)(h/3)) >> 25)] = Al[(size_t)h*KWH + kw0 + c];
    }
  } else {
    for (int h = t; h < NS; h += 192){
      int r = h % 3;
      work[0][r*128 + (__brev((unsigned)(h/3)) >> 25)] = Al[(size_t)h*KWH + kw0];
    }
  }
  __syncthreads();
  int sub = t >> 6, j = t & 63;
  #pragma unroll
  for (int st = 0; st < 7; ++st){
    int half = 1 << st;
    int pos = j & (half - 1);
    int ia = sub*128 + (((j >> st) << (st + 1)) | pos);
    int ib = ia + half;
    float2 tw = Trow[(192 >> st) * pos];
    #pragma unroll
    for (int c = 0; c < 8; ++c){
      if (c < cols){
        float2 a = work[c][ia], b = cmul(work[c][ib], tw);
        work[c][ia] = make_float2(a.x + b.x, a.y + b.y);
        work[c][ib] = make_float2(a.x - b.x, a.y - b.y);
      }
    }
    __syncthreads();
  }
  // combine + epilogue per column
  int k1a = t & 127, k1b = (t + 192) & 127;
  float2 w1 = Trow[t], w2 = Trow[(2*t) % 384];
  float s1 = 0.f, s2 = 0.f;
  float* Bbc = Bm + (size_t)bc*HWSZ;
  #pragma unroll
  for (int c = 0; c < 8; ++c){
    if (c < cols){
      float2 p1 = cmul(w1, work[c][128 + k1a]);
      float2 p2 = cmul(w2, work[c][256 + k1a]);
      float2 y0 = work[c][k1a];
      float2 Xa = make_float2(y0.x + p1.x + p2.x, y0.y + p1.y + p2.y);
      float2 q1 = cmul(w1, work[c][128 + k1b]);
      float2 q2 = cmul(w2, work[c][256 + k1b]);
      float2 z0 = work[c][k1b];
      float2 Xb = make_float2(z0.x - q1.x + q2.x, z0.y - q1.y + q2.y);
      int kw = kw0 + c;
      #pragma unroll
      for (int kk = 0; kk < 2; ++kk){
        int kh = t + kk*192;
        float2 X = kk ? Xb : Xa;
        float mag = logf(sqrtf(X.x*X.x + X.y*X.y) + 1.f);
        int u = mod384(kh + 192);          // shifted H index
        int v = mod384(kw + 192);          // shifted W index
        Bbc[(size_t)u*NS + v] = mag;
        s1 += mag; s2 += mag*mag;
        if (kw >= 1 && kw <= 191){         // conj mirror -> kw2 in [193,383]
          int kh2 = mod384(NS - kh);
          int u2 = mod384(kh2 + 192);
          int v2 = mod384(NS - kw + 192);  // = 192 - kw
          Bbc[(size_t)u2*NS + v2] = mag;
          s1 += mag; s2 += mag*mag;
        }
      }
    }
  }
  float w1s = wave_sum(s1), w2s = wave_sum(s2);
  if ((t & 63) == 0){ rs[t >> 6] = w1s; rs[3 + (t >> 6)] = w2s; }
  __syncthreads();
  if (t == 0){
    atomicAdd(&stats[bc*2],     rs[0] + rs[1] + rs[2]);
    atomicAdd(&stats[bc*2 + 1], rs[3] + rs[4] + rs[5]);
  }
}

__global__ void k_finalize(const float* __restrict__ stats, const float* __restrict__ rgbsum,
                           float* __restrict__ ss, float* __restrict__ rgbmean){
  int t = threadIdx.x;
  if (t < NIMG){
    const float inv_n = 1.f / 147456.f;
    float mean = stats[t*2] * inv_n;
    float var  = fmaxf(stats[t*2 + 1] * inv_n - mean*mean, 0.f);
    float inv  = 1.f / (sqrtf(var) + 1e-8f);
    ss[t*2]     = inv;
    ss[t*2 + 1] = -mean * inv;
    rgbmean[t]  = rgbsum[t] * inv_n;
  }
}

// Pack conv1 weights to bf16 [64][192]: k' = (ic*7+kh)*8 + kw, kw==7 -> 0,
// k' >= 168 -> 0.
__global__ void k_w1prep(const float* __restrict__ w1, unsigned short* __restrict__ w1p){
  int idx = blockIdx.x*256 + (int)threadIdx.x;
  if (idx >= 64*192) return;
  int oc = idx / 192, k = idx - oc*192;
  int rk = k >> 3, kw = k & 7;
  float val = 0.f;
  if (rk < 21 && kw < 7){
    int ic = rk / 7, kh = rk - 7*ic;
    val = w1[oc*147 + ic*49 + kh*7 + kw];
  }
  w1p[idx] = f2bf(val);
}

// conv1(7x7,s2,p3)+BN+ReLU via MFMA 16x16x32 bf16 (unchanged from round 7).
__global__ __launch_bounds__(256) void k_conv1mfma(const float* __restrict__ Bm,
    const float* __restrict__ ss, const unsigned short* __restrict__ w1p,
    const float* __restrict__ b1, const float* __restrict__ g1,
    const float* __restrict__ bb1, unsigned short* __restrict__ E, int b0){
  __shared__ unsigned short pt[3*37*40];
  int blk = blockIdx.x;
  int li = blk / 144, rem = blk - li*144;
  int rg = rem / 12, cg = rem - rg*12;
  int r0 = rg*16, c0 = cg*16;
  int b = b0 + li;
  int t = threadIdx.x;
  float sc[3], sh[3];
  #pragma unroll
  for (int ic = 0; ic < 3; ++ic){ sc[ic] = ss[(b*3 + ic)*2]; sh[ic] = ss[(b*3 + ic)*2 + 1]; }
  const int h0 = 2*r0 - 3, w0 = 2*c0 - 3;
  const float* Bb = Bm + (size_t)b*3*HWSZ;
  for (int lin = t; lin < 3*37*40; lin += 256){
    int ic = lin / 1480; int r = lin - ic*1480;
    int hr = r / 40, wc = r - hr*40;
    int hg = h0 + hr, wg = w0 + wc;
    bool v = (wc < 38) && ((unsigned)hg < (unsigned)NS) && ((unsigned)wg < (unsigned)NS);
    float raw = v ? Bb[(size_t)ic*HWSZ + (size_t)hg*NS + wg] : 0.f;
    pt[lin] = v ? f2bf(fmaf(raw, sc[ic], sh[ic])) : (unsigned short)0;
  }
  __syncthreads();

  int wave = t >> 6, lane = t & 63;
  int lm = lane & 15, lg = lane >> 4;
  int oc = wave*16 + lm;
  U16 bf[6];
  #pragma unroll
  for (int ks = 0; ks < 6; ++ks)
    bf[ks].q = *(const uint4*)(w1p + oc*192 + ks*32 + lg*8);
  int cbase[6];
  #pragma unroll
  for (int ks = 0; ks < 6; ++ks){
    int rk = ks*4 + lg;
    if (rk > 20) rk = 20;
    int ic = rk / 7, kh = rk - 7*ic;
    cbase[ks] = ic*1480 + kh*40 + 2*lm;
  }
  const float bneps = rsqrtf(1.f + 1e-5f);
  float bias = b1[oc];
  float gsc = g1[oc]*bneps, bbv = bb1[oc];
  unsigned short* Eb = E + (((size_t)li*C1OUT + oc)*C1DIM + r0)*C1DIM + c0 + lg*4;

  #pragma unroll 1
  for (int rt = 0; rt < 16; ++rt){
    f32x4_t acc = {bias, bias, bias, bias};
    #pragma unroll
    for (int ks = 0; ks < 6; ++ks){
      U16 a;
      const unsigned* pp = (const unsigned*)&pt[cbase[ks] + 80*rt];
      a.u[0] = pp[0]; a.u[1] = pp[1]; a.u[2] = pp[2]; a.u[3] = pp[3];
      acc = __builtin_amdgcn_mfma_f32_16x16x32_bf16(a.v, bf[ks].v, acc, 0, 0, 0);
    }
    ushort4 o;
    o.x = f2bf(fmaxf(fmaf(acc[0], gsc, bbv), 0.f));
    o.y = f2bf(fmaxf(fmaf(acc[1], gsc, bbv), 0.f));
    o.z = f2bf(fmaxf(fmaf(acc[2], gsc, bbv), 0.f));
    o.w = f2bf(fmaxf(fmaf(acc[3], gsc, bbv), 0.f));
    *(ushort4*)(Eb + (size_t)rt*C1DIM) = o;
  }
}

// maxpool 3x3 s2 p1 over E (bf16, >=0) -> D f32
__global__ __launch_bounds__(256) void k_pool(const unsigned short* __restrict__ E,
    float* __restrict__ D){
  __shared__ unsigned short sE[33][196];
  int blk = blockIdx.x;
  int li = blk / 384, rem = blk - li*384;
  int oc = rem / 6, band = rem - oc*6;
  int r0 = band*16;
  int t = threadIdx.x;
  const unsigned short* Ep = E + ((size_t)li*C1OUT + oc)*C1DIM*C1DIM;
  for (int lin = t; lin < 33*196; lin += 256){
    int rr = lin / 196, cc = lin - rr*196;
    int cr = 2*r0 - 1 + rr, gc = cc - 1;
    bool v = ((unsigned)cr < (unsigned)C1DIM) && ((unsigned)gc < (unsigned)C1DIM) && (cc < 195);
    sE[rr][cc] = v ? Ep[(size_t)cr*C1DIM + gc] : (unsigned short)0;
  }
  __syncthreads();
  float* Dp = D + ((size_t)li*C1OUT + oc)*PHW + (size_t)r0*PDIM;
  #pragma unroll
  for (int ii = 0; ii < 6; ++ii){
    int j = ii*256 + t;
    int pr = j / PDIM, pc = j - pr*PDIM;
    float mx = 0.f;
    #pragma unroll
    for (int dh = 0; dh < 3; ++dh)
      #pragma unroll
      for (int dw = 0; dw < 3; ++dw)
        mx = fmaxf(mx, bf2f(sE[2*pr + dh][2*pc + dw]));
    Dp[(size_t)pr*PDIM + pc] = mx;
  }
}

// conv2(3x3,p1)+BN+ReLU fused with global-average-pool (fp32, unchanged).
__global__ __launch_bounds__(256) void k_conv2pool(const float* __restrict__ D,
    const float* __restrict__ w2, const float* __restrict__ b2,
    const float* __restrict__ g2, const float* __restrict__ bb2,
    float* __restrict__ freq_acc, int b0){
  __shared__ float sD[16][18][19];
  __shared__ float pr[4][32];
  int blk = blockIdx.x;
  int bl = blk / 144;
  int rem = blk - bl*144;
  int tile = rem >> 2, g = rem & 3;
  int b = b0 + bl;
  int t = threadIdx.x;
  int oh0 = (tile / 6) * 16, ow0 = (tile % 6) * 16;
  int ol = t >> 4, wl = t & 15;
  const float* Db = D + (size_t)bl*C1OUT*PHW;
  float acc[32];
  #pragma unroll
  for (int o = 0; o < 32; ++o) acc[o] = 0.f;
  #pragma unroll 1
  for (int icc = 0; icc < 4; ++icc){
    __syncthreads();
    for (int lin = t; lin < 16*18*18; lin += 256){
      int ic = lin / 324; int r = lin - ic*324;
      int h = r / 18, w = r - h*18;
      int hg = oh0 - 1 + h, wg = ow0 - 1 + w;
      bool v = ((unsigned)hg < (unsigned)PDIM) && ((unsigned)wg < (unsigned)PDIM);
      sD[ic][h][w] = v ? Db[(size_t)(icc*16 + ic)*PHW + (size_t)hg*PDIM + wg] : 0.f;
    }
    __syncthreads();
    #pragma unroll 1
    for (int i = 0; i < 16; ++i){
      #pragma unroll
      for (int kh = 0; kh < 3; ++kh){
        const float* row = &sD[i][ol + kh][wl];
        float r0 = row[0], r1 = row[1], r2 = row[2];
        const float* wp = w2 + (size_t)(g*32)*576 + (icc*16 + i)*9 + kh*3;
        #pragma unroll
        for (int o = 0; o < 32; ++o){
          const float* w3 = wp + o*576;
          acc[o] = fmaf(w3[0], r0, fmaf(w3[1], r1, fmaf(w3[2], r2, acc[o])));
        }
      }
    }
  }
  const float bneps = rsqrtf(1.f + 1e-5f);
  int wv = t >> 6;
  #pragma unroll
  for (int o = 0; o < 32; ++o){
    int oc = g*32 + o;
    float val = fmaxf(fmaf(acc[o] + b2[oc], g2[oc]*bneps, bb2[oc]), 0.f);
    float s = wave_sum(val);
    if ((t & 63) == 0) pr[wv][o] = s;
  }
  __syncthreads();
  if (t < 32){
    float s = pr[0][t] + pr[1][t] + pr[2][t] + pr[3][t];
    atomicAdd(&freq_acc[b*C2OUT + g*32 + t], s);
  }
}

// RGB head + concat + 3-layer MLP, one block per batch sample.
__global__ __launch_bounds__(256) void k_mlp(const float* __restrict__ rgbmean,
    const float* __restrict__ freq_acc, const float* __restrict__ w_rgb,
    const float* __restrict__ b_rgb, const float* __restrict__ fc1w,
    const float* __restrict__ fc1b, const float* __restrict__ fc2w,
    const float* __restrict__ fc2b, const float* __restrict__ fc3w,
    const float* __restrict__ fc3b, float* __restrict__ out){
  __shared__ float z[130], z1[256], z2[128];
  int b = blockIdx.x, t = threadIdx.x;
  if (t < 2){
    float s = b_rgb[t];
    #pragma unroll
    for (int c = 0; c < 3; ++c) s += rgbmean[b*3 + c] * w_rgb[c*2 + t];
    z[t] = s;
  }
  if (t < 128) z[2 + t] = freq_acc[b*C2OUT + t] * (1.f/9216.f);
  __syncthreads();
  { float s = fc1b[t];
    for (int k = 0; k < 130; ++k) s = fmaf(z[k], fc1w[k*256 + t], s);
    z1[t] = fmaxf(s, 0.f); }
  __syncthreads();
  if (t < 128){
    float s = fc2b[t];
    for (int k = 0; k < 256; ++k) s = fmaf(z1[k], fc2w[k*128 + t], s);
    z2[t] = fmaxf(s, 0.f); }
  __syncthreads();
  if (t < 2){
    float s = fc3b[t];
    for (int k = 0; k < 128; ++k) s = fmaf(z2[k], fc3w[k*2 + t], s);
    out[b*2 + t] = s; }
}

extern "C" void kernel_launch(void* const* d_in, const int* in_sizes, int n_in,
                              void* d_out, int out_size, void* d_ws, size_t ws_size,
                              hipStream_t stream){
  const float* x     = (const float*)d_in[0];
  const float* w_rgb = (const float*)d_in[1];
  const float* b_rgb = (const float*)d_in[2];
  const float* w1    = (const float*)d_in[3];
  const float* b1    = (const float*)d_in[4];
  const float* g1    = (const float*)d_in[5];
  const float* bb1   = (const float*)d_in[6];
  const float* w2    = (const float*)d_in[7];
  const float* b2    = (const float*)d_in[8];
  const float* g2    = (const float*)d_in[9];
  const float* bb2   = (const float*)d_in[10];
  const float* fc1w  = (const float*)d_in[11];
  const float* fc1b  = (const float*)d_in[12];
  const float* fc2w  = (const float*)d_in[13];
  const float* fc2b  = (const float*)d_in[14];
  const float* fc3w  = (const float*)d_in[15];
  const float* fc3b  = (const float*)d_in[16];

  const bool full = (ws_size >= NEED_F);
  const int dftloop = full ? 1 : 4;
  const int dftCH   = full ? 96 : 24;
  const int cvloop  = full ? 4 : 16;
  const int cvB     = full ? 8 : 2;

  char* ws = (char*)d_ws;
  float2* T  = (float2*)(ws + OFF_T);
  float*  Bm = (float*)(ws + OFF_B);
  float2* A  = (float2*)(ws + OFF_S);
  unsigned short* E   = (unsigned short*)(ws + OFF_S + OFF_E);
  float*          D   = (float*)(ws + OFF_S + (full ? OFF_D_F : OFF_D_C));
  unsigned short* w1p = (unsigned short*)(ws + OFF_S + (full ? OFF_W_F : OFF_W_C));
  float*  sm = (float*)(ws + (full ? OFF_SM_F : OFF_SM_C));
  float* rgbsum = sm;            // 96
  float* stats  = sm + 96;       // 192
  float* freqa  = sm + 288;      // 4096
  float* rgbm   = sm + 4384;     // 96
  float* ssb    = sm + 4480;     // 192

  hipMemsetAsync(sm, 0, 4672*sizeof(float), stream);
  k_twiddle<<<(NS*NS + 255)/256, 256, 0, stream>>>(T);
  for (int c = 0; c < dftloop; ++c){
    k_dft_rows<<<dftCH*48, 192, 0, stream>>>(x, T, A, rgbsum, c*dftCH);
    k_dft_cols<<<dftCH*25, 192, 0, stream>>>(A, T, Bm, stats, c*dftCH);
  }
  k_finalize<<<1, 128, 0, stream>>>(stats, rgbsum, ssb, rgbm);
  k_w1prep<<<48, 256, 0, stream>>>(w1, w1p);
  for (int c = 0; c < cvloop; ++c){
    k_conv1mfma<<<cvB*144, 256, 0, stream>>>(Bm, ssb, w1p, b1, g1, bb1, E, c*cvB);
    k_pool<<<cvB*384, 256, 0, stream>>>(E, D);
    k_conv2pool<<<cvB*144, 256, 0, stream>>>(D, w2, b2, g2, bb2, freqa, c*cvB);
  }
  k_mlp<<<NB, 256, 0, stream>>>(rgbm, freqa, w_rgb, b_rgb, fc1w, fc1b,
                                fc2w, fc2b, fc3w, fc3b, (float*)d_out);
}

// Round 10
// 591.949 us; speedup vs baseline: 15.4137x; 2.5524x over previous
//
#include <hip/hip_runtime.h>
#include <math.h>

// Problem dims
#define NB    32
#define NC    3
#define NIMG  (NB*NC)      // 96 image-channels
#define NS    384
#define HWSZ  (NS*NS)      // 147456
#define C1OUT 64
#define C1DIM 192
#define PDIM  96
#define PHW   (PDIM*PDIM)  // 9216
#define C2OUT 128
#define KWH   193          // stored half-spectrum width (kw = 0..192)
#define PI_F  3.14159265358979323846f

// ---- workspace layout (bytes) ----
// T: float2[384][384] twiddle table        =  1,179,648  @ 0
// B: float [96][384][384] shifted log-mag  = 56,623,104  @ OFF_B
// S: scratch (time-shared):                              @ OFF_S
//   dft phase : A float2[96][384][193] = 56,918,016 (full) / [24] (chunked)
//   conv phase: E bf16[8][192][192][64] = 37,748,736 (full) / [2] = 9,437,184 (chunked)
//   weight tables after A: w1p 24,576 + w2ph 147,456 + w2pl 147,456 = 319,488
// smalls: rgbsum[96] stats[192] freqacc[4096] rgbmean[96] ss[192]
static const size_t OFF_T    = 0;
static const size_t OFF_B    = 1179648;
static const size_t OFF_S    = 57802752;
static const size_t OFF_SM_F = 133300224;
static const size_t OFF_SM_C = 76677120;
static const size_t NEED_F   = 133318912;
static const size_t OFF_E    = 0;
static const size_t OFF_W_F  = 57016320;    // after A-full (56,918,016)
static const size_t OFF_W_C  = 14229504;    // after A-chunk

typedef __attribute__((ext_vector_type(8))) short bf16x8_t;
typedef __attribute__((ext_vector_type(4))) float f32x4_t;
union U16 { unsigned u[4]; uint4 q; bf16x8_t v; };

__device__ __forceinline__ float wave_sum(float v){
  #pragma unroll
  for (int off = 32; off; off >>= 1) v += __shfl_down(v, off);
  return v;
}
__device__ __forceinline__ unsigned short f2bf(float f){
  unsigned u = __float_as_uint(f);
  u += 0x7FFFu + ((u >> 16) & 1u);
  return (unsigned short)(u >> 16);
}
__device__ __forceinline__ float bf2f(unsigned short h){
  return __uint_as_float(((unsigned)h) << 16);
}
// packed u16 max (valid as bf16-max for non-negative values: ReLU outputs)
__device__ __forceinline__ unsigned pmax16(unsigned a, unsigned b){
  unsigned al = a & 0xffffu, ah = a >> 16, bl = b & 0xffffu, bh = b >> 16;
  unsigned ml = al > bl ? al : bl, mh = ah > bh ? ah : bh;
  return (mh << 16) | ml;
}
__device__ __forceinline__ uint4 pmax8(uint4 a, uint4 b){
  uint4 r;
  r.x = pmax16(a.x, b.x); r.y = pmax16(a.y, b.y);
  r.z = pmax16(a.z, b.z); r.w = pmax16(a.w, b.w);
  return r;
}
// proper mod-384 for v in [0, 768): NOT "& 383" (384 not a power of two).
__device__ __forceinline__ int mod384(int v){ return v >= NS ? v - NS : v; }
__device__ __forceinline__ float2 cmul(float2 a, float2 b){
  return make_float2(a.x*b.x - a.y*b.y, a.x*b.y + a.y*b.x);
}

// Twiddle table: T[k][n] = exp(-2*pi*i*(k*n mod 384)/384). Exact int reduction.
__global__ void k_twiddle(float2* __restrict__ T){
  int idx = blockIdx.x*256 + (int)threadIdx.x;
  if (idx >= NS*NS) return;
  int k = idx / NS, n = idx - k*NS;
  int m = (k*n) % NS;
  float ang = -2.0f*PI_F*(float)m/(float)NS;
  T[idx] = make_float2(cosf(ang), sinf(ang));
}

// Row FFT (along W, real input): 8 rows/block as 4 packed complex FFTs.
__global__ __launch_bounds__(192) void k_dft_rows(const float* __restrict__ x,
    const float2* __restrict__ T, float2* __restrict__ A,
    float* __restrict__ rgbsum, int bc0){
  __shared__ float2 work[4][384];
  __shared__ float rs[3];
  const float2* Trow = T + NS;             // W384^m
  int blk = blockIdx.x;
  int bcl = blk / 48, rg = blk % 48;
  int bc = bc0 + bcl;
  int t = threadIdx.x;
  const float* xp = x + (size_t)bc*HWSZ + (size_t)rg*8*NS;
  int nA = t,        rA = nA % 3, iA = (rA*128) + (__brev((unsigned)(nA/3)) >> 25);
  int nB = t + 192,  rB = nB % 3, iB = (rB*128) + (__brev((unsigned)(nB/3)) >> 25);
  float lsum = 0.f;
  #pragma unroll
  for (int c = 0; c < 4; ++c){
    float a0 = xp[(2*c)*NS + nA],   b0 = xp[(2*c+1)*NS + nA];
    float a1 = xp[(2*c)*NS + nB],   b1 = xp[(2*c+1)*NS + nB];
    work[c][iA] = make_float2(a0, b0);
    work[c][iB] = make_float2(a1, b1);
    lsum += a0 + b0 + a1 + b1;
  }
  float ws = wave_sum(lsum);
  if ((t & 63) == 0) rs[t >> 6] = ws;
  __syncthreads();
  if (t == 0) atomicAdd(&rgbsum[bc], rs[0] + rs[1] + rs[2]);

  int sub = t >> 6, j = t & 63;
  #pragma unroll
  for (int st = 0; st < 7; ++st){
    int half = 1 << st;
    int pos = j & (half - 1);
    int ia = sub*128 + (((j >> st) << (st + 1)) | pos);
    int ib = ia + half;
    float2 tw = Trow[(192 >> st) * pos];
    #pragma unroll
    for (int c = 0; c < 4; ++c){
      float2 a = work[c][ia], b = cmul(work[c][ib], tw);
      work[c][ia] = make_float2(a.x + b.x, a.y + b.y);
      work[c][ib] = make_float2(a.x - b.x, a.y - b.y);
    }
    __syncthreads();
  }
  int k1a = t & 127, k1b = (t + 192) & 127;
  float2 w1 = Trow[t], w2 = Trow[(2*t) % 384];
  float2 Xa[4], Xb[4];
  #pragma unroll
  for (int c = 0; c < 4; ++c){
    float2 p1 = cmul(w1, work[c][128 + k1a]);
    float2 p2 = cmul(w2, work[c][256 + k1a]);
    float2 y0 = work[c][k1a];
    Xa[c] = make_float2(y0.x + p1.x + p2.x, y0.y + p1.y + p2.y);
    float2 q1 = cmul(w1, work[c][128 + k1b]);
    float2 q2 = cmul(w2, work[c][256 + k1b]);
    float2 z0 = work[c][k1b];
    Xb[c] = make_float2(z0.x - q1.x + q2.x, z0.y - q1.y + q2.y);
  }
  __syncthreads();
  #pragma unroll
  for (int c = 0; c < 4; ++c){ work[c][t] = Xa[c]; work[c][t + 192] = Xb[c]; }
  __syncthreads();
  int tm = (t == 0) ? 0 : (384 - t);
  #pragma unroll
  for (int c = 0; c < 4; ++c){
    float2 Zk = Xa[c];
    float2 Zm = work[c][tm];
    size_t b0r = ((size_t)bcl*NS + rg*8 + 2*c)*KWH;
    size_t b1r = b0r + KWH;
    A[b0r + t] = make_float2(0.5f*(Zk.x + Zm.x), 0.5f*(Zk.y - Zm.y));
    A[b1r + t] = make_float2(0.5f*(Zk.y + Zm.y), 0.5f*(Zm.x - Zk.x));
    if (t == 0){
      float2 Zn = Xb[c];
      A[b0r + 192] = make_float2(Zn.x, 0.f);
      A[b1r + 192] = make_float2(Zn.y, 0.f);
    }
  }
}

// Column FFT for kw in [0,192], 8 columns/block; mag/log1p/fftshift/mirror/stats.
__global__ __launch_bounds__(192) void k_dft_cols(const float2* __restrict__ A,
    const float2* __restrict__ T, float* __restrict__ Bm,
    float* __restrict__ stats, int bc0){
  __shared__ float2 work[8][384];
  __shared__ float rs[6];
  const float2* Trow = T + NS;
  int blk = blockIdx.x;
  int bcl = blk / 25, cg = blk % 25;
  int bc = bc0 + bcl;
  int kw0 = cg*8;
  int cols = (cg == 24) ? 1 : 8;
  int t = threadIdx.x;
  const float2* Al = A + (size_t)bcl*NS*KWH;
  if (cols == 8){
    #pragma unroll
    for (int i = 0; i < 16; ++i){
      int lin = i*192 + t;
      int h = lin >> 3, c = lin & 7;
      int r = h % 3;
      work[c][r*128 + (__brev((unsigned)(h/3)) >> 25)] = Al[(size_t)h*KWH + kw0 + c];
    }
  } else {
    for (int h = t; h < NS; h += 192){
      int r = h % 3;
      work[0][r*128 + (__brev((unsigned)(h/3)) >> 25)] = Al[(size_t)h*KWH + kw0];
    }
  }
  __syncthreads();
  int sub = t >> 6, j = t & 63;
  #pragma unroll
  for (int st = 0; st < 7; ++st){
    int half = 1 << st;
    int pos = j & (half - 1);
    int ia = sub*128 + (((j >> st) << (st + 1)) | pos);
    int ib = ia + half;
    float2 tw = Trow[(192 >> st) * pos];
    #pragma unroll
    for (int c = 0; c < 8; ++c){
      if (c < cols){
        float2 a = work[c][ia], b = cmul(work[c][ib], tw);
        work[c][ia] = make_float2(a.x + b.x, a.y + b.y);
        work[c][ib] = make_float2(a.x - b.x, a.y - b.y);
      }
    }
    __syncthreads();
  }
  int k1a = t & 127, k1b = (t + 192) & 127;
  float2 w1 = Trow[t], w2 = Trow[(2*t) % 384];
  float s1 = 0.f, s2 = 0.f;
  float* Bbc = Bm + (size_t)bc*HWSZ;
  #pragma unroll
  for (int c = 0; c < 8; ++c){
    if (c < cols){
      float2 p1 = cmul(w1, work[c][128 + k1a]);
      float2 p2 = cmul(w2, work[c][256 + k1a]);
      float2 y0 = work[c][k1a];
      float2 Xa = make_float2(y0.x + p1.x + p2.x, y0.y + p1.y + p2.y);
      float2 q1 = cmul(w1, work[c][128 + k1b]);
      float2 q2 = cmul(w2, work[c][256 + k1b]);
      float2 z0 = work[c][k1b];
      float2 Xb = make_float2(z0.x - q1.x + q2.x, z0.y - q1.y + q2.y);
      int kw = kw0 + c;
      #pragma unroll
      for (int kk = 0; kk < 2; ++kk){
        int kh = t + kk*192;
        float2 X = kk ? Xb : Xa;
        float mag = logf(sqrtf(X.x*X.x + X.y*X.y) + 1.f);
        int u = mod384(kh + 192);
        int v = mod384(kw + 192);
        Bbc[(size_t)u*NS + v] = mag;
        s1 += mag; s2 += mag*mag;
        if (kw >= 1 && kw <= 191){
          int kh2 = mod384(NS - kh);
          int u2 = mod384(kh2 + 192);
          int v2 = mod384(NS - kw + 192);
          Bbc[(size_t)u2*NS + v2] = mag;
          s1 += mag; s2 += mag*mag;
        }
      }
    }
  }
  float w1s = wave_sum(s1), w2s = wave_sum(s2);
  if ((t & 63) == 0){ rs[t >> 6] = w1s; rs[3 + (t >> 6)] = w2s; }
  __syncthreads();
  if (t == 0){
    atomicAdd(&stats[bc*2],     rs[0] + rs[1] + rs[2]);
    atomicAdd(&stats[bc*2 + 1], rs[3] + rs[4] + rs[5]);
  }
}

__global__ void k_finalize(const float* __restrict__ stats, const float* __restrict__ rgbsum,
                           float* __restrict__ ss, float* __restrict__ rgbmean){
  int t = threadIdx.x;
  if (t < NIMG){
    const float inv_n = 1.f / 147456.f;
    float mean = stats[t*2] * inv_n;
    float var  = fmaxf(stats[t*2 + 1] * inv_n - mean*mean, 0.f);
    float inv  = 1.f / (sqrtf(var) + 1e-8f);
    ss[t*2]     = inv;
    ss[t*2 + 1] = -mean * inv;
    rgbmean[t]  = rgbsum[t] * inv_n;
  }
}

// Pack conv1 weights to bf16 [64][192]: k' = (ic*7+kh)*8 + kw, kw==7 -> 0.
__global__ void k_w1prep(const float* __restrict__ w1, unsigned short* __restrict__ w1p){
  int idx = blockIdx.x*256 + (int)threadIdx.x;
  if (idx >= 64*192) return;
  int oc = idx / 192, k = idx - oc*192;
  int rk = k >> 3, kw = k & 7;
  float val = 0.f;
  if (rk < 21 && kw < 7){
    int ic = rk / 7, kh = rk - 7*ic;
    val = w1[oc*147 + ic*49 + kh*7 + kw];
  }
  w1p[idx] = f2bf(val);
}

// Pack conv2 weights, split hi/lo bf16: [128][576], k = tap*64 + ic.
// w = wh + wl with wl = bf16(w - bf16(w)) -> residual ~2^-18, conv2 MFMA
// path numerically equivalent to fp32 (inputs are exact bf16 already).
__global__ void k_w2prep(const float* __restrict__ w2,
    unsigned short* __restrict__ w2ph, unsigned short* __restrict__ w2pl){
  int idx = blockIdx.x*256 + (int)threadIdx.x;
  if (idx >= 128*576) return;
  int oc = idx / 576, k = idx - oc*576;
  int tap = k >> 6, ic = k & 63;
  float w = w2[(size_t)oc*576 + ic*9 + tap];
  unsigned short hi = f2bf(w);
  w2ph[idx] = hi;
  w2pl[idx] = f2bf(w - bf2f(hi));
}

// conv1(7x7,s2,p3)+BN+ReLU via MFMA 16x16x32 bf16.
// Operand order mfma(weights, patch, acc): C row = oc (lg*4+j), col = position.
// E written [img][h][w][oc] (oc-minor, ushort4/lane coalesced) for conv2.
__global__ __launch_bounds__(256) void k_conv1mfma(const float* __restrict__ Bm,
    const float* __restrict__ ss, const unsigned short* __restrict__ w1p,
    const float* __restrict__ b1, const float* __restrict__ g1,
    const float* __restrict__ bb1, unsigned short* __restrict__ E, int b0){
  __shared__ unsigned short pt[3*37*40];
  int blk = blockIdx.x;
  int li = blk / 144, rem = blk - li*144;
  int rg = rem / 12, cg = rem - rg*12;
  int r0 = rg*16, c0 = cg*16;
  int b = b0 + li;
  int t = threadIdx.x;
  float sc[3], sh[3];
  #pragma unroll
  for (int ic = 0; ic < 3; ++ic){ sc[ic] = ss[(b*3 + ic)*2]; sh[ic] = ss[(b*3 + ic)*2 + 1]; }
  const int h0 = 2*r0 - 3, w0 = 2*c0 - 3;
  const float* Bb = Bm + (size_t)b*3*HWSZ;
  for (int lin = t; lin < 3*37*40; lin += 256){
    int ic = lin / 1480; int r = lin - ic*1480;
    int hr = r / 40, wc = r - hr*40;
    int hg = h0 + hr, wg = w0 + wc;
    bool v = (wc < 38) && ((unsigned)hg < (unsigned)NS) && ((unsigned)wg < (unsigned)NS);
    float raw = v ? Bb[(size_t)ic*HWSZ + (size_t)hg*NS + wg] : 0.f;
    pt[lin] = v ? f2bf(fmaf(raw, sc[ic], sh[ic])) : (unsigned short)0;
  }
  __syncthreads();

  int wave = t >> 6, lane = t & 63;
  int lm = lane & 15, lg = lane >> 4;
  // A-frag (weights): row = lm -> oc_in = wave*16 + lm
  U16 bf[6];
  #pragma unroll
  for (int ks = 0; ks < 6; ++ks)
    bf[ks].q = *(const uint4*)(w1p + (wave*16 + lm)*192 + ks*32 + lg*8);
  // B-frag (patch): col = lm -> position col c0+lm; k-slice rows via lg
  int cbase[6];
  #pragma unroll
  for (int ks = 0; ks < 6; ++ks){
    int rk = ks*4 + lg;
    if (rk > 20) rk = 20;
    int ic = rk / 7, kh = rk - 7*ic;
    cbase[ks] = ic*1480 + kh*40 + 2*lm;
  }
  const float bneps = rsqrtf(1.f + 1e-5f);
  // output oc = wave*16 + lg*4 + j  -> vector coeff loads
  float4 b4  = *(const float4*)(b1  + wave*16 + lg*4);
  float4 g4  = *(const float4*)(g1  + wave*16 + lg*4);
  float4 bb4 = *(const float4*)(bb1 + wave*16 + lg*4);
  float4 gs4 = make_float4(g4.x*bneps, g4.y*bneps, g4.z*bneps, g4.w*bneps);
  unsigned short* Eb = E + (((size_t)li*C1DIM + r0)*C1DIM + c0 + lm)*64 + wave*16 + lg*4;

  #pragma unroll 1
  for (int rt = 0; rt < 16; ++rt){
    f32x4_t acc = {b4.x, b4.y, b4.z, b4.w};
    #pragma unroll
    for (int ks = 0; ks < 6; ++ks){
      U16 a;
      const unsigned* pp = (const unsigned*)&pt[cbase[ks] + 80*rt];
      a.u[0] = pp[0]; a.u[1] = pp[1]; a.u[2] = pp[2]; a.u[3] = pp[3];
      acc = __builtin_amdgcn_mfma_f32_16x16x32_bf16(bf[ks].v, a.v, acc, 0, 0, 0);
    }
    ushort4 o;
    o.x = f2bf(fmaxf(fmaf(acc[0], gs4.x, bb4.x), 0.f));
    o.y = f2bf(fmaxf(fmaf(acc[1], gs4.y, bb4.y), 0.f));
    o.z = f2bf(fmaxf(fmaf(acc[2], gs4.z, bb4.z), 0.f));
    o.w = f2bf(fmaxf(fmaf(acc[3], gs4.w, bb4.w), 0.f));
    *(ushort4*)(Eb + (size_t)rt*C1DIM*64) = o;
  }
}

// conv2(3x3,p1)+BN+ReLU + global-avg-pool via MFMA, maxpool fused into staging.
// Block = 8x16 output positions x all 128 oc (8 waves). K = 576 tap-major
// (k = tap*64+ic, 18 ksteps, no padding waste). Weights split hi/lo (2 MFMA).
// LDS [hp][g][wp][8ic]: MFMA B-frag reads are quarter-wave contiguous
// (16 lanes x 16B = 256B span) -> conflict-free by construction.
__global__ __launch_bounds__(512) void k_conv2mfma(const unsigned short* __restrict__ E,
    const unsigned short* __restrict__ w2ph, const unsigned short* __restrict__ w2pl,
    const float* __restrict__ b2, const float* __restrict__ g2,
    const float* __restrict__ bb2, float* __restrict__ freq_acc, int b0){
  __shared__ unsigned short sD[10*1152];   // [hp(10)][g(8)][wp(18)][8ic] = 23,040 B
  int blk = blockIdx.x;
  int li = blk / 72, tile = blk - li*72;
  int rb = tile / 6, cb = tile - rb*6;
  int r0 = rb*8, c0 = cb*16;
  int b = b0 + li;
  int t = threadIdx.x;
  const unsigned short* Eb = E + (size_t)li*C1DIM*C1DIM*64;
  // staging with fused 3x3/s2 maxpool: 10*18*8 = 1440 x 16B
  for (int lin = t; lin < 1440; lin += 512){
    int g = lin & 7; int rm = lin >> 3;
    int wp = rm % 18, hp = rm / 18;
    int ph = r0 + hp - 1, pw = c0 + wp - 1;
    uint4 mx = make_uint4(0u,0u,0u,0u);
    if ((unsigned)ph < (unsigned)PDIM && (unsigned)pw < (unsigned)PDIM){
      #pragma unroll
      for (int dh = 0; dh < 3; ++dh){
        int eh = 2*ph - 1 + dh;
        if ((unsigned)eh >= (unsigned)C1DIM) continue;
        #pragma unroll
        for (int dw = 0; dw < 3; ++dw){
          int ew = 2*pw - 1 + dw;
          if ((unsigned)ew >= (unsigned)C1DIM) continue;
          uint4 v = *(const uint4*)(Eb + ((size_t)eh*C1DIM + ew)*64 + g*8);
          mx = pmax8(mx, v);
        }
      }
    }
    *(uint4*)&sD[hp*1152 + g*144 + wp*8] = mx;
  }
  __syncthreads();

  int wave = t >> 6, lane = t & 63;
  int lm = lane & 15, lg = lane >> 4;
  int octile = wave*16;
  const float bneps = rsqrtf(1.f + 1e-5f);
  float4 b4  = *(const float4*)(b2  + octile + lg*4);
  float4 g4  = *(const float4*)(g2  + octile + lg*4);
  float4 bb4 = *(const float4*)(bb2 + octile + lg*4);
  f32x4_t acc[8];
  #pragma unroll
  for (int nt = 0; nt < 8; ++nt){
    acc[nt][0] = b4.x; acc[nt][1] = b4.y; acc[nt][2] = b4.z; acc[nt][3] = b4.w;
  }
  const unsigned short* whp = w2ph + (size_t)(octile + lm)*576;
  const unsigned short* wlp = w2pl + (size_t)(octile + lm)*576;
  #pragma unroll
  for (int ks = 0; ks < 18; ++ks){
    const int tap = ks >> 1, h32 = ks & 1;
    const int dh = tap / 3, dw = tap - 3*(tap/3);
    U16 wh, wl;
    wh.q = *(const uint4*)(whp + ks*32 + lg*8);
    wl.q = *(const uint4*)(wlp + ks*32 + lg*8);
    int base = (h32*4 + lg)*144 + (lm + dw)*8;
    #pragma unroll
    for (int nt = 0; nt < 8; ++nt){
      U16 a;
      a.q = *(const uint4*)&sD[(nt + dh)*1152 + base];
      acc[nt] = __builtin_amdgcn_mfma_f32_16x16x32_bf16(wh.v, a.v, acc[nt], 0, 0, 0);
      acc[nt] = __builtin_amdgcn_mfma_f32_16x16x32_bf16(wl.v, a.v, acc[nt], 0, 0, 0);
    }
  }
  // BN+ReLU per output (C row = oc octile+lg*4+j, col = position c0+lm), then pool-sum
  float s0 = 0.f, s1 = 0.f, s2 = 0.f, s3 = 0.f;
  float gx = g4.x*bneps, gy = g4.y*bneps, gz = g4.z*bneps, gw = g4.w*bneps;
  #pragma unroll
  for (int nt = 0; nt < 8; ++nt){
    s0 += fmaxf(fmaf(acc[nt][0], gx, bb4.x), 0.f);
    s1 += fmaxf(fmaf(acc[nt][1], gy, bb4.y), 0.f);
    s2 += fmaxf(fmaf(acc[nt][2], gz, bb4.z), 0.f);
    s3 += fmaxf(fmaf(acc[nt][3], gw, bb4.w), 0.f);
  }
  #pragma unroll
  for (int off = 1; off < 16; off <<= 1){
    s0 += __shfl_xor(s0, off);
    s1 += __shfl_xor(s1, off);
    s2 += __shfl_xor(s2, off);
    s3 += __shfl_xor(s3, off);
  }
  if (lm == 0){
    float* fa = freq_acc + (size_t)b*C2OUT + octile + lg*4;
    atomicAdd(fa + 0, s0); atomicAdd(fa + 1, s1);
    atomicAdd(fa + 2, s2); atomicAdd(fa + 3, s3);
  }
}

// RGB head + concat + 3-layer MLP, one block per batch sample.
__global__ __launch_bounds__(256) void k_mlp(const float* __restrict__ rgbmean,
    const float* __restrict__ freq_acc, const float* __restrict__ w_rgb,
    const float* __restrict__ b_rgb, const float* __restrict__ fc1w,
    const float* __restrict__ fc1b, const float* __restrict__ fc2w,
    const float* __restrict__ fc2b, const float* __restrict__ fc3w,
    const float* __restrict__ fc3b, float* __restrict__ out){
  __shared__ float z[130], z1[256], z2[128];
  int b = blockIdx.x, t = threadIdx.x;
  if (t < 2){
    float s = b_rgb[t];
    #pragma unroll
    for (int c = 0; c < 3; ++c) s += rgbmean[b*3 + c] * w_rgb[c*2 + t];
    z[t] = s;
  }
  if (t < 128) z[2 + t] = freq_acc[b*C2OUT + t] * (1.f/9216.f);
  __syncthreads();
  { float s = fc1b[t];
    for (int k = 0; k < 130; ++k) s = fmaf(z[k], fc1w[k*256 + t], s);
    z1[t] = fmaxf(s, 0.f); }
  __syncthreads();
  if (t < 128){
    float s = fc2b[t];
    for (int k = 0; k < 256; ++k) s = fmaf(z1[k], fc2w[k*128 + t], s);
    z2[t] = fmaxf(s, 0.f); }
  __syncthreads();
  if (t < 2){
    float s = fc3b[t];
    for (int k = 0; k < 128; ++k) s = fmaf(z2[k], fc3w[k*2 + t], s);
    out[b*2 + t] = s; }
}

extern "C" void kernel_launch(void* const* d_in, const int* in_sizes, int n_in,
                              void* d_out, int out_size, void* d_ws, size_t ws_size,
                              hipStream_t stream){
  const float* x     = (const float*)d_in[0];
  const float* w_rgb = (const float*)d_in[1];
  const float* b_rgb = (const float*)d_in[2];
  const float* w1    = (const float*)d_in[3];
  const float* b1    = (const float*)d_in[4];
  const float* g1    = (const float*)d_in[5];
  const float* bb1   = (const float*)d_in[6];
  const float* w2    = (const float*)d_in[7];
  const float* b2    = (const float*)d_in[8];
  const float* g2    = (const float*)d_in[9];
  const float* bb2   = (const float*)d_in[10];
  const float* fc1w  = (const float*)d_in[11];
  const float* fc1b  = (const float*)d_in[12];
  const float* fc2w  = (const float*)d_in[13];
  const float* fc2b  = (const float*)d_in[14];
  const float* fc3w  = (const float*)d_in[15];
  const float* fc3b  = (const float*)d_in[16];

  const bool full = (ws_size >= NEED_F);
  const int dftloop = full ? 1 : 4;
  const int dftCH   = full ? 96 : 24;
  const int cvloop  = full ? 4 : 16;
  const int cvB     = full ? 8 : 2;

  char* ws = (char*)d_ws;
  float2* T  = (float2*)(ws + OFF_T);
  float*  Bm = (float*)(ws + OFF_B);
  float2* A  = (float2*)(ws + OFF_S);
  unsigned short* E    = (unsigned short*)(ws + OFF_S + OFF_E);
  const size_t offw    = OFF_S + (full ? OFF_W_F : OFF_W_C);
  unsigned short* w1p  = (unsigned short*)(ws + offw);
  unsigned short* w2ph = (unsigned short*)(ws + offw + 24576);
  unsigned short* w2pl = (unsigned short*)(ws + offw + 24576 + 147456);
  float*  sm = (float*)(ws + (full ? OFF_SM_F : OFF_SM_C));
  float* rgbsum = sm;            // 96
  float* stats  = sm + 96;       // 192
  float* freqa  = sm + 288;      // 4096
  float* rgbm   = sm + 4384;     // 96
  float* ssb    = sm + 4480;     // 192

  hipMemsetAsync(sm, 0, 4672*sizeof(float), stream);
  k_twiddle<<<(NS*NS + 255)/256, 256, 0, stream>>>(T);
  for (int c = 0; c < dftloop; ++c){
    k_dft_rows<<<dftCH*48, 192, 0, stream>>>(x, T, A, rgbsum, c*dftCH);
    k_dft_cols<<<dftCH*25, 192, 0, stream>>>(A, T, Bm, stats, c*dftCH);
  }
  k_finalize<<<1, 128, 0, stream>>>(stats, rgbsum, ssb, rgbm);
  k_w1prep<<<48, 256, 0, stream>>>(w1, w1p);
  k_w2prep<<<288, 256, 0, stream>>>(w2, w2ph, w2pl);
  for (int c = 0; c < cvloop; ++c){
    k_conv1mfma<<<cvB*144, 256, 0, stream>>>(Bm, ssb, w1p, b1, g1, bb1, E, c*cvB);
    k_conv2mfma<<<cvB*72, 512, 0, stream>>>(E, w2ph, w2pl, b2, g2, bb2, freqa, c*cvB);
  }
  k_mlp<<<NB, 256, 0, stream>>>(rgbm, freqa, w_rgb, b_rgb, fc1w, fc1b,
                                fc2w, fc2b, fc3w, fc3b, (float*)d_out);
}

// Round 11
// 591.720 us; speedup vs baseline: 15.4196x; 1.0004x over previous
//
#include <hip/hip_runtime.h>
#include <math.h>

// Problem dims
#define NB    32
#define NC    3
#define NIMG  (NB*NC)      // 96 image-channels
#define NS    384
#define HWSZ  (NS*NS)      // 147456
#define C1OUT 64
#define C1DIM 192
#define PDIM  96
#define PHW   (PDIM*PDIM)  // 9216
#define C2OUT 128
#define KWH   193          // stored half-spectrum width (kw = 0..192)
#define PI_F  3.14159265358979323846f

// ---- workspace layout (bytes) ----
// T: float2[384][384] twiddle table        =  1,179,648  @ 0
// B: float [96][384][384] shifted log-mag  = 56,623,104  @ OFF_B
// S: scratch (time-shared):                              @ OFF_S
//   dft phase : A float2[96][384][193] = 56,918,016 (full) / [24] (chunked)
//   conv phase: E bf16[8][192][192][64] = 37,748,736 (full) / [2] = 9,437,184 (chunked)
//   weight tables after A: w1p 24,576 + w2ph 147,456 + w2pl 147,456 = 319,488
// smalls: rgbsum[96] stats[192] freqacc[4096] rgbmean[96] ss[192]
static const size_t OFF_T    = 0;
static const size_t OFF_B    = 1179648;
static const size_t OFF_S    = 57802752;
static const size_t OFF_SM_F = 133300224;
static const size_t OFF_SM_C = 76677120;
static const size_t NEED_F   = 133318912;
static const size_t OFF_E    = 0;
static const size_t OFF_W_F  = 57016320;    // after A-full (56,918,016)
static const size_t OFF_W_C  = 14229504;    // after A-chunk

typedef __attribute__((ext_vector_type(8))) short bf16x8_t;
typedef __attribute__((ext_vector_type(4))) float f32x4_t;
union U16 { unsigned u[4]; uint4 q; bf16x8_t v; };

__device__ __forceinline__ float wave_sum(float v){
  #pragma unroll
  for (int off = 32; off; off >>= 1) v += __shfl_down(v, off);
  return v;
}
__device__ __forceinline__ unsigned short f2bf(float f){
  unsigned u = __float_as_uint(f);
  u += 0x7FFFu + ((u >> 16) & 1u);
  return (unsigned short)(u >> 16);
}
__device__ __forceinline__ float bf2f(unsigned short h){
  return __uint_as_float(((unsigned)h) << 16);
}
// packed u16 max (valid as bf16-max for non-negative values: ReLU outputs)
__device__ __forceinline__ unsigned pmax16(unsigned a, unsigned b){
  unsigned al = a & 0xffffu, ah = a >> 16, bl = b & 0xffffu, bh = b >> 16;
  unsigned ml = al > bl ? al : bl, mh = ah > bh ? ah : bh;
  return (mh << 16) | ml;
}
__device__ __forceinline__ uint4 pmax8(uint4 a, uint4 b){
  uint4 r;
  r.x = pmax16(a.x, b.x); r.y = pmax16(a.y, b.y);
  r.z = pmax16(a.z, b.z); r.w = pmax16(a.w, b.w);
  return r;
}
// proper mod-384 for v in [0, 768): NOT "& 383" (384 not a power of two).
__device__ __forceinline__ int mod384(int v){ return v >= NS ? v - NS : v; }
__device__ __forceinline__ float2 cmul(float2 a, float2 b){
  return make_float2(a.x*b.x - a.y*b.y, a.x*b.y + a.y*b.x);
}

// Twiddle table: T[k][n] = exp(-2*pi*i*(k*n mod 384)/384). Exact int reduction.
__global__ void k_twiddle(float2* __restrict__ T){
  int idx = blockIdx.x*256 + (int)threadIdx.x;
  if (idx >= NS*NS) return;
  int k = idx / NS, n = idx - k*NS;
  int m = (k*n) % NS;
  float ang = -2.0f*PI_F*(float)m/(float)NS;
  T[idx] = make_float2(cosf(ang), sinf(ang));
}

// Row FFT (along W, real input): 8 rows/block as 4 packed complex FFTs.
__global__ __launch_bounds__(192) void k_dft_rows(const float* __restrict__ x,
    const float2* __restrict__ T, float2* __restrict__ A,
    float* __restrict__ rgbsum, int bc0){
  __shared__ float2 work[4][384];
  __shared__ float rs[3];
  const float2* Trow = T + NS;             // W384^m
  int blk = blockIdx.x;
  int bcl = blk / 48, rg = blk % 48;
  int bc = bc0 + bcl;
  int t = threadIdx.x;
  const float* xp = x + (size_t)bc*HWSZ + (size_t)rg*8*NS;
  int nA = t,        rA = nA % 3, iA = (rA*128) + (__brev((unsigned)(nA/3)) >> 25);
  int nB = t + 192,  rB = nB % 3, iB = (rB*128) + (__brev((unsigned)(nB/3)) >> 25);
  float lsum = 0.f;
  #pragma unroll
  for (int c = 0; c < 4; ++c){
    float a0 = xp[(2*c)*NS + nA],   b0 = xp[(2*c+1)*NS + nA];
    float a1 = xp[(2*c)*NS + nB],   b1 = xp[(2*c+1)*NS + nB];
    work[c][iA] = make_float2(a0, b0);
    work[c][iB] = make_float2(a1, b1);
    lsum += a0 + b0 + a1 + b1;
  }
  float ws = wave_sum(lsum);
  if ((t & 63) == 0) rs[t >> 6] = ws;
  __syncthreads();
  if (t == 0) atomicAdd(&rgbsum[bc], rs[0] + rs[1] + rs[2]);

  int sub = t >> 6, j = t & 63;
  #pragma unroll
  for (int st = 0; st < 7; ++st){
    int half = 1 << st;
    int pos = j & (half - 1);
    int ia = sub*128 + (((j >> st) << (st + 1)) | pos);
    int ib = ia + half;
    float2 tw = Trow[(192 >> st) * pos];
    #pragma unroll
    for (int c = 0; c < 4; ++c){
      float2 a = work[c][ia], b = cmul(work[c][ib], tw);
      work[c][ia] = make_float2(a.x + b.x, a.y + b.y);
      work[c][ib] = make_float2(a.x - b.x, a.y - b.y);
    }
    __syncthreads();
  }
  int k1a = t & 127, k1b = (t + 192) & 127;
  float2 w1 = Trow[t], w2 = Trow[(2*t) % 384];
  float2 Xa[4], Xb[4];
  #pragma unroll
  for (int c = 0; c < 4; ++c){
    float2 p1 = cmul(w1, work[c][128 + k1a]);
    float2 p2 = cmul(w2, work[c][256 + k1a]);
    float2 y0 = work[c][k1a];
    Xa[c] = make_float2(y0.x + p1.x + p2.x, y0.y + p1.y + p2.y);
    float2 q1 = cmul(w1, work[c][128 + k1b]);
    float2 q2 = cmul(w2, work[c][256 + k1b]);
    float2 z0 = work[c][k1b];
    Xb[c] = make_float2(z0.x - q1.x + q2.x, z0.y - q1.y + q2.y);
  }
  __syncthreads();
  #pragma unroll
  for (int c = 0; c < 4; ++c){ work[c][t] = Xa[c]; work[c][t + 192] = Xb[c]; }
  __syncthreads();
  int tm = (t == 0) ? 0 : (384 - t);
  #pragma unroll
  for (int c = 0; c < 4; ++c){
    float2 Zk = Xa[c];
    float2 Zm = work[c][tm];
    size_t b0r = ((size_t)bcl*NS + rg*8 + 2*c)*KWH;
    size_t b1r = b0r + KWH;
    A[b0r + t] = make_float2(0.5f*(Zk.x + Zm.x), 0.5f*(Zk.y - Zm.y));
    A[b1r + t] = make_float2(0.5f*(Zk.y + Zm.y), 0.5f*(Zm.x - Zk.x));
    if (t == 0){
      float2 Zn = Xb[c];
      A[b0r + 192] = make_float2(Zn.x, 0.f);
      A[b1r + 192] = make_float2(Zn.y, 0.f);
    }
  }
}

// Column FFT for kw in [0,192], 8 columns/block; mag/log1p/fftshift/mirror/stats.
__global__ __launch_bounds__(192) void k_dft_cols(const float2* __restrict__ A,
    const float2* __restrict__ T, float* __restrict__ Bm,
    float* __restrict__ stats, int bc0){
  __shared__ float2 work[8][384];
  __shared__ float rs[6];
  const float2* Trow = T + NS;
  int blk = blockIdx.x;
  int bcl = blk / 25, cg = blk % 25;
  int bc = bc0 + bcl;
  int kw0 = cg*8;
  int cols = (cg == 24) ? 1 : 8;
  int t = threadIdx.x;
  const float2* Al = A + (size_t)bcl*NS*KWH;
  if (cols == 8){
    #pragma unroll
    for (int i = 0; i < 16; ++i){
      int lin = i*192 + t;
      int h = lin >> 3, c = lin & 7;
      int r = h % 3;
      work[c][r*128 + (__brev((unsigned)(h/3)) >> 25)] = Al[(size_t)h*KWH + kw0 + c];
    }
  } else {
    for (int h = t; h < NS; h += 192){
      int r = h % 3;
      work[0][r*128 + (__brev((unsigned)(h/3)) >> 25)] = Al[(size_t)h*KWH + kw0];
    }
  }
  __syncthreads();
  int sub = t >> 6, j = t & 63;
  #pragma unroll
  for (int st = 0; st < 7; ++st){
    int half = 1 << st;
    int pos = j & (half - 1);
    int ia = sub*128 + (((j >> st) << (st + 1)) | pos);
    int ib = ia + half;
    float2 tw = Trow[(192 >> st) * pos];
    #pragma unroll
    for (int c = 0; c < 8; ++c){
      if (c < cols){
        float2 a = work[c][ia], b = cmul(work[c][ib], tw);
        work[c][ia] = make_float2(a.x + b.x, a.y + b.y);
        work[c][ib] = make_float2(a.x - b.x, a.y - b.y);
      }
    }
    __syncthreads();
  }
  int k1a = t & 127, k1b = (t + 192) & 127;
  float2 w1 = Trow[t], w2 = Trow[(2*t) % 384];
  float s1 = 0.f, s2 = 0.f;
  float* Bbc = Bm + (size_t)bc*HWSZ;
  #pragma unroll
  for (int c = 0; c < 8; ++c){
    if (c < cols){
      float2 p1 = cmul(w1, work[c][128 + k1a]);
      float2 p2 = cmul(w2, work[c][256 + k1a]);
      float2 y0 = work[c][k1a];
      float2 Xa = make_float2(y0.x + p1.x + p2.x, y0.y + p1.y + p2.y);
      float2 q1 = cmul(w1, work[c][128 + k1b]);
      float2 q2 = cmul(w2, work[c][256 + k1b]);
      float2 z0 = work[c][k1b];
      float2 Xb = make_float2(z0.x - q1.x + q2.x, z0.y - q1.y + q2.y);
      int kw = kw0 + c;
      #pragma unroll
      for (int kk = 0; kk < 2; ++kk){
        int kh = t + kk*192;
        float2 X = kk ? Xb : Xa;
        float mag = logf(sqrtf(X.x*X.x + X.y*X.y) + 1.f);
        int u = mod384(kh + 192);
        int v = mod384(kw + 192);
        Bbc[(size_t)u*NS + v] = mag;
        s1 += mag; s2 += mag*mag;
        if (kw >= 1 && kw <= 191){
          int kh2 = mod384(NS - kh);
          int u2 = mod384(kh2 + 192);
          int v2 = mod384(NS - kw + 192);
          Bbc[(size_t)u2*NS + v2] = mag;
          s1 += mag; s2 += mag*mag;
        }
      }
    }
  }
  float w1s = wave_sum(s1), w2s = wave_sum(s2);
  if ((t & 63) == 0){ rs[t >> 6] = w1s; rs[3 + (t >> 6)] = w2s; }
  __syncthreads();
  if (t == 0){
    atomicAdd(&stats[bc*2],     rs[0] + rs[1] + rs[2]);
    atomicAdd(&stats[bc*2 + 1], rs[3] + rs[4] + rs[5]);
  }
}

__global__ void k_finalize(const float* __restrict__ stats, const float* __restrict__ rgbsum,
                           float* __restrict__ ss, float* __restrict__ rgbmean){
  int t = threadIdx.x;
  if (t < NIMG){
    const float inv_n = 1.f / 147456.f;
    float mean = stats[t*2] * inv_n;
    float var  = fmaxf(stats[t*2 + 1] * inv_n - mean*mean, 0.f);
    float inv  = 1.f / (sqrtf(var) + 1e-8f);
    ss[t*2]     = inv;
    ss[t*2 + 1] = -mean * inv;
    rgbmean[t]  = rgbsum[t] * inv_n;
  }
}

// Pack conv1 weights to bf16 [64][192]: k' = (ic*7+kh)*8 + kw, kw==7 -> 0.
__global__ void k_w1prep(const float* __restrict__ w1, unsigned short* __restrict__ w1p){
  int idx = blockIdx.x*256 + (int)threadIdx.x;
  if (idx >= 64*192) return;
  int oc = idx / 192, k = idx - oc*192;
  int rk = k >> 3, kw = k & 7;
  float val = 0.f;
  if (rk < 21 && kw < 7){
    int ic = rk / 7, kh = rk - 7*ic;
    val = w1[oc*147 + ic*49 + kh*7 + kw];
  }
  w1p[idx] = f2bf(val);
}

// Pack conv2 weights, split hi/lo bf16: [128][576], k = tap*64 + ic.
// w = wh + wl with wl = bf16(w - bf16(w)) -> residual ~2^-18, conv2 MFMA
// path numerically equivalent to fp32 (inputs are exact bf16 already).
__global__ void k_w2prep(const float* __restrict__ w2,
    unsigned short* __restrict__ w2ph, unsigned short* __restrict__ w2pl){
  int idx = blockIdx.x*256 + (int)threadIdx.x;
  if (idx >= 128*576) return;
  int oc = idx / 576, k = idx - oc*576;
  int tap = k >> 6, ic = k & 63;
  float w = w2[(size_t)oc*576 + ic*9 + tap];
  unsigned short hi = f2bf(w);
  w2ph[idx] = hi;
  w2pl[idx] = f2bf(w - bf2f(hi));
}

// conv1(7x7,s2,p3)+BN+ReLU via MFMA 16x16x32 bf16.
// Operand order mfma(weights, patch, acc): C row = oc (lg*4+j), col = position.
// E written [img][h][w][oc] (oc-minor, ushort4/lane coalesced) for conv2.
__global__ __launch_bounds__(256) void k_conv1mfma(const float* __restrict__ Bm,
    const float* __restrict__ ss, const unsigned short* __restrict__ w1p,
    const float* __restrict__ b1, const float* __restrict__ g1,
    const float* __restrict__ bb1, unsigned short* __restrict__ E, int b0){
  __shared__ unsigned short pt[3*37*40];
  int blk = blockIdx.x;
  int li = blk / 144, rem = blk - li*144;
  int rg = rem / 12, cg = rem - rg*12;
  int r0 = rg*16, c0 = cg*16;
  int b = b0 + li;
  int t = threadIdx.x;
  float sc[3], sh[3];
  #pragma unroll
  for (int ic = 0; ic < 3; ++ic){ sc[ic] = ss[(b*3 + ic)*2]; sh[ic] = ss[(b*3 + ic)*2 + 1]; }
  const int h0 = 2*r0 - 3, w0 = 2*c0 - 3;
  const float* Bb = Bm + (size_t)b*3*HWSZ;
  for (int lin = t; lin < 3*37*40; lin += 256){
    int ic = lin / 1480; int r = lin - ic*1480;
    int hr = r / 40, wc = r - hr*40;
    int hg = h0 + hr, wg = w0 + wc;
    bool v = (wc < 38) && ((unsigned)hg < (unsigned)NS) && ((unsigned)wg < (unsigned)NS);
    float raw = v ? Bb[(size_t)ic*HWSZ + (size_t)hg*NS + wg] : 0.f;
    pt[lin] = v ? f2bf(fmaf(raw, sc[ic], sh[ic])) : (unsigned short)0;
  }
  __syncthreads();

  int wave = t >> 6, lane = t & 63;
  int lm = lane & 15, lg = lane >> 4;
  // A-frag (weights): row = lm -> oc_in = wave*16 + lm
  U16 bf[6];
  #pragma unroll
  for (int ks = 0; ks < 6; ++ks)
    bf[ks].q = *(const uint4*)(w1p + (wave*16 + lm)*192 + ks*32 + lg*8);
  // B-frag (patch): col = lm -> position col c0+lm; k-slice rows via lg
  int cbase[6];
  #pragma unroll
  for (int ks = 0; ks < 6; ++ks){
    int rk = ks*4 + lg;
    if (rk > 20) rk = 20;
    int ic = rk / 7, kh = rk - 7*ic;
    cbase[ks] = ic*1480 + kh*40 + 2*lm;
  }
  const float bneps = rsqrtf(1.f + 1e-5f);
  // output oc = wave*16 + lg*4 + j  -> vector coeff loads
  float4 b4  = *(const float4*)(b1  + wave*16 + lg*4);
  float4 g4  = *(const float4*)(g1  + wave*16 + lg*4);
  float4 bb4 = *(const float4*)(bb1 + wave*16 + lg*4);
  float4 gs4 = make_float4(g4.x*bneps, g4.y*bneps, g4.z*bneps, g4.w*bneps);
  unsigned short* Eb = E + (((size_t)li*C1DIM + r0)*C1DIM + c0 + lm)*64 + wave*16 + lg*4;

  #pragma unroll 1
  for (int rt = 0; rt < 16; ++rt){
    f32x4_t acc = {b4.x, b4.y, b4.z, b4.w};
    #pragma unroll
    for (int ks = 0; ks < 6; ++ks){
      U16 a;
      const unsigned* pp = (const unsigned*)&pt[cbase[ks] + 80*rt];
      a.u[0] = pp[0]; a.u[1] = pp[1]; a.u[2] = pp[2]; a.u[3] = pp[3];
      acc = __builtin_amdgcn_mfma_f32_16x16x32_bf16(bf[ks].v, a.v, acc, 0, 0, 0);
    }
    ushort4 o;
    o.x = f2bf(fmaxf(fmaf(acc[0], gs4.x, bb4.x), 0.f));
    o.y = f2bf(fmaxf(fmaf(acc[1], gs4.y, bb4.y), 0.f));
    o.z = f2bf(fmaxf(fmaf(acc[2], gs4.z, bb4.z), 0.f));
    o.w = f2bf(fmaxf(fmaf(acc[3], gs4.w, bb4.w), 0.f));
    *(ushort4*)(Eb + (size_t)rt*C1DIM*64) = o;
  }
}

// conv2(3x3,p1)+BN+ReLU + global-avg-pool via MFMA, maxpool fused into staging.
// Block = 8x16 output positions x all 128 oc (8 waves). K = 576 tap-major
// (k = tap*64+ic, 18 ksteps, no padding waste). Weights split hi/lo (2 MFMA).
// LDS [hp][g][wp][8ic]: MFMA B-frag reads are quarter-wave contiguous
// (16 lanes x 16B = 256B span) -> conflict-free by construction.
__global__ __launch_bounds__(512) void k_conv2mfma(const unsigned short* __restrict__ E,
    const unsigned short* __restrict__ w2ph, const unsigned short* __restrict__ w2pl,
    const float* __restrict__ b2, const float* __restrict__ g2,
    const float* __restrict__ bb2, float* __restrict__ freq_acc, int b0){
  __shared__ unsigned short sD[10*1152];   // [hp(10)][g(8)][wp(18)][8ic] = 23,040 B
  int blk = blockIdx.x;
  int li = blk / 72, tile = blk - li*72;
  int rb = tile / 6, cb = tile - rb*6;
  int r0 = rb*8, c0 = cb*16;
  int b = b0 + li;
  int t = threadIdx.x;
  const unsigned short* Eb = E + (size_t)li*C1DIM*C1DIM*64;
  // staging with fused 3x3/s2 maxpool: 10*18*8 = 1440 x 16B
  for (int lin = t; lin < 1440; lin += 512){
    int g = lin & 7; int rm = lin >> 3;
    int wp = rm % 18, hp = rm / 18;
    int ph = r0 + hp - 1, pw = c0 + wp - 1;
    uint4 mx = make_uint4(0u,0u,0u,0u);
    if ((unsigned)ph < (unsigned)PDIM && (unsigned)pw < (unsigned)PDIM){
      #pragma unroll
      for (int dh = 0; dh < 3; ++dh){
        int eh = 2*ph - 1 + dh;
        if ((unsigned)eh >= (unsigned)C1DIM) continue;
        #pragma unroll
        for (int dw = 0; dw < 3; ++dw){
          int ew = 2*pw - 1 + dw;
          if ((unsigned)ew >= (unsigned)C1DIM) continue;
          uint4 v = *(const uint4*)(Eb + ((size_t)eh*C1DIM + ew)*64 + g*8);
          mx = pmax8(mx, v);
        }
      }
    }
    *(uint4*)&sD[hp*1152 + g*144 + wp*8] = mx;
  }
  __syncthreads();

  int wave = t >> 6, lane = t & 63;
  int lm = lane & 15, lg = lane >> 4;
  int octile = wave*16;
  const float bneps = rsqrtf(1.f + 1e-5f);
  float4 b4  = *(const float4*)(b2  + octile + lg*4);
  float4 g4  = *(const float4*)(g2  + octile + lg*4);
  float4 bb4 = *(const float4*)(bb2 + octile + lg*4);
  f32x4_t acc[8];
  #pragma unroll
  for (int nt = 0; nt < 8; ++nt){
    acc[nt][0] = b4.x; acc[nt][1] = b4.y; acc[nt][2] = b4.z; acc[nt][3] = b4.w;
  }
  const unsigned short* whp = w2ph + (size_t)(octile + lm)*576;
  const unsigned short* wlp = w2pl + (size_t)(octile + lm)*576;
  #pragma unroll
  for (int ks = 0; ks < 18; ++ks){
    const int tap = ks >> 1, h32 = ks & 1;
    const int dh = tap / 3, dw = tap - 3*(tap/3);
    U16 wh, wl;
    wh.q = *(const uint4*)(whp + ks*32 + lg*8);
    wl.q = *(const uint4*)(wlp + ks*32 + lg*8);
    int base = (h32*4 + lg)*144 + (lm + dw)*8;
    #pragma unroll
    for (int nt = 0; nt < 8; ++nt){
      U16 a;
      a.q = *(const uint4*)&sD[(nt + dh)*1152 + base];
      acc[nt] = __builtin_amdgcn_mfma_f32_16x16x32_bf16(wh.v, a.v, acc[nt], 0, 0, 0);
      acc[nt] = __builtin_amdgcn_mfma_f32_16x16x32_bf16(wl.v, a.v, acc[nt], 0, 0, 0);
    }
  }
  // BN+ReLU per output (C row = oc octile+lg*4+j, col = position c0+lm), then pool-sum
  float s0 = 0.f, s1 = 0.f, s2 = 0.f, s3 = 0.f;
  float gx = g4.x*bneps, gy = g4.y*bneps, gz = g4.z*bneps, gw = g4.w*bneps;
  #pragma unroll
  for (int nt = 0; nt < 8; ++nt){
    s0 += fmaxf(fmaf(acc[nt][0], gx, bb4.x), 0.f);
    s1 += fmaxf(fmaf(acc[nt][1], gy, bb4.y), 0.f);
    s2 += fmaxf(fmaf(acc[nt][2], gz, bb4.z), 0.f);
    s3 += fmaxf(fmaf(acc[nt][3], gw, bb4.w), 0.f);
  }
  #pragma unroll
  for (int off = 1; off < 16; off <<= 1){
    s0 += __shfl_xor(s0, off);
    s1 += __shfl_xor(s1, off);
    s2 += __shfl_xor(s2, off);
    s3 += __shfl_xor(s3, off);
  }
  if (lm == 0){
    float* fa = freq_acc + (size_t)b*C2OUT + octile + lg*4;
    atomicAdd(fa + 0, s0); atomicAdd(fa + 1, s1);
    atomicAdd(fa + 2, s2); atomicAdd(fa + 3, s3);
  }
}

// RGB head + concat + 3-layer MLP, one block per batch sample.
__global__ __launch_bounds__(256) void k_mlp(const float* __restrict__ rgbmean,
    const float* __restrict__ freq_acc, const float* __restrict__ w_rgb,
    const float* __restrict__ b_rgb, const float* __restrict__ fc1w,
    const float* __restrict__ fc1b, const float* __restrict__ fc2w,
    const float* __restrict__ fc2b, const float* __restrict__ fc3w,
    const float* __restrict__ fc3b, float* __restrict__ out){
  __shared__ float z[130], z1[256], z2[128];
  int b = blockIdx.x, t = threadIdx.x;
  if (t < 2){
    float s = b_rgb[t];
    #pragma unroll
    for (int c = 0; c < 3; ++c) s += rgbmean[b*3 + c] * w_rgb[c*2 + t];
    z[t] = s;
  }
  if (t < 128) z[2 + t] = freq_acc[b*C2OUT + t] * (1.f/9216.f);
  __syncthreads();
  { float s = fc1b[t];
    for (int k = 0; k < 130; ++k) s = fmaf(z[k], fc1w[k*256 + t], s);
    z1[t] = fmaxf(s, 0.f); }
  __syncthreads();
  if (t < 128){
    float s = fc2b[t];
    for (int k = 0; k < 256; ++k) s = fmaf(z1[k], fc2w[k*128 + t], s);
    z2[t] = fmaxf(s, 0.f); }
  __syncthreads();
  if (t < 2){
    float s = fc3b[t];
    for (int k = 0; k < 128; ++k) s = fmaf(z2[k], fc3w[k*2 + t], s);
    out[b*2 + t] = s; }
}

extern "C" void kernel_launch(void* const* d_in, const int* in_sizes, int n_in,
                              void* d_out, int out_size, void* d_ws, size_t ws_size,
                              hipStream_t stream){
  const float* x     = (const float*)d_in[0];
  const float* w_rgb = (const float*)d_in[1];
  const float* b_rgb = (const float*)d_in[2];
  const float* w1    = (const float*)d_in[3];
  const float* b1    = (const float*)d_in[4];
  const float* g1    = (const float*)d_in[5];
  const float* bb1   = (const float*)d_in[6];
  const float* w2    = (const float*)d_in[7];
  const float* b2    = (const float*)d_in[8];
  const float* g2    = (const float*)d_in[9];
  const float* bb2   = (const float*)d_in[10];
  const float* fc1w  = (const float*)d_in[11];
  const float* fc1b  = (const float*)d_in[12];
  const float* fc2w  = (const float*)d_in[13];
  const float* fc2b  = (const float*)d_in[14];
  const float* fc3w  = (const float*)d_in[15];
  const float* fc3b  = (const float*)d_in[16];

  const bool full = (ws_size >= NEED_F);
  const int dftloop = full ? 1 : 4;
  const int dftCH   = full ? 96 : 24;
  const int cvloop  = full ? 4 : 16;
  const int cvB     = full ? 8 : 2;

  char* ws = (char*)d_ws;
  float2* T  = (float2*)(ws + OFF_T);
  float*  Bm = (float*)(ws + OFF_B);
  float2* A  = (float2*)(ws + OFF_S);
  unsigned short* E    = (unsigned short*)(ws + OFF_S + OFF_E);
  const size_t offw    = OFF_S + (full ? OFF_W_F : OFF_W_C);
  unsigned short* w1p  = (unsigned short*)(ws + offw);
  unsigned short* w2ph = (unsigned short*)(ws + offw + 24576);
  unsigned short* w2pl = (unsigned short*)(ws + offw + 24576 + 147456);
  float*  sm = (float*)(ws + (full ? OFF_SM_F : OFF_SM_C));
  float* rgbsum = sm;            // 96
  float* stats  = sm + 96;       // 192
  float* freqa  = sm + 288;      // 4096
  float* rgbm   = sm + 4384;     // 96
  float* ssb    = sm + 4480;     // 192

  hipMemsetAsync(sm, 0, 4672*sizeof(float), stream);
  k_twiddle<<<(NS*NS + 255)/256, 256, 0, stream>>>(T);
  for (int c = 0; c < dftloop; ++c){
    k_dft_rows<<<dftCH*48, 192, 0, stream>>>(x, T, A, rgbsum, c*dftCH);
    k_dft_cols<<<dftCH*25, 192, 0, stream>>>(A, T, Bm, stats, c*dftCH);
  }
  k_finalize<<<1, 128, 0, stream>>>(stats, rgbsum, ssb, rgbm);
  k_w1prep<<<48, 256, 0, stream>>>(w1, w1p);
  k_w2prep<<<288, 256, 0, stream>>>(w2, w2ph, w2pl);
  for (int c = 0; c < cvloop; ++c){
    k_conv1mfma<<<cvB*144, 256, 0, stream>>>(Bm, ssb, w1p, b1, g1, bb1, E, c*cvB);
    k_conv2mfma<<<cvB*72, 512, 0, stream>>>(E, w2ph, w2pl, b2, g2, bb2, freqa, c*cvB);
  }
  k_mlp<<<NB, 256, 0, stream>>>(rgbm, freqa, w_rgb, b_rgb, fc1w, fc1b,
                                fc2w, fc2b, fc3w, fc3b, (float*)d_out);
}

// Round 12
// 479.307 us; speedup vs baseline: 19.0360x; 1.2345x over previous
//
#include <hip/hip_runtime.h>
#include <math.h>

// Problem dims
#define NB    32
#define NC    3
#define NIMG  (NB*NC)      // 96 image-channels
#define NS    384
#define HWSZ  (NS*NS)      // 147456
#define C1OUT 64
#define C1DIM 192
#define PDIM  96
#define PHW   (PDIM*PDIM)  // 9216
#define C2OUT 128
#define KWH   193          // stored half-spectrum width (kw = 0..192)
#define PI_F  3.14159265358979323846f

// ---- workspace layout (bytes) ----
// T: float2[384][384] twiddle region (only row 1 used) @ 0
// B: float [96][384][384] shifted log-mag  = 56,623,104  @ OFF_B
// S: scratch (time-shared):                              @ OFF_S
//   dft phase : A float2[96][384][193] = 56,918,016 (full) / [24] (chunked)
//   conv phase: E bf16[8][192][192][64] = 37,748,736 (full) / [2] (chunked)
//   weight tables after A: w1p 24,576 + w2ph 147,456 + w2pl 147,456
// smalls: rgbsum[96] stats[192] freqacc[4096] rgbmean[96] ss[192]
static const size_t OFF_T    = 0;
static const size_t OFF_B    = 1179648;
static const size_t OFF_S    = 57802752;
static const size_t OFF_SM_F = 133300224;
static const size_t OFF_SM_C = 76677120;
static const size_t NEED_F   = 133318912;
static const size_t OFF_E    = 0;
static const size_t OFF_W_F  = 57016320;    // after A-full (56,918,016)
static const size_t OFF_W_C  = 14229504;    // after A-chunk

typedef __attribute__((ext_vector_type(8))) short bf16x8_t;
typedef __attribute__((ext_vector_type(4))) float f32x4_t;
union U16 { unsigned u[4]; uint4 q; bf16x8_t v; };

__device__ __forceinline__ float wave_sum(float v){
  #pragma unroll
  for (int off = 32; off; off >>= 1) v += __shfl_down(v, off);
  return v;
}
__device__ __forceinline__ unsigned short f2bf(float f){
  unsigned u = __float_as_uint(f);
  u += 0x7FFFu + ((u >> 16) & 1u);
  return (unsigned short)(u >> 16);
}
__device__ __forceinline__ float bf2f(unsigned short h){
  return __uint_as_float(((unsigned)h) << 16);
}
// packed u16 max (valid as bf16-max for non-negative values: ReLU outputs)
__device__ __forceinline__ unsigned pmax16(unsigned a, unsigned b){
  unsigned al = a & 0xffffu, ah = a >> 16, bl = b & 0xffffu, bh = b >> 16;
  unsigned ml = al > bl ? al : bl, mh = ah > bh ? ah : bh;
  return (mh << 16) | ml;
}
__device__ __forceinline__ uint4 pmax8(uint4 a, uint4 b){
  uint4 r;
  r.x = pmax16(a.x, b.x); r.y = pmax16(a.y, b.y);
  r.z = pmax16(a.z, b.z); r.w = pmax16(a.w, b.w);
  return r;
}
// proper mod-384 for v in [0, 768): NOT "& 383" (384 not a power of two).
__device__ __forceinline__ int mod384(int v){ return v >= NS ? v - NS : v; }
__device__ __forceinline__ float2 cmul(float2 a, float2 b){
  return make_float2(a.x*b.x - a.y*b.y, a.x*b.y + a.y*b.x);
}

// Twiddle row 1 only: Trow[n] = exp(-2*pi*i*n/384) (bit-identical to the old
// full-table row; FFT kernels only ever read T+NS).
__global__ void k_twiddle(float2* __restrict__ T){
  int idx = blockIdx.x*256 + (int)threadIdx.x;
  if (idx >= NS) return;
  float ang = -2.0f*PI_F*(float)idx/(float)NS;
  T[NS + idx] = make_float2(cosf(ang), sinf(ang));
}

// Row FFT (along W, real input): 8 rows/block as 4 packed complex FFTs.
__global__ __launch_bounds__(192) void k_dft_rows(const float* __restrict__ x,
    const float2* __restrict__ T, float2* __restrict__ A,
    float* __restrict__ rgbsum, int bc0){
  __shared__ float2 work[4][384];
  __shared__ float rs[3];
  const float2* Trow = T + NS;             // W384^m
  int blk = blockIdx.x;
  int bcl = blk / 48, rg = blk % 48;
  int bc = bc0 + bcl;
  int t = threadIdx.x;
  const float* xp = x + (size_t)bc*HWSZ + (size_t)rg*8*NS;
  int nA = t,        rA = nA % 3, iA = (rA*128) + (__brev((unsigned)(nA/3)) >> 25);
  int nB = t + 192,  rB = nB % 3, iB = (rB*128) + (__brev((unsigned)(nB/3)) >> 25);
  float lsum = 0.f;
  #pragma unroll
  for (int c = 0; c < 4; ++c){
    float a0 = xp[(2*c)*NS + nA],   b0 = xp[(2*c+1)*NS + nA];
    float a1 = xp[(2*c)*NS + nB],   b1 = xp[(2*c+1)*NS + nB];
    work[c][iA] = make_float2(a0, b0);
    work[c][iB] = make_float2(a1, b1);
    lsum += a0 + b0 + a1 + b1;
  }
  float ws = wave_sum(lsum);
  if ((t & 63) == 0) rs[t >> 6] = ws;
  __syncthreads();
  if (t == 0) atomicAdd(&rgbsum[bc], rs[0] + rs[1] + rs[2]);

  int sub = t >> 6, j = t & 63;
  #pragma unroll
  for (int st = 0; st < 7; ++st){
    int half = 1 << st;
    int pos = j & (half - 1);
    int ia = sub*128 + (((j >> st) << (st + 1)) | pos);
    int ib = ia + half;
    float2 tw = Trow[(192 >> st) * pos];
    #pragma unroll
    for (int c = 0; c < 4; ++c){
      float2 a = work[c][ia], b = cmul(work[c][ib], tw);
      work[c][ia] = make_float2(a.x + b.x, a.y + b.y);
      work[c][ib] = make_float2(a.x - b.x, a.y - b.y);
    }
    __syncthreads();
  }
  int k1a = t & 127, k1b = (t + 192) & 127;
  float2 w1 = Trow[t], w2 = Trow[(2*t) % 384];
  float2 Xa[4], Xb[4];
  #pragma unroll
  for (int c = 0; c < 4; ++c){
    float2 p1 = cmul(w1, work[c][128 + k1a]);
    float2 p2 = cmul(w2, work[c][256 + k1a]);
    float2 y0 = work[c][k1a];
    Xa[c] = make_float2(y0.x + p1.x + p2.x, y0.y + p1.y + p2.y);
    float2 q1 = cmul(w1, work[c][128 + k1b]);
    float2 q2 = cmul(w2, work[c][256 + k1b]);
    float2 z0 = work[c][k1b];
    Xb[c] = make_float2(z0.x - q1.x + q2.x, z0.y - q1.y + q2.y);
  }
  __syncthreads();
  #pragma unroll
  for (int c = 0; c < 4; ++c){ work[c][t] = Xa[c]; work[c][t + 192] = Xb[c]; }
  __syncthreads();
  int tm = (t == 0) ? 0 : (384 - t);
  #pragma unroll
  for (int c = 0; c < 4; ++c){
    float2 Zk = Xa[c];
    float2 Zm = work[c][tm];
    size_t b0r = ((size_t)bcl*NS + rg*8 + 2*c)*KWH;
    size_t b1r = b0r + KWH;
    A[b0r + t] = make_float2(0.5f*(Zk.x + Zm.x), 0.5f*(Zk.y - Zm.y));
    A[b1r + t] = make_float2(0.5f*(Zk.y + Zm.y), 0.5f*(Zm.x - Zk.x));
    if (t == 0){
      float2 Zn = Xb[c];
      A[b0r + 192] = make_float2(Zn.x, 0.f);
      A[b1r + 192] = make_float2(Zn.y, 0.f);
    }
  }
}

// Column FFT for kw in [0,192], 8 columns/block. Epilogue now transposes the
// mags through LDS (mg[384][9]) and writes B in ROW-SEGMENTS:
//  - main band: 8 consecutive cols at v = kw0+192, two aligned float4 per row
//  - mirror band (conj symmetry): row-reversed copy of main band at
//    v2 = 185-kw0..192-kw0, col-reversed; no recompute needed since
//    B[u][192-kw] = B[(384-u)%384][kw+192].
// This cuts HBM write amplification 16x -> 2x (was WRITE_SIZE 410 MB vs
// 56.6 MB of data in round 11).
__global__ __launch_bounds__(192) void k_dft_cols(const float2* __restrict__ A,
    const float2* __restrict__ T, float* __restrict__ Bm,
    float* __restrict__ stats, int bc0){
  __shared__ float2 work[8][384];
  __shared__ float mg[384][9];             // +1 pad col: stride-9 -> 2-way banks
  __shared__ float rs[6];
  const float2* Trow = T + NS;
  int blk = blockIdx.x;
  int bcl = blk / 25, cg = blk % 25;
  int bc = bc0 + bcl;
  int kw0 = cg*8;
  int cols = (cg == 24) ? 1 : 8;
  int t = threadIdx.x;
  const float2* Al = A + (size_t)bcl*NS*KWH;
  if (cols == 8){
    #pragma unroll
    for (int i = 0; i < 16; ++i){
      int lin = i*192 + t;
      int h = lin >> 3, c = lin & 7;
      int r = h % 3;
      work[c][r*128 + (__brev((unsigned)(h/3)) >> 25)] = Al[(size_t)h*KWH + kw0 + c];
    }
  } else {
    for (int h = t; h < NS; h += 192){
      int r = h % 3;
      work[0][r*128 + (__brev((unsigned)(h/3)) >> 25)] = Al[(size_t)h*KWH + kw0];
    }
  }
  __syncthreads();
  int sub = t >> 6, j = t & 63;
  #pragma unroll
  for (int st = 0; st < 7; ++st){
    int half = 1 << st;
    int pos = j & (half - 1);
    int ia = sub*128 + (((j >> st) << (st + 1)) | pos);
    int ib = ia + half;
    float2 tw = Trow[(192 >> st) * pos];
    #pragma unroll
    for (int c = 0; c < 8; ++c){
      if (c < cols){
        float2 a = work[c][ia], b = cmul(work[c][ib], tw);
        work[c][ia] = make_float2(a.x + b.x, a.y + b.y);
        work[c][ib] = make_float2(a.x - b.x, a.y - b.y);
      }
    }
    __syncthreads();
  }
  // combine + mag into LDS transpose buffer; stats with mirror weight 2
  int k1a = t & 127, k1b = (t + 192) & 127;
  float2 w1 = Trow[t], w2 = Trow[(2*t) % 384];
  float s1 = 0.f, s2 = 0.f;
  #pragma unroll
  for (int c = 0; c < 8; ++c){
    if (c < cols){
      float2 p1 = cmul(w1, work[c][128 + k1a]);
      float2 p2 = cmul(w2, work[c][256 + k1a]);
      float2 y0 = work[c][k1a];
      float2 Xa = make_float2(y0.x + p1.x + p2.x, y0.y + p1.y + p2.y);
      float2 q1 = cmul(w1, work[c][128 + k1b]);
      float2 q2 = cmul(w2, work[c][256 + k1b]);
      float2 z0 = work[c][k1b];
      float2 Xb = make_float2(z0.x - q1.x + q2.x, z0.y - q1.y + q2.y);
      float ma = logf(sqrtf(Xa.x*Xa.x + Xa.y*Xa.y) + 1.f);   // kh = t     -> u = t+192
      float mb = logf(sqrtf(Xb.x*Xb.x + Xb.y*Xb.y) + 1.f);   // kh = t+192 -> u = t
      int kw = kw0 + c;
      float wgt = (kw >= 1 && kw <= 191) ? 2.f : 1.f;
      s1 += wgt*(ma + mb);
      s2 += wgt*(ma*ma + mb*mb);
      mg[t + 192][c] = ma;
      mg[t][c]       = mb;
    }
  }
  __syncthreads();
  // write phase: each thread owns rows u = t and t+192
  float* Bbc = Bm + (size_t)bc*HWSZ;
  if (cols == 8){
    int vm = kw0 + 192;                    // main band start (mult of 8 -> 32B aligned)
    int v2lo = 185 - kw0;                  // mirror band start
    int jmax = (kw0 == 0) ? 7 : 8;         // kw0==0: col c=0 (kw=0) has no mirror
    #pragma unroll
    for (int rr = 0; rr < 2; ++rr){
      int u = t + rr*192;
      float* row = Bbc + (size_t)u*NS;
      float4 a0 = make_float4(mg[u][0], mg[u][1], mg[u][2], mg[u][3]);
      float4 a1 = make_float4(mg[u][4], mg[u][5], mg[u][6], mg[u][7]);
      *(float4*)(row + vm)     = a0;
      *(float4*)(row + vm + 4) = a1;
      int um = (u == 0) ? 0 : 384 - u;     // mirror source row
      #pragma unroll
      for (int j2 = 0; j2 < 8; ++j2){
        if (j2 < jmax) row[v2lo + j2] = mg[um][7 - j2];
      }
    }
  } else {                                 // kw = 192 -> shifted col v = 0
    #pragma unroll
    for (int rr = 0; rr < 2; ++rr){
      int u = t + rr*192;
      Bbc[(size_t)u*NS] = mg[u][0];
    }
  }
  float w1s = wave_sum(s1), w2s = wave_sum(s2);
  if ((t & 63) == 0){ rs[t >> 6] = w1s; rs[3 + (t >> 6)] = w2s; }
  __syncthreads();
  if (t == 0){
    atomicAdd(&stats[bc*2],     rs[0] + rs[1] + rs[2]);
    atomicAdd(&stats[bc*2 + 1], rs[3] + rs[4] + rs[5]);
  }
}

__global__ void k_finalize(const float* __restrict__ stats, const float* __restrict__ rgbsum,
                           float* __restrict__ ss, float* __restrict__ rgbmean){
  int t = threadIdx.x;
  if (t < NIMG){
    const float inv_n = 1.f / 147456.f;
    float mean = stats[t*2] * inv_n;
    float var  = fmaxf(stats[t*2 + 1] * inv_n - mean*mean, 0.f);
    float inv  = 1.f / (sqrtf(var) + 1e-8f);
    ss[t*2]     = inv;
    ss[t*2 + 1] = -mean * inv;
    rgbmean[t]  = rgbsum[t] * inv_n;
  }
}

// Pack conv1 weights to bf16 [64][192]: k' = (ic*7+kh)*8 + kw, kw==7 -> 0.
__global__ void k_w1prep(const float* __restrict__ w1, unsigned short* __restrict__ w1p){
  int idx = blockIdx.x*256 + (int)threadIdx.x;
  if (idx >= 64*192) return;
  int oc = idx / 192, k = idx - oc*192;
  int rk = k >> 3, kw = k & 7;
  float val = 0.f;
  if (rk < 21 && kw < 7){
    int ic = rk / 7, kh = rk - 7*ic;
    val = w1[oc*147 + ic*49 + kh*7 + kw];
  }
  w1p[idx] = f2bf(val);
}

// Pack conv2 weights, split hi/lo bf16: [128][576], k = tap*64 + ic.
__global__ void k_w2prep(const float* __restrict__ w2,
    unsigned short* __restrict__ w2ph, unsigned short* __restrict__ w2pl){
  int idx = blockIdx.x*256 + (int)threadIdx.x;
  if (idx >= 128*576) return;
  int oc = idx / 576, k = idx - oc*576;
  int tap = k >> 6, ic = k & 63;
  float w = w2[(size_t)oc*576 + ic*9 + tap];
  unsigned short hi = f2bf(w);
  w2ph[idx] = hi;
  w2pl[idx] = f2bf(w - bf2f(hi));
}

// conv1(7x7,s2,p3)+BN+ReLU via MFMA 16x16x32 bf16 (unchanged from round 11).
__global__ __launch_bounds__(256) void k_conv1mfma(const float* __restrict__ Bm,
    const float* __restrict__ ss, const unsigned short* __restrict__ w1p,
    const float* __restrict__ b1, const float* __restrict__ g1,
    const float* __restrict__ bb1, unsigned short* __restrict__ E, int b0){
  __shared__ unsigned short pt[3*37*40];
  int blk = blockIdx.x;
  int li = blk / 144, rem = blk - li*144;
  int rg = rem / 12, cg = rem - rg*12;
  int r0 = rg*16, c0 = cg*16;
  int b = b0 + li;
  int t = threadIdx.x;
  float sc[3], sh[3];
  #pragma unroll
  for (int ic = 0; ic < 3; ++ic){ sc[ic] = ss[(b*3 + ic)*2]; sh[ic] = ss[(b*3 + ic)*2 + 1]; }
  const int h0 = 2*r0 - 3, w0 = 2*c0 - 3;
  const float* Bb = Bm + (size_t)b*3*HWSZ;
  for (int lin = t; lin < 3*37*40; lin += 256){
    int ic = lin / 1480; int r = lin - ic*1480;
    int hr = r / 40, wc = r - hr*40;
    int hg = h0 + hr, wg = w0 + wc;
    bool v = (wc < 38) && ((unsigned)hg < (unsigned)NS) && ((unsigned)wg < (unsigned)NS);
    float raw = v ? Bb[(size_t)ic*HWSZ + (size_t)hg*NS + wg] : 0.f;
    pt[lin] = v ? f2bf(fmaf(raw, sc[ic], sh[ic])) : (unsigned short)0;
  }
  __syncthreads();

  int wave = t >> 6, lane = t & 63;
  int lm = lane & 15, lg = lane >> 4;
  U16 bf[6];
  #pragma unroll
  for (int ks = 0; ks < 6; ++ks)
    bf[ks].q = *(const uint4*)(w1p + (wave*16 + lm)*192 + ks*32 + lg*8);
  int cbase[6];
  #pragma unroll
  for (int ks = 0; ks < 6; ++ks){
    int rk = ks*4 + lg;
    if (rk > 20) rk = 20;
    int ic = rk / 7, kh = rk - 7*ic;
    cbase[ks] = ic*1480 + kh*40 + 2*lm;
  }
  const float bneps = rsqrtf(1.f + 1e-5f);
  float4 b4  = *(const float4*)(b1  + wave*16 + lg*4);
  float4 g4  = *(const float4*)(g1  + wave*16 + lg*4);
  float4 bb4 = *(const float4*)(bb1 + wave*16 + lg*4);
  float4 gs4 = make_float4(g4.x*bneps, g4.y*bneps, g4.z*bneps, g4.w*bneps);
  unsigned short* Eb = E + (((size_t)li*C1DIM + r0)*C1DIM + c0 + lm)*64 + wave*16 + lg*4;

  #pragma unroll 1
  for (int rt = 0; rt < 16; ++rt){
    f32x4_t acc = {b4.x, b4.y, b4.z, b4.w};
    #pragma unroll
    for (int ks = 0; ks < 6; ++ks){
      U16 a;
      const unsigned* pp = (const unsigned*)&pt[cbase[ks] + 80*rt];
      a.u[0] = pp[0]; a.u[1] = pp[1]; a.u[2] = pp[2]; a.u[3] = pp[3];
      acc = __builtin_amdgcn_mfma_f32_16x16x32_bf16(bf[ks].v, a.v, acc, 0, 0, 0);
    }
    ushort4 o;
    o.x = f2bf(fmaxf(fmaf(acc[0], gs4.x, bb4.x), 0.f));
    o.y = f2bf(fmaxf(fmaf(acc[1], gs4.y, bb4.y), 0.f));
    o.z = f2bf(fmaxf(fmaf(acc[2], gs4.z, bb4.z), 0.f));
    o.w = f2bf(fmaxf(fmaf(acc[3], gs4.w, bb4.w), 0.f));
    *(ushort4*)(Eb + (size_t)rt*C1DIM*64) = o;
  }
}

// conv2(3x3,p1)+BN+ReLU + global-avg-pool via MFMA (unchanged from round 11).
__global__ __launch_bounds__(512) void k_conv2mfma(const unsigned short* __restrict__ E,
    const unsigned short* __restrict__ w2ph, const unsigned short* __restrict__ w2pl,
    const float* __restrict__ b2, const float* __restrict__ g2,
    const float* __restrict__ bb2, float* __restrict__ freq_acc, int b0){
  __shared__ unsigned short sD[10*1152];   // [hp(10)][g(8)][wp(18)][8ic]
  int blk = blockIdx.x;
  int li = blk / 72, tile = blk - li*72;
  int rb = tile / 6, cb = tile - rb*6;
  int r0 = rb*8, c0 = cb*16;
  int b = b0 + li;
  int t = threadIdx.x;
  const unsigned short* Eb = E + (size_t)li*C1DIM*C1DIM*64;
  for (int lin = t; lin < 1440; lin += 512){
    int g = lin & 7; int rm = lin >> 3;
    int wp = rm % 18, hp = rm / 18;
    int ph = r0 + hp - 1, pw = c0 + wp - 1;
    uint4 mx = make_uint4(0u,0u,0u,0u);
    if ((unsigned)ph < (unsigned)PDIM && (unsigned)pw < (unsigned)PDIM){
      #pragma unroll
      for (int dh = 0; dh < 3; ++dh){
        int eh = 2*ph - 1 + dh;
        if ((unsigned)eh >= (unsigned)C1DIM) continue;
        #pragma unroll
        for (int dw = 0; dw < 3; ++dw){
          int ew = 2*pw - 1 + dw;
          if ((unsigned)ew >= (unsigned)C1DIM) continue;
          uint4 v = *(const uint4*)(Eb + ((size_t)eh*C1DIM + ew)*64 + g*8);
          mx = pmax8(mx, v);
        }
      }
    }
    *(uint4*)&sD[hp*1152 + g*144 + wp*8] = mx;
  }
  __syncthreads();

  int wave = t >> 6, lane = t & 63;
  int lm = lane & 15, lg = lane >> 4;
  int octile = wave*16;
  const float bneps = rsqrtf(1.f + 1e-5f);
  float4 b4  = *(const float4*)(b2  + octile + lg*4);
  float4 g4  = *(const float4*)(g2  + octile + lg*4);
  float4 bb4 = *(const float4*)(bb2 + octile + lg*4);
  f32x4_t acc[8];
  #pragma unroll
  for (int nt = 0; nt < 8; ++nt){
    acc[nt][0] = b4.x; acc[nt][1] = b4.y; acc[nt][2] = b4.z; acc[nt][3] = b4.w;
  }
  const unsigned short* whp = w2ph + (size_t)(octile + lm)*576;
  const unsigned short* wlp = w2pl + (size_t)(octile + lm)*576;
  #pragma unroll
  for (int ks = 0; ks < 18; ++ks){
    const int tap = ks >> 1, h32 = ks & 1;
    const int dh = tap / 3, dw = tap - 3*(tap/3);
    U16 wh, wl;
    wh.q = *(const uint4*)(whp + ks*32 + lg*8);
    wl.q = *(const uint4*)(wlp + ks*32 + lg*8);
    int base = (h32*4 + lg)*144 + (lm + dw)*8;
    #pragma unroll
    for (int nt = 0; nt < 8; ++nt){
      U16 a;
      a.q = *(const uint4*)&sD[(nt + dh)*1152 + base];
      acc[nt] = __builtin_amdgcn_mfma_f32_16x16x32_bf16(wh.v, a.v, acc[nt], 0, 0, 0);
      acc[nt] = __builtin_amdgcn_mfma_f32_16x16x32_bf16(wl.v, a.v, acc[nt], 0, 0, 0);
    }
  }
  float s0 = 0.f, s1 = 0.f, s2 = 0.f, s3 = 0.f;
  float gx = g4.x*bneps, gy = g4.y*bneps, gz = g4.z*bneps, gw = g4.w*bneps;
  #pragma unroll
  for (int nt = 0; nt < 8; ++nt){
    s0 += fmaxf(fmaf(acc[nt][0], gx, bb4.x), 0.f);
    s1 += fmaxf(fmaf(acc[nt][1], gy, bb4.y), 0.f);
    s2 += fmaxf(fmaf(acc[nt][2], gz, bb4.z), 0.f);
    s3 += fmaxf(fmaf(acc[nt][3], gw, bb4.w), 0.f);
  }
  #pragma unroll
  for (int off = 1; off < 16; off <<= 1){
    s0 += __shfl_xor(s0, off);
    s1 += __shfl_xor(s1, off);
    s2 += __shfl_xor(s2, off);
    s3 += __shfl_xor(s3, off);
  }
  if (lm == 0){
    float* fa = freq_acc + (size_t)b*C2OUT + octile + lg*4;
    atomicAdd(fa + 0, s0); atomicAdd(fa + 1, s1);
    atomicAdd(fa + 2, s2); atomicAdd(fa + 3, s3);
  }
}

// RGB head + concat + 3-layer MLP, one block per batch sample.
__global__ __launch_bounds__(256) void k_mlp(const float* __restrict__ rgbmean,
    const float* __restrict__ freq_acc, const float* __restrict__ w_rgb,
    const float* __restrict__ b_rgb, const float* __restrict__ fc1w,
    const float* __restrict__ fc1b, const float* __restrict__ fc2w,
    const float* __restrict__ fc2b, const float* __restrict__ fc3w,
    const float* __restrict__ fc3b, float* __restrict__ out){
  __shared__ float z[130], z1[256], z2[128];
  int b = blockIdx.x, t = threadIdx.x;
  if (t < 2){
    float s = b_rgb[t];
    #pragma unroll
    for (int c = 0; c < 3; ++c) s += rgbmean[b*3 + c] * w_rgb[c*2 + t];
    z[t] = s;
  }
  if (t < 128) z[2 + t] = freq_acc[b*C2OUT + t] * (1.f/9216.f);
  __syncthreads();
  { float s = fc1b[t];
    for (int k = 0; k < 130; ++k) s = fmaf(z[k], fc1w[k*256 + t], s);
    z1[t] = fmaxf(s, 0.f); }
  __syncthreads();
  if (t < 128){
    float s = fc2b[t];
    for (int k = 0; k < 256; ++k) s = fmaf(z1[k], fc2w[k*128 + t], s);
    z2[t] = fmaxf(s, 0.f); }
  __syncthreads();
  if (t < 2){
    float s = fc3b[t];
    for (int k = 0; k < 128; ++k) s = fmaf(z2[k], fc3w[k*2 + t], s);
    out[b*2 + t] = s; }
}

extern "C" void kernel_launch(void* const* d_in, const int* in_sizes, int n_in,
                              void* d_out, int out_size, void* d_ws, size_t ws_size,
                              hipStream_t stream){
  const float* x     = (const float*)d_in[0];
  const float* w_rgb = (const float*)d_in[1];
  const float* b_rgb = (const float*)d_in[2];
  const float* w1    = (const float*)d_in[3];
  const float* b1    = (const float*)d_in[4];
  const float* g1    = (const float*)d_in[5];
  const float* bb1   = (const float*)d_in[6];
  const float* w2    = (const float*)d_in[7];
  const float* b2    = (const float*)d_in[8];
  const float* g2    = (const float*)d_in[9];
  const float* bb2   = (const float*)d_in[10];
  const float* fc1w  = (const float*)d_in[11];
  const float* fc1b  = (const float*)d_in[12];
  const float* fc2w  = (const float*)d_in[13];
  const float* fc2b  = (const float*)d_in[14];
  const float* fc3w  = (const float*)d_in[15];
  const float* fc3b  = (const float*)d_in[16];

  const bool full = (ws_size >= NEED_F);
  const int dftloop = full ? 1 : 4;
  const int dftCH   = full ? 96 : 24;
  const int cvloop  = full ? 4 : 16;
  const int cvB     = full ? 8 : 2;

  char* ws = (char*)d_ws;
  float2* T  = (float2*)(ws + OFF_T);
  float*  Bm = (float*)(ws + OFF_B);
  float2* A  = (float2*)(ws + OFF_S);
  unsigned short* E    = (unsigned short*)(ws + OFF_S + OFF_E);
  const size_t offw    = OFF_S + (full ? OFF_W_F : OFF_W_C);
  unsigned short* w1p  = (unsigned short*)(ws + offw);
  unsigned short* w2ph = (unsigned short*)(ws + offw + 24576);
  unsigned short* w2pl = (unsigned short*)(ws + offw + 24576 + 147456);
  float*  sm = (float*)(ws + (full ? OFF_SM_F : OFF_SM_C));
  float* rgbsum = sm;            // 96
  float* stats  = sm + 96;       // 192
  float* freqa  = sm + 288;      // 4096
  float* rgbm   = sm + 4384;     // 96
  float* ssb    = sm + 4480;     // 192

  hipMemsetAsync(sm, 0, 4672*sizeof(float), stream);
  k_twiddle<<<2, 256, 0, stream>>>(T);
  for (int c = 0; c < dftloop; ++c){
    k_dft_rows<<<dftCH*48, 192, 0, stream>>>(x, T, A, rgbsum, c*dftCH);
    k_dft_cols<<<dftCH*25, 192, 0, stream>>>(A, T, Bm, stats, c*dftCH);
  }
  k_finalize<<<1, 128, 0, stream>>>(stats, rgbsum, ssb, rgbm);
  k_w1prep<<<48, 256, 0, stream>>>(w1, w1p);
  k_w2prep<<<288, 256, 0, stream>>>(w2, w2ph, w2pl);
  for (int c = 0; c < cvloop; ++c){
    k_conv1mfma<<<cvB*144, 256, 0, stream>>>(Bm, ssb, w1p, b1, g1, bb1, E, c*cvB);
    k_conv2mfma<<<cvB*72, 512, 0, stream>>>(E, w2ph, w2pl, b2, g2, bb2, freqa, c*cvB);
  }
  k_mlp<<<NB, 256, 0, stream>>>(rgbm, freqa, w_rgb, b_rgb, fc1w, fc1b,
                                fc2w, fc2b, fc3w, fc3b, (float*)d_out);
}

// Round 13
// 404.912 us; speedup vs baseline: 22.5335x; 1.1837x over previous
//
#include <hip/hip_runtime.h>
#include <math.h>

// Problem dims
#define NB    32
#define NC    3
#define NIMG  (NB*NC)      // 96 image-channels
#define NS    384
#define HWSZ  (NS*NS)      // 147456
#define C1OUT 64
#define C1DIM 192
#define PDIM  96
#define PHW   (PDIM*PDIM)  // 9216
#define C2OUT 128
#define KWH   193          // stored half-spectrum width in A (kw = 0..192)
#define BHW   192          // stored half-spectrum width in Bh (v = 192..383)
#define PI_F  3.14159265358979323846f

// ---- workspace layout (bytes) ----
// T region @0 (1,179,648 B): twiddle row f2[768] @0 (6KB used),
//   w1p bf16[64][192] @8192, w2ph @32768, w2pl @180224 (ends 327,680)
// B region @OFF_B: Bh f32[96][384][192] = 28,311,552 + col0 f32[96][384]=147,456
// S region @OFF_S (75,497,472 B, time-shared):
//   dft phase : A float2[96][384][193] = 56,918,016 (full) / [24] (chunked)
//   conv phase: E bf16[16][192][192][64] = 75,497,472 (full) / [2] (chunked)
// smalls @OFF_SM: rgbsum[96] stats[192] freqacc[4096] rgbmean[96] ss[192]
static const size_t OFF_T    = 0;
static const size_t OFF_TW1  = 8192;
static const size_t OFF_TW2H = 32768;
static const size_t OFF_TW2L = 180224;
static const size_t OFF_B    = 1179648;
static const size_t OFF_C0   = 1179648 + 28311552;   // col0
static const size_t OFF_S    = 57802752;
static const size_t OFF_SM_F = 133300224;
static const size_t OFF_SM_C = 76677120;
static const size_t NEED_F   = 133318912;

// padded LDS index for FFT work arrays: breaks 2^k-stride bank conflicts
#define WI(i) ((i) + ((i) >> 4))

typedef __attribute__((ext_vector_type(8))) short bf16x8_t;
typedef __attribute__((ext_vector_type(4))) float f32x4_t;
union U16 { unsigned u[4]; uint4 q; bf16x8_t v; };

__device__ __forceinline__ float wave_sum(float v){
  #pragma unroll
  for (int off = 32; off; off >>= 1) v += __shfl_down(v, off);
  return v;
}
__device__ __forceinline__ unsigned short f2bf(float f){
  unsigned u = __float_as_uint(f);
  u += 0x7FFFu + ((u >> 16) & 1u);
  return (unsigned short)(u >> 16);
}
__device__ __forceinline__ float bf2f(unsigned short h){
  return __uint_as_float(((unsigned)h) << 16);
}
__device__ __forceinline__ unsigned pmax16(unsigned a, unsigned b){
  unsigned al = a & 0xffffu, ah = a >> 16, bl = b & 0xffffu, bh = b >> 16;
  unsigned ml = al > bl ? al : bl, mh = ah > bh ? ah : bh;
  return (mh << 16) | ml;
}
__device__ __forceinline__ uint4 pmax8(uint4 a, uint4 b){
  uint4 r;
  r.x = pmax16(a.x, b.x); r.y = pmax16(a.y, b.y);
  r.z = pmax16(a.z, b.z); r.w = pmax16(a.w, b.w);
  return r;
}
// proper mod-384 for v in [0, 768): NOT "& 383" (384 not a power of two).
__device__ __forceinline__ int mod384(int v){ return v >= NS ? v - NS : v; }
__device__ __forceinline__ float2 cmul(float2 a, float2 b){
  return make_float2(a.x*b.x - a.y*b.y, a.x*b.y + a.y*b.x);
}

// Merged prep: twiddle row W384^m + conv1 bf16 weight pack + conv2 hi/lo split.
__global__ void k_prep(const float* __restrict__ w1, const float* __restrict__ w2,
    float2* __restrict__ T, unsigned short* __restrict__ w1p,
    unsigned short* __restrict__ w2ph, unsigned short* __restrict__ w2pl){
  int idx = blockIdx.x*256 + (int)threadIdx.x;
  if (idx < NS){
    float ang = -2.0f*PI_F*(float)idx/(float)NS;
    T[NS + idx] = make_float2(cosf(ang), sinf(ang));
  }
  if (idx < 64*192){
    int oc = idx / 192, k = idx - oc*192;
    int rk = k >> 3, kw = k & 7;
    float val = 0.f;
    if (rk < 21 && kw < 7){
      int ic = rk / 7, kh = rk - 7*ic;
      val = w1[oc*147 + ic*49 + kh*7 + kw];
    }
    w1p[idx] = f2bf(val);
  }
  if (idx < 128*576){
    int oc = idx / 576, k = idx - oc*576;
    int tap = k >> 6, ic = k & 63;
    float w = w2[(size_t)oc*576 + ic*9 + tap];
    unsigned short hi = f2bf(w);
    w2ph[idx] = hi;
    w2pl[idx] = f2bf(w - bf2f(hi));
  }
}

// Row FFT (along W, real input): 8 rows/block as 4 packed complex FFTs.
// work[] padded via WI() to break butterfly bank conflicts.
__global__ __launch_bounds__(192) void k_dft_rows(const float* __restrict__ x,
    const float2* __restrict__ T, float2* __restrict__ A,
    float* __restrict__ rgbsum, int bc0){
  __shared__ float2 work[4][408];          // WI(383)=406 max
  __shared__ float rs[3];
  const float2* Trow = T + NS;             // W384^m
  int blk = blockIdx.x;
  int bcl = blk / 48, rg = blk % 48;
  int bc = bc0 + bcl;
  int t = threadIdx.x;
  const float* xp = x + (size_t)bc*HWSZ + (size_t)rg*8*NS;
  int nA = t,        rA = nA % 3, iA = (rA*128) + (__brev((unsigned)(nA/3)) >> 25);
  int nB = t + 192,  rB = nB % 3, iB = (rB*128) + (__brev((unsigned)(nB/3)) >> 25);
  float lsum = 0.f;
  #pragma unroll
  for (int c = 0; c < 4; ++c){
    float a0 = xp[(2*c)*NS + nA],   b0 = xp[(2*c+1)*NS + nA];
    float a1 = xp[(2*c)*NS + nB],   b1 = xp[(2*c+1)*NS + nB];
    work[c][WI(iA)] = make_float2(a0, b0);
    work[c][WI(iB)] = make_float2(a1, b1);
    lsum += a0 + b0 + a1 + b1;
  }
  float ws = wave_sum(lsum);
  if ((t & 63) == 0) rs[t >> 6] = ws;
  __syncthreads();
  if (t == 0) atomicAdd(&rgbsum[bc], rs[0] + rs[1] + rs[2]);

  int sub = t >> 6, j = t & 63;
  #pragma unroll
  for (int st = 0; st < 7; ++st){
    int half = 1 << st;
    int pos = j & (half - 1);
    int ia = sub*128 + (((j >> st) << (st + 1)) | pos);
    int ib = ia + half;
    float2 tw = Trow[(192 >> st) * pos];
    #pragma unroll
    for (int c = 0; c < 4; ++c){
      float2 a = work[c][WI(ia)], b = cmul(work[c][WI(ib)], tw);
      work[c][WI(ia)] = make_float2(a.x + b.x, a.y + b.y);
      work[c][WI(ib)] = make_float2(a.x - b.x, a.y - b.y);
    }
    __syncthreads();
  }
  int k1a = t & 127, k1b = (t + 192) & 127;
  float2 w1 = Trow[t], w2 = Trow[(2*t) % 384];
  float2 Xa[4], Xb[4];
  #pragma unroll
  for (int c = 0; c < 4; ++c){
    float2 p1 = cmul(w1, work[c][WI(128 + k1a)]);
    float2 p2 = cmul(w2, work[c][WI(256 + k1a)]);
    float2 y0 = work[c][WI(k1a)];
    Xa[c] = make_float2(y0.x + p1.x + p2.x, y0.y + p1.y + p2.y);
    float2 q1 = cmul(w1, work[c][WI(128 + k1b)]);
    float2 q2 = cmul(w2, work[c][WI(256 + k1b)]);
    float2 z0 = work[c][WI(k1b)];
    Xb[c] = make_float2(z0.x - q1.x + q2.x, z0.y - q1.y + q2.y);
  }
  __syncthreads();
  #pragma unroll
  for (int c = 0; c < 4; ++c){ work[c][WI(t)] = Xa[c]; work[c][WI(t + 192)] = Xb[c]; }
  __syncthreads();
  int tm = (t == 0) ? 0 : (384 - t);
  #pragma unroll
  for (int c = 0; c < 4; ++c){
    float2 Zk = Xa[c];
    float2 Zm = work[c][WI(tm)];
    size_t b0r = ((size_t)bcl*NS + rg*8 + 2*c)*KWH;
    size_t b1r = b0r + KWH;
    A[b0r + t] = make_float2(0.5f*(Zk.x + Zm.x), 0.5f*(Zk.y - Zm.y));
    A[b1r + t] = make_float2(0.5f*(Zk.y + Zm.y), 0.5f*(Zm.x - Zk.x));
    if (t == 0){
      float2 Zn = Xb[c];
      A[b0r + 192] = make_float2(Zn.x, 0.f);
      A[b1r + 192] = make_float2(Zn.y, 0.f);
    }
  }
}

// Column FFT for kw in [0,192], 8 columns/block. HALF-SPECTRUM output:
// only v = kw+192 (i.e. Bh col j = kw) plus col0 (v=0, kw=192) are written;
// the lower half v in [1,191] is reconstructed at conv1-read time via
// B[u][v] = B[(384-u)%384][(384-v)%384] (conjugate symmetry; same identity
// round-12's mirror writes used, which passed). Mag-transpose buffer reuses
// work[] (combine held in registers) -> LDS 26 KB, 6 blocks/CU.
__global__ __launch_bounds__(192) void k_dft_cols(const float2* __restrict__ A,
    const float2* __restrict__ T, float* __restrict__ Bh, float* __restrict__ col0,
    float* __restrict__ stats, int bc0){
  __shared__ float2 work[8][408];
  __shared__ float rs[6];
  float* mgp = (float*)work;               // overlay after combine: mg[u][c] = mgp[u*9+c]
  const float2* Trow = T + NS;
  int blk = blockIdx.x;
  int bcl = blk / 25, cg = blk % 25;
  int bc = bc0 + bcl;
  int kw0 = cg*8;
  int cols = (cg == 24) ? 1 : 8;
  int t = threadIdx.x;
  const float2* Al = A + (size_t)bcl*NS*KWH;
  if (cols == 8){
    #pragma unroll
    for (int i = 0; i < 16; ++i){
      int lin = i*192 + t;
      int h = lin >> 3, c = lin & 7;
      int r = h % 3;
      work[c][WI(r*128 + (__brev((unsigned)(h/3)) >> 25))] = Al[(size_t)h*KWH + kw0 + c];
    }
  } else {
    for (int h = t; h < NS; h += 192){
      int r = h % 3;
      work[0][WI(r*128 + (__brev((unsigned)(h/3)) >> 25))] = Al[(size_t)h*KWH + kw0];
    }
  }
  __syncthreads();
  int sub = t >> 6, j = t & 63;
  #pragma unroll
  for (int st = 0; st < 7; ++st){
    int half = 1 << st;
    int pos = j & (half - 1);
    int ia = sub*128 + (((j >> st) << (st + 1)) | pos);
    int ib = ia + half;
    float2 tw = Trow[(192 >> st) * pos];
    #pragma unroll
    for (int c = 0; c < 8; ++c){
      if (c < cols){
        float2 a = work[c][WI(ia)], b = cmul(work[c][WI(ib)], tw);
        work[c][WI(ia)] = make_float2(a.x + b.x, a.y + b.y);
        work[c][WI(ib)] = make_float2(a.x - b.x, a.y - b.y);
      }
    }
    __syncthreads();
  }
  // combine + mag into REGISTERS; stats with mirror weight 2
  int k1a = t & 127, k1b = (t + 192) & 127;
  float2 w1 = Trow[t], w2 = Trow[(2*t) % 384];
  float s1 = 0.f, s2 = 0.f;
  float ma[8], mb[8];
  #pragma unroll
  for (int c = 0; c < 8; ++c){
    ma[c] = 0.f; mb[c] = 0.f;
    if (c < cols){
      float2 p1 = cmul(w1, work[c][WI(128 + k1a)]);
      float2 p2 = cmul(w2, work[c][WI(256 + k1a)]);
      float2 y0 = work[c][WI(k1a)];
      float2 Xa = make_float2(y0.x + p1.x + p2.x, y0.y + p1.y + p2.y);
      float2 q1 = cmul(w1, work[c][WI(128 + k1b)]);
      float2 q2 = cmul(w2, work[c][WI(256 + k1b)]);
      float2 z0 = work[c][WI(k1b)];
      float2 Xb = make_float2(z0.x - q1.x + q2.x, z0.y - q1.y + q2.y);
      ma[c] = logf(sqrtf(Xa.x*Xa.x + Xa.y*Xa.y) + 1.f);   // kh = t     -> u = t+192
      mb[c] = logf(sqrtf(Xb.x*Xb.x + Xb.y*Xb.y) + 1.f);   // kh = t+192 -> u = t
      int kw = kw0 + c;
      float wgt = (kw >= 1 && kw <= 191) ? 2.f : 1.f;
      s1 += wgt*(ma[c] + mb[c]);
      s2 += wgt*(ma[c]*ma[c] + mb[c]*mb[c]);
    }
  }
  __syncthreads();                         // done reading work
  #pragma unroll
  for (int c = 0; c < 8; ++c){
    if (c < cols){
      mgp[(t + 192)*9 + c] = ma[c];
      mgp[t*9 + c]         = mb[c];
    }
  }
  __syncthreads();
  // write phase: each thread owns rows u = t and t+192; main band only
  if (cols == 8){
    float* Bhc = Bh + (size_t)bc*NS*BHW;
    #pragma unroll
    for (int rr = 0; rr < 2; ++rr){
      int u = t + rr*192;
      float* row = Bhc + (size_t)u*BHW + kw0;     // j = kw -> v = kw+192
      *(float4*)(row)     = make_float4(mgp[u*9+0], mgp[u*9+1], mgp[u*9+2], mgp[u*9+3]);
      *(float4*)(row + 4) = make_float4(mgp[u*9+4], mgp[u*9+5], mgp[u*9+6], mgp[u*9+7]);
    }
  } else {                                 // kw = 192 -> shifted col v = 0
    float* c0c = col0 + (size_t)bc*NS;
    #pragma unroll
    for (int rr = 0; rr < 2; ++rr){
      int u = t + rr*192;
      c0c[u] = mgp[u*9];
    }
  }
  float w1s = wave_sum(s1), w2s = wave_sum(s2);
  if ((t & 63) == 0){ rs[t >> 6] = w1s; rs[3 + (t >> 6)] = w2s; }
  __syncthreads();
  if (t == 0){
    atomicAdd(&stats[bc*2],     rs[0] + rs[1] + rs[2]);
    atomicAdd(&stats[bc*2 + 1], rs[3] + rs[4] + rs[5]);
  }
}

__global__ void k_finalize(const float* __restrict__ stats, const float* __restrict__ rgbsum,
                           float* __restrict__ ss, float* __restrict__ rgbmean){
  int t = threadIdx.x;
  if (t < NIMG){
    const float inv_n = 1.f / 147456.f;
    float mean = stats[t*2] * inv_n;
    float var  = fmaxf(stats[t*2 + 1] * inv_n - mean*mean, 0.f);
    float inv  = 1.f / (sqrtf(var) + 1e-8f);
    ss[t*2]     = inv;
    ss[t*2 + 1] = -mean * inv;
    rgbmean[t]  = rgbsum[t] * inv_n;
  }
}

// conv1(7x7,s2,p3)+BN+ReLU via MFMA 16x16x32 bf16. Staging gathers from the
// half-spectrum with reflection: wg>=192 -> Bh[hg][wg-192]; wg in [1,191] ->
// Bh[(384-hg)%384][192-wg]; wg==0 -> col0[hg].
__global__ __launch_bounds__(256) void k_conv1mfma(const float* __restrict__ Bh,
    const float* __restrict__ col0, const float* __restrict__ ss,
    const unsigned short* __restrict__ w1p, const float* __restrict__ b1,
    const float* __restrict__ g1, const float* __restrict__ bb1,
    unsigned short* __restrict__ E, int b0){
  __shared__ unsigned short pt[3*37*40];
  int blk = blockIdx.x;
  int li = blk / 144, rem = blk - li*144;
  int rg = rem / 12, cg = rem - rg*12;
  int r0 = rg*16, c0 = cg*16;
  int b = b0 + li;
  int t = threadIdx.x;
  float sc[3], sh[3];
  #pragma unroll
  for (int ic = 0; ic < 3; ++ic){ sc[ic] = ss[(b*3 + ic)*2]; sh[ic] = ss[(b*3 + ic)*2 + 1]; }
  const int h0 = 2*r0 - 3, w0 = 2*c0 - 3;
  for (int lin = t; lin < 3*37*40; lin += 256){
    int ic = lin / 1480; int r = lin - ic*1480;
    int hr = r / 40, wc = r - hr*40;
    int hg = h0 + hr, wg = w0 + wc;
    bool v = (wc < 38) && ((unsigned)hg < (unsigned)NS) && ((unsigned)wg < (unsigned)NS);
    float raw = 0.f;
    if (v){
      const float* Bc = Bh + (size_t)(b*3 + ic)*NS*BHW;
      if (wg >= 192)      raw = Bc[(size_t)hg*BHW + (wg - 192)];
      else if (wg >= 1)   raw = Bc[(size_t)mod384(NS - hg)*BHW + (192 - wg)];
      else                raw = col0[(size_t)(b*3 + ic)*NS + hg];
    }
    pt[lin] = v ? f2bf(fmaf(raw, sc[ic], sh[ic])) : (unsigned short)0;
  }
  __syncthreads();

  int wave = t >> 6, lane = t & 63;
  int lm = lane & 15, lg = lane >> 4;
  U16 bf[6];
  #pragma unroll
  for (int ks = 0; ks < 6; ++ks)
    bf[ks].q = *(const uint4*)(w1p + (wave*16 + lm)*192 + ks*32 + lg*8);
  int cbase[6];
  #pragma unroll
  for (int ks = 0; ks < 6; ++ks){
    int rk = ks*4 + lg;
    if (rk > 20) rk = 20;
    int ic = rk / 7, kh = rk - 7*ic;
    cbase[ks] = ic*1480 + kh*40 + 2*lm;
  }
  const float bneps = rsqrtf(1.f + 1e-5f);
  float4 b4  = *(const float4*)(b1  + wave*16 + lg*4);
  float4 g4  = *(const float4*)(g1  + wave*16 + lg*4);
  float4 bb4 = *(const float4*)(bb1 + wave*16 + lg*4);
  float4 gs4 = make_float4(g4.x*bneps, g4.y*bneps, g4.z*bneps, g4.w*bneps);
  unsigned short* Eb = E + (((size_t)li*C1DIM + r0)*C1DIM + c0 + lm)*64 + wave*16 + lg*4;

  #pragma unroll 1
  for (int rt = 0; rt < 16; ++rt){
    f32x4_t acc = {b4.x, b4.y, b4.z, b4.w};
    #pragma unroll
    for (int ks = 0; ks < 6; ++ks){
      U16 a;
      const unsigned* pp = (const unsigned*)&pt[cbase[ks] + 80*rt];
      a.u[0] = pp[0]; a.u[1] = pp[1]; a.u[2] = pp[2]; a.u[3] = pp[3];
      acc = __builtin_amdgcn_mfma_f32_16x16x32_bf16(bf[ks].v, a.v, acc, 0, 0, 0);
    }
    ushort4 o;
    o.x = f2bf(fmaxf(fmaf(acc[0], gs4.x, bb4.x), 0.f));
    o.y = f2bf(fmaxf(fmaf(acc[1], gs4.y, bb4.y), 0.f));
    o.z = f2bf(fmaxf(fmaf(acc[2], gs4.z, bb4.z), 0.f));
    o.w = f2bf(fmaxf(fmaf(acc[3], gs4.w, bb4.w), 0.f));
    *(ushort4*)(Eb + (size_t)rt*C1DIM*64) = o;
  }
}

// conv2(3x3,p1)+BN+ReLU + global-avg-pool via MFMA (unchanged from round 12).
__global__ __launch_bounds__(512) void k_conv2mfma(const unsigned short* __restrict__ E,
    const unsigned short* __restrict__ w2ph, const unsigned short* __restrict__ w2pl,
    const float* __restrict__ b2, const float* __restrict__ g2,
    const float* __restrict__ bb2, float* __restrict__ freq_acc, int b0){
  __shared__ unsigned short sD[10*1152];   // [hp(10)][g(8)][wp(18)][8ic]
  int blk = blockIdx.x;
  int li = blk / 72, tile = blk - li*72;
  int rb = tile / 6, cb = tile - rb*6;
  int r0 = rb*8, c0 = cb*16;
  int b = b0 + li;
  int t = threadIdx.x;
  const unsigned short* Eb = E + (size_t)li*C1DIM*C1DIM*64;
  for (int lin = t; lin < 1440; lin += 512){
    int g = lin & 7; int rm = lin >> 3;
    int wp = rm % 18, hp = rm / 18;
    int ph = r0 + hp - 1, pw = c0 + wp - 1;
    uint4 mx = make_uint4(0u,0u,0u,0u);
    if ((unsigned)ph < (unsigned)PDIM && (unsigned)pw < (unsigned)PDIM){
      #pragma unroll
      for (int dh = 0; dh < 3; ++dh){
        int eh = 2*ph - 1 + dh;
        if ((unsigned)eh >= (unsigned)C1DIM) continue;
        #pragma unroll
        for (int dw = 0; dw < 3; ++dw){
          int ew = 2*pw - 1 + dw;
          if ((unsigned)ew >= (unsigned)C1DIM) continue;
          uint4 v = *(const uint4*)(Eb + ((size_t)eh*C1DIM + ew)*64 + g*8);
          mx = pmax8(mx, v);
        }
      }
    }
    *(uint4*)&sD[hp*1152 + g*144 + wp*8] = mx;
  }
  __syncthreads();

  int wave = t >> 6, lane = t & 63;
  int lm = lane & 15, lg = lane >> 4;
  int octile = wave*16;
  const float bneps = rsqrtf(1.f + 1e-5f);
  float4 b4  = *(const float4*)(b2  + octile + lg*4);
  float4 g4  = *(const float4*)(g2  + octile + lg*4);
  float4 bb4 = *(const float4*)(bb2 + octile + lg*4);
  f32x4_t acc[8];
  #pragma unroll
  for (int nt = 0; nt < 8; ++nt){
    acc[nt][0] = b4.x; acc[nt][1] = b4.y; acc[nt][2] = b4.z; acc[nt][3] = b4.w;
  }
  const unsigned short* whp = w2ph + (size_t)(octile + lm)*576;
  const unsigned short* wlp = w2pl + (size_t)(octile + lm)*576;
  #pragma unroll
  for (int ks = 0; ks < 18; ++ks){
    const int tap = ks >> 1, h32 = ks & 1;
    const int dh = tap / 3, dw = tap - 3*(tap/3);
    U16 wh, wl;
    wh.q = *(const uint4*)(whp + ks*32 + lg*8);
    wl.q = *(const uint4*)(wlp + ks*32 + lg*8);
    int base = (h32*4 + lg)*144 + (lm + dw)*8;
    #pragma unroll
    for (int nt = 0; nt < 8; ++nt){
      U16 a;
      a.q = *(const uint4*)&sD[(nt + dh)*1152 + base];
      acc[nt] = __builtin_amdgcn_mfma_f32_16x16x32_bf16(wh.v, a.v, acc[nt], 0, 0, 0);
      acc[nt] = __builtin_amdgcn_mfma_f32_16x16x32_bf16(wl.v, a.v, acc[nt], 0, 0, 0);
    }
  }
  float s0 = 0.f, s1 = 0.f, s2 = 0.f, s3 = 0.f;
  float gx = g4.x*bneps, gy = g4.y*bneps, gz = g4.z*bneps, gw = g4.w*bneps;
  #pragma unroll
  for (int nt = 0; nt < 8; ++nt){
    s0 += fmaxf(fmaf(acc[nt][0], gx, bb4.x), 0.f);
    s1 += fmaxf(fmaf(acc[nt][1], gy, bb4.y), 0.f);
    s2 += fmaxf(fmaf(acc[nt][2], gz, bb4.z), 0.f);
    s3 += fmaxf(fmaf(acc[nt][3], gw, bb4.w), 0.f);
  }
  #pragma unroll
  for (int off = 1; off < 16; off <<= 1){
    s0 += __shfl_xor(s0, off);
    s1 += __shfl_xor(s1, off);
    s2 += __shfl_xor(s2, off);
    s3 += __shfl_xor(s3, off);
  }
  if (lm == 0){
    float* fa = freq_acc + (size_t)b*C2OUT + octile + lg*4;
    atomicAdd(fa + 0, s0); atomicAdd(fa + 1, s1);
    atomicAdd(fa + 2, s2); atomicAdd(fa + 3, s3);
  }
}

// RGB head + concat + 3-layer MLP, one block per batch sample.
__global__ __launch_bounds__(256) void k_mlp(const float* __restrict__ rgbmean,
    const float* __restrict__ freq_acc, const float* __restrict__ w_rgb,
    const float* __restrict__ b_rgb, const float* __restrict__ fc1w,
    const float* __restrict__ fc1b, const float* __restrict__ fc2w,
    const float* __restrict__ fc2b, const float* __restrict__ fc3w,
    const float* __restrict__ fc3b, float* __restrict__ out){
  __shared__ float z[130], z1[256], z2[128];
  int b = blockIdx.x, t = threadIdx.x;
  if (t < 2){
    float s = b_rgb[t];
    #pragma unroll
    for (int c = 0; c < 3; ++c) s += rgbmean[b*3 + c] * w_rgb[c*2 + t];
    z[t] = s;
  }
  if (t < 128) z[2 + t] = freq_acc[b*C2OUT + t] * (1.f/9216.f);
  __syncthreads();
  { float s = fc1b[t];
    for (int k = 0; k < 130; ++k) s = fmaf(z[k], fc1w[k*256 + t], s);
    z1[t] = fmaxf(s, 0.f); }
  __syncthreads();
  if (t < 128){
    float s = fc2b[t];
    for (int k = 0; k < 256; ++k) s = fmaf(z1[k], fc2w[k*128 + t], s);
    z2[t] = fmaxf(s, 0.f); }
  __syncthreads();
  if (t < 2){
    float s = fc3b[t];
    for (int k = 0; k < 128; ++k) s = fmaf(z2[k], fc3w[k*2 + t], s);
    out[b*2 + t] = s; }
}

extern "C" void kernel_launch(void* const* d_in, const int* in_sizes, int n_in,
                              void* d_out, int out_size, void* d_ws, size_t ws_size,
                              hipStream_t stream){
  const float* x     = (const float*)d_in[0];
  const float* w_rgb = (const float*)d_in[1];
  const float* b_rgb = (const float*)d_in[2];
  const float* w1    = (const float*)d_in[3];
  const float* b1    = (const float*)d_in[4];
  const float* g1    = (const float*)d_in[5];
  const float* bb1   = (const float*)d_in[6];
  const float* w2    = (const float*)d_in[7];
  const float* b2    = (const float*)d_in[8];
  const float* g2    = (const float*)d_in[9];
  const float* bb2   = (const float*)d_in[10];
  const float* fc1w  = (const float*)d_in[11];
  const float* fc1b  = (const float*)d_in[12];
  const float* fc2w  = (const float*)d_in[13];
  const float* fc2b  = (const float*)d_in[14];
  const float* fc3w  = (const float*)d_in[15];
  const float* fc3b  = (const float*)d_in[16];

  const bool full = (ws_size >= NEED_F);
  const int dftloop = full ? 1 : 4;
  const int dftCH   = full ? 96 : 24;
  const int cvloop  = full ? 2 : 16;       // E16 fits S exactly in full mode
  const int cvB     = full ? 16 : 2;

  char* ws = (char*)d_ws;
  float2* T  = (float2*)(ws + OFF_T);
  unsigned short* w1p  = (unsigned short*)(ws + OFF_TW1);
  unsigned short* w2ph = (unsigned short*)(ws + OFF_TW2H);
  unsigned short* w2pl = (unsigned short*)(ws + OFF_TW2L);
  float*  Bh   = (float*)(ws + OFF_B);
  float*  col0 = (float*)(ws + OFF_C0);
  float2* A    = (float2*)(ws + OFF_S);
  unsigned short* E = (unsigned short*)(ws + OFF_S);
  float*  sm = (float*)(ws + (full ? OFF_SM_F : OFF_SM_C));
  float* rgbsum = sm;            // 96
  float* stats  = sm + 96;       // 192
  float* freqa  = sm + 288;      // 4096
  float* rgbm   = sm + 4384;     // 96
  float* ssb    = sm + 4480;     // 192

  hipMemsetAsync(sm, 0, 4672*sizeof(float), stream);
  k_prep<<<288, 256, 0, stream>>>(w1, w2, T, w1p, w2ph, w2pl);
  for (int c = 0; c < dftloop; ++c){
    k_dft_rows<<<dftCH*48, 192, 0, stream>>>(x, T, A, rgbsum, c*dftCH);
    k_dft_cols<<<dftCH*25, 192, 0, stream>>>(A, T, Bh, col0, stats, c*dftCH);
  }
  k_finalize<<<1, 128, 0, stream>>>(stats, rgbsum, ssb, rgbm);
  for (int c = 0; c < cvloop; ++c){
    k_conv1mfma<<<cvB*144, 256, 0, stream>>>(Bh, col0, ssb, w1p, b1, g1, bb1, E, c*cvB);
    k_conv2mfma<<<cvB*72, 512, 0, stream>>>(E, w2ph, w2pl, b2, g2, bb2, freqa, c*cvB);
  }
  k_mlp<<<NB, 256, 0, stream>>>(rgbm, freqa, w_rgb, b_rgb, fc1w, fc1b,
                                fc2w, fc2b, fc3w, fc3b, (float*)d_out);
}

// Round 14
// 403.890 us; speedup vs baseline: 22.5905x; 1.0025x over previous
//
#include <hip/hip_runtime.h>
#include <math.h>

// Problem dims
#define NB    32
#define NC    3
#define NIMG  (NB*NC)      // 96 image-channels
#define NS    384
#define HWSZ  (NS*NS)      // 147456
#define C1OUT 64
#define C1DIM 192
#define PDIM  96
#define PHW   (PDIM*PDIM)  // 9216
#define C2OUT 128
#define KWH   193          // stored half-spectrum width in A (kw = 0..192)
#define BHW   192          // stored half-spectrum width in Bh (v = 192..383)
#define PI_F  3.14159265358979323846f

// ---- workspace layout (bytes) ----
// T region @0 (1,179,648 B): twiddle row f2[768] @0 (6KB used),
//   w1p bf16[64][192] @8192, w2ph @32768, w2pl @180224 (ends 327,680)
// B region @OFF_B: Bh f32[96][384][192] = 28,311,552 + col0 f32[96][384]=147,456
// S region @OFF_S (75,497,472 B, time-shared):
//   dft phase : A float2[96][384][193] = 56,918,016 (full) / [24] (chunked)
//   conv phase: E bf16[16][192][192][64] = 75,497,472 (full) / [2] (chunked)
// smalls @OFF_SM: rgbsum[96] stats[192] freqacc[4096] rgbmean[96] ss[192]
static const size_t OFF_T    = 0;
static const size_t OFF_TW1  = 8192;
static const size_t OFF_TW2H = 32768;
static const size_t OFF_TW2L = 180224;
static const size_t OFF_B    = 1179648;
static const size_t OFF_C0   = 1179648 + 28311552;   // col0
static const size_t OFF_S    = 57802752;
static const size_t OFF_SM_F = 133300224;
static const size_t OFF_SM_C = 76677120;
static const size_t NEED_F   = 133318912;

// padded LDS index for FFT work arrays: breaks 2^k-stride bank conflicts
#define WI(i) ((i) + ((i) >> 4))

typedef __attribute__((ext_vector_type(8))) short bf16x8_t;
typedef __attribute__((ext_vector_type(4))) float f32x4_t;
union U16 { unsigned u[4]; uint4 q; bf16x8_t v; };

__device__ __forceinline__ float wave_sum(float v){
  #pragma unroll
  for (int off = 32; off; off >>= 1) v += __shfl_down(v, off);
  return v;
}
__device__ __forceinline__ unsigned short f2bf(float f){
  unsigned u = __float_as_uint(f);
  u += 0x7FFFu + ((u >> 16) & 1u);
  return (unsigned short)(u >> 16);
}
__device__ __forceinline__ float bf2f(unsigned short h){
  return __uint_as_float(((unsigned)h) << 16);
}
__device__ __forceinline__ unsigned pmax16(unsigned a, unsigned b){
  unsigned al = a & 0xffffu, ah = a >> 16, bl = b & 0xffffu, bh = b >> 16;
  unsigned ml = al > bl ? al : bl, mh = ah > bh ? ah : bh;
  return (mh << 16) | ml;
}
__device__ __forceinline__ uint4 pmax8(uint4 a, uint4 b){
  uint4 r;
  r.x = pmax16(a.x, b.x); r.y = pmax16(a.y, b.y);
  r.z = pmax16(a.z, b.z); r.w = pmax16(a.w, b.w);
  return r;
}
// proper mod-384 for v in [0, 768): NOT "& 383" (384 not a power of two).
__device__ __forceinline__ int mod384(int v){ return v >= NS ? v - NS : v; }
__device__ __forceinline__ float2 cmul(float2 a, float2 b){
  return make_float2(a.x*b.x - a.y*b.y, a.x*b.y + a.y*b.x);
}

// Merged prep: twiddle row W384^m + conv1 bf16 weight pack + conv2 hi/lo split.
__global__ void k_prep(const float* __restrict__ w1, const float* __restrict__ w2,
    float2* __restrict__ T, unsigned short* __restrict__ w1p,
    unsigned short* __restrict__ w2ph, unsigned short* __restrict__ w2pl){
  int idx = blockIdx.x*256 + (int)threadIdx.x;
  if (idx < NS){
    float ang = -2.0f*PI_F*(float)idx/(float)NS;
    T[NS + idx] = make_float2(cosf(ang), sinf(ang));
  }
  if (idx < 64*192){
    int oc = idx / 192, k = idx - oc*192;
    int rk = k >> 3, kw = k & 7;
    float val = 0.f;
    if (rk < 21 && kw < 7){
      int ic = rk / 7, kh = rk - 7*ic;
      val = w1[oc*147 + ic*49 + kh*7 + kw];
    }
    w1p[idx] = f2bf(val);
  }
  if (idx < 128*576){
    int oc = idx / 576, k = idx - oc*576;
    int tap = k >> 6, ic = k & 63;
    float w = w2[(size_t)oc*576 + ic*9 + tap];
    unsigned short hi = f2bf(w);
    w2ph[idx] = hi;
    w2pl[idx] = f2bf(w - bf2f(hi));
  }
}

// Row FFT (along W, real input): 8 rows/block as 4 packed complex FFTs.
// work[] padded via WI() to break butterfly bank conflicts.
__global__ __launch_bounds__(192) void k_dft_rows(const float* __restrict__ x,
    const float2* __restrict__ T, float2* __restrict__ A,
    float* __restrict__ rgbsum, int bc0){
  __shared__ float2 work[4][408];          // WI(383)=406 max
  __shared__ float rs[3];
  const float2* Trow = T + NS;             // W384^m
  int blk = blockIdx.x;
  int bcl = blk / 48, rg = blk % 48;
  int bc = bc0 + bcl;
  int t = threadIdx.x;
  const float* xp = x + (size_t)bc*HWSZ + (size_t)rg*8*NS;
  int nA = t,        rA = nA % 3, iA = (rA*128) + (__brev((unsigned)(nA/3)) >> 25);
  int nB = t + 192,  rB = nB % 3, iB = (rB*128) + (__brev((unsigned)(nB/3)) >> 25);
  float lsum = 0.f;
  #pragma unroll
  for (int c = 0; c < 4; ++c){
    float a0 = xp[(2*c)*NS + nA],   b0 = xp[(2*c+1)*NS + nA];
    float a1 = xp[(2*c)*NS + nB],   b1 = xp[(2*c+1)*NS + nB];
    work[c][WI(iA)] = make_float2(a0, b0);
    work[c][WI(iB)] = make_float2(a1, b1);
    lsum += a0 + b0 + a1 + b1;
  }
  float ws = wave_sum(lsum);
  if ((t & 63) == 0) rs[t >> 6] = ws;
  __syncthreads();
  if (t == 0) atomicAdd(&rgbsum[bc], rs[0] + rs[1] + rs[2]);

  int sub = t >> 6, j = t & 63;
  #pragma unroll
  for (int st = 0; st < 7; ++st){
    int half = 1 << st;
    int pos = j & (half - 1);
    int ia = sub*128 + (((j >> st) << (st + 1)) | pos);
    int ib = ia + half;
    float2 tw = Trow[(192 >> st) * pos];
    #pragma unroll
    for (int c = 0; c < 4; ++c){
      float2 a = work[c][WI(ia)], b = cmul(work[c][WI(ib)], tw);
      work[c][WI(ia)] = make_float2(a.x + b.x, a.y + b.y);
      work[c][WI(ib)] = make_float2(a.x - b.x, a.y - b.y);
    }
    __syncthreads();
  }
  int k1a = t & 127, k1b = (t + 192) & 127;
  float2 w1 = Trow[t], w2 = Trow[(2*t) % 384];
  float2 Xa[4], Xb[4];
  #pragma unroll
  for (int c = 0; c < 4; ++c){
    float2 p1 = cmul(w1, work[c][WI(128 + k1a)]);
    float2 p2 = cmul(w2, work[c][WI(256 + k1a)]);
    float2 y0 = work[c][WI(k1a)];
    Xa[c] = make_float2(y0.x + p1.x + p2.x, y0.y + p1.y + p2.y);
    float2 q1 = cmul(w1, work[c][WI(128 + k1b)]);
    float2 q2 = cmul(w2, work[c][WI(256 + k1b)]);
    float2 z0 = work[c][WI(k1b)];
    Xb[c] = make_float2(z0.x - q1.x + q2.x, z0.y - q1.y + q2.y);
  }
  __syncthreads();
  #pragma unroll
  for (int c = 0; c < 4; ++c){ work[c][WI(t)] = Xa[c]; work[c][WI(t + 192)] = Xb[c]; }
  __syncthreads();
  int tm = (t == 0) ? 0 : (384 - t);
  #pragma unroll
  for (int c = 0; c < 4; ++c){
    float2 Zk = Xa[c];
    float2 Zm = work[c][WI(tm)];
    size_t b0r = ((size_t)bcl*NS + rg*8 + 2*c)*KWH;
    size_t b1r = b0r + KWH;
    A[b0r + t] = make_float2(0.5f*(Zk.x + Zm.x), 0.5f*(Zk.y - Zm.y));
    A[b1r + t] = make_float2(0.5f*(Zk.y + Zm.y), 0.5f*(Zm.x - Zk.x));
    if (t == 0){
      float2 Zn = Xb[c];
      A[b0r + 192] = make_float2(Zn.x, 0.f);
      A[b1r + 192] = make_float2(Zn.y, 0.f);
    }
  }
}

// Column FFT for kw in [0,192], 8 columns/block. HALF-SPECTRUM output:
// only v = kw+192 (i.e. Bh col j = kw) plus col0 (v=0, kw=192) are written;
// the lower half v in [1,191] is reconstructed at conv1-read time via
// B[u][v] = B[(384-u)%384][(384-v)%384] (conjugate symmetry; same identity
// round-12's mirror writes used, which passed). Mag-transpose buffer reuses
// work[] (combine held in registers) -> LDS 26 KB, 6 blocks/CU.
__global__ __launch_bounds__(192) void k_dft_cols(const float2* __restrict__ A,
    const float2* __restrict__ T, float* __restrict__ Bh, float* __restrict__ col0,
    float* __restrict__ stats, int bc0){
  __shared__ float2 work[8][408];
  __shared__ float rs[6];
  float* mgp = (float*)work;               // overlay after combine: mg[u][c] = mgp[u*9+c]
  const float2* Trow = T + NS;
  int blk = blockIdx.x;
  int bcl = blk / 25, cg = blk % 25;
  int bc = bc0 + bcl;
  int kw0 = cg*8;
  int cols = (cg == 24) ? 1 : 8;
  int t = threadIdx.x;
  const float2* Al = A + (size_t)bcl*NS*KWH;
  if (cols == 8){
    #pragma unroll
    for (int i = 0; i < 16; ++i){
      int lin = i*192 + t;
      int h = lin >> 3, c = lin & 7;
      int r = h % 3;
      work[c][WI(r*128 + (__brev((unsigned)(h/3)) >> 25))] = Al[(size_t)h*KWH + kw0 + c];
    }
  } else {
    for (int h = t; h < NS; h += 192){
      int r = h % 3;
      work[0][WI(r*128 + (__brev((unsigned)(h/3)) >> 25))] = Al[(size_t)h*KWH + kw0];
    }
  }
  __syncthreads();
  int sub = t >> 6, j = t & 63;
  #pragma unroll
  for (int st = 0; st < 7; ++st){
    int half = 1 << st;
    int pos = j & (half - 1);
    int ia = sub*128 + (((j >> st) << (st + 1)) | pos);
    int ib = ia + half;
    float2 tw = Trow[(192 >> st) * pos];
    #pragma unroll
    for (int c = 0; c < 8; ++c){
      if (c < cols){
        float2 a = work[c][WI(ia)], b = cmul(work[c][WI(ib)], tw);
        work[c][WI(ia)] = make_float2(a.x + b.x, a.y + b.y);
        work[c][WI(ib)] = make_float2(a.x - b.x, a.y - b.y);
      }
    }
    __syncthreads();
  }
  // combine + mag into REGISTERS; stats with mirror weight 2
  int k1a = t & 127, k1b = (t + 192) & 127;
  float2 w1 = Trow[t], w2 = Trow[(2*t) % 384];
  float s1 = 0.f, s2 = 0.f;
  float ma[8], mb[8];
  #pragma unroll
  for (int c = 0; c < 8; ++c){
    ma[c] = 0.f; mb[c] = 0.f;
    if (c < cols){
      float2 p1 = cmul(w1, work[c][WI(128 + k1a)]);
      float2 p2 = cmul(w2, work[c][WI(256 + k1a)]);
      float2 y0 = work[c][WI(k1a)];
      float2 Xa = make_float2(y0.x + p1.x + p2.x, y0.y + p1.y + p2.y);
      float2 q1 = cmul(w1, work[c][WI(128 + k1b)]);
      float2 q2 = cmul(w2, work[c][WI(256 + k1b)]);
      float2 z0 = work[c][WI(k1b)];
      float2 Xb = make_float2(z0.x - q1.x + q2.x, z0.y - q1.y + q2.y);
      ma[c] = logf(sqrtf(Xa.x*Xa.x + Xa.y*Xa.y) + 1.f);   // kh = t     -> u = t+192
      mb[c] = logf(sqrtf(Xb.x*Xb.x + Xb.y*Xb.y) + 1.f);   // kh = t+192 -> u = t
      int kw = kw0 + c;
      float wgt = (kw >= 1 && kw <= 191) ? 2.f : 1.f;
      s1 += wgt*(ma[c] + mb[c]);
      s2 += wgt*(ma[c]*ma[c] + mb[c]*mb[c]);
    }
  }
  __syncthreads();                         // done reading work
  #pragma unroll
  for (int c = 0; c < 8; ++c){
    if (c < cols){
      mgp[(t + 192)*9 + c] = ma[c];
      mgp[t*9 + c]         = mb[c];
    }
  }
  __syncthreads();
  // write phase: each thread owns rows u = t and t+192; main band only
  if (cols == 8){
    float* Bhc = Bh + (size_t)bc*NS*BHW;
    #pragma unroll
    for (int rr = 0; rr < 2; ++rr){
      int u = t + rr*192;
      float* row = Bhc + (size_t)u*BHW + kw0;     // j = kw -> v = kw+192
      *(float4*)(row)     = make_float4(mgp[u*9+0], mgp[u*9+1], mgp[u*9+2], mgp[u*9+3]);
      *(float4*)(row + 4) = make_float4(mgp[u*9+4], mgp[u*9+5], mgp[u*9+6], mgp[u*9+7]);
    }
  } else {                                 // kw = 192 -> shifted col v = 0
    float* c0c = col0 + (size_t)bc*NS;
    #pragma unroll
    for (int rr = 0; rr < 2; ++rr){
      int u = t + rr*192;
      c0c[u] = mgp[u*9];
    }
  }
  float w1s = wave_sum(s1), w2s = wave_sum(s2);
  if ((t & 63) == 0){ rs[t >> 6] = w1s; rs[3 + (t >> 6)] = w2s; }
  __syncthreads();
  if (t == 0){
    atomicAdd(&stats[bc*2],     rs[0] + rs[1] + rs[2]);
    atomicAdd(&stats[bc*2 + 1], rs[3] + rs[4] + rs[5]);
  }
}

__global__ void k_finalize(const float* __restrict__ stats, const float* __restrict__ rgbsum,
                           float* __restrict__ ss, float* __restrict__ rgbmean){
  int t = threadIdx.x;
  if (t < NIMG){
    const float inv_n = 1.f / 147456.f;
    float mean = stats[t*2] * inv_n;
    float var  = fmaxf(stats[t*2 + 1] * inv_n - mean*mean, 0.f);
    float inv  = 1.f / (sqrtf(var) + 1e-8f);
    ss[t*2]     = inv;
    ss[t*2 + 1] = -mean * inv;
    rgbmean[t]  = rgbsum[t] * inv_n;
  }
}

// conv1(7x7,s2,p3)+BN+ReLU via MFMA 16x16x32 bf16. Staging gathers from the
// half-spectrum with reflection: wg>=192 -> Bh[hg][wg-192]; wg in [1,191] ->
// Bh[(384-hg)%384][192-wg]; wg==0 -> col0[hg].
__global__ __launch_bounds__(256) void k_conv1mfma(const float* __restrict__ Bh,
    const float* __restrict__ col0, const float* __restrict__ ss,
    const unsigned short* __restrict__ w1p, const float* __restrict__ b1,
    const float* __restrict__ g1, const float* __restrict__ bb1,
    unsigned short* __restrict__ E, int b0){
  __shared__ unsigned short pt[3*37*40];
  int blk = blockIdx.x;
  int li = blk / 144, rem = blk - li*144;
  int rg = rem / 12, cg = rem - rg*12;
  int r0 = rg*16, c0 = cg*16;
  int b = b0 + li;
  int t = threadIdx.x;
  float sc[3], sh[3];
  #pragma unroll
  for (int ic = 0; ic < 3; ++ic){ sc[ic] = ss[(b*3 + ic)*2]; sh[ic] = ss[(b*3 + ic)*2 + 1]; }
  const int h0 = 2*r0 - 3, w0 = 2*c0 - 3;
  for (int lin = t; lin < 3*37*40; lin += 256){
    int ic = lin / 1480; int r = lin - ic*1480;
    int hr = r / 40, wc = r - hr*40;
    int hg = h0 + hr, wg = w0 + wc;
    bool v = (wc < 38) && ((unsigned)hg < (unsigned)NS) && ((unsigned)wg < (unsigned)NS);
    float raw = 0.f;
    if (v){
      const float* Bc = Bh + (size_t)(b*3 + ic)*NS*BHW;
      if (wg >= 192)      raw = Bc[(size_t)hg*BHW + (wg - 192)];
      else if (wg >= 1)   raw = Bc[(size_t)mod384(NS - hg)*BHW + (192 - wg)];
      else                raw = col0[(size_t)(b*3 + ic)*NS + hg];
    }
    pt[lin] = v ? f2bf(fmaf(raw, sc[ic], sh[ic])) : (unsigned short)0;
  }
  __syncthreads();

  int wave = t >> 6, lane = t & 63;
  int lm = lane & 15, lg = lane >> 4;
  U16 bf[6];
  #pragma unroll
  for (int ks = 0; ks < 6; ++ks)
    bf[ks].q = *(const uint4*)(w1p + (wave*16 + lm)*192 + ks*32 + lg*8);
  int cbase[6];
  #pragma unroll
  for (int ks = 0; ks < 6; ++ks){
    int rk = ks*4 + lg;
    if (rk > 20) rk = 20;
    int ic = rk / 7, kh = rk - 7*ic;
    cbase[ks] = ic*1480 + kh*40 + 2*lm;
  }
  const float bneps = rsqrtf(1.f + 1e-5f);
  float4 b4  = *(const float4*)(b1  + wave*16 + lg*4);
  float4 g4  = *(const float4*)(g1  + wave*16 + lg*4);
  float4 bb4 = *(const float4*)(bb1 + wave*16 + lg*4);
  float4 gs4 = make_float4(g4.x*bneps, g4.y*bneps, g4.z*bneps, g4.w*bneps);
  unsigned short* Eb = E + (((size_t)li*C1DIM + r0)*C1DIM + c0 + lm)*64 + wave*16 + lg*4;

  #pragma unroll 1
  for (int rt = 0; rt < 16; ++rt){
    f32x4_t acc = {b4.x, b4.y, b4.z, b4.w};
    #pragma unroll
    for (int ks = 0; ks < 6; ++ks){
      U16 a;
      const unsigned* pp = (const unsigned*)&pt[cbase[ks] + 80*rt];
      a.u[0] = pp[0]; a.u[1] = pp[1]; a.u[2] = pp[2]; a.u[3] = pp[3];
      acc = __builtin_amdgcn_mfma_f32_16x16x32_bf16(bf[ks].v, a.v, acc, 0, 0, 0);
    }
    ushort4 o;
    o.x = f2bf(fmaxf(fmaf(acc[0], gs4.x, bb4.x), 0.f));
    o.y = f2bf(fmaxf(fmaf(acc[1], gs4.y, bb4.y), 0.f));
    o.z = f2bf(fmaxf(fmaf(acc[2], gs4.z, bb4.z), 0.f));
    o.w = f2bf(fmaxf(fmaf(acc[3], gs4.w, bb4.w), 0.f));
    *(ushort4*)(Eb + (size_t)rt*C1DIM*64) = o;
  }
}

// conv2(3x3,p1)+BN+ReLU + global-avg-pool via MFMA (unchanged from round 12).
__global__ __launch_bounds__(512) void k_conv2mfma(const unsigned short* __restrict__ E,
    const unsigned short* __restrict__ w2ph, const unsigned short* __restrict__ w2pl,
    const float* __restrict__ b2, const float* __restrict__ g2,
    const float* __restrict__ bb2, float* __restrict__ freq_acc, int b0){
  __shared__ unsigned short sD[10*1152];   // [hp(10)][g(8)][wp(18)][8ic]
  int blk = blockIdx.x;
  int li = blk / 72, tile = blk - li*72;
  int rb = tile / 6, cb = tile - rb*6;
  int r0 = rb*8, c0 = cb*16;
  int b = b0 + li;
  int t = threadIdx.x;
  const unsigned short* Eb = E + (size_t)li*C1DIM*C1DIM*64;
  for (int lin = t; lin < 1440; lin += 512){
    int g = lin & 7; int rm = lin >> 3;
    int wp = rm % 18, hp = rm / 18;
    int ph = r0 + hp - 1, pw = c0 + wp - 1;
    uint4 mx = make_uint4(0u,0u,0u,0u);
    if ((unsigned)ph < (unsigned)PDIM && (unsigned)pw < (unsigned)PDIM){
      #pragma unroll
      for (int dh = 0; dh < 3; ++dh){
        int eh = 2*ph - 1 + dh;
        if ((unsigned)eh >= (unsigned)C1DIM) continue;
        #pragma unroll
        for (int dw = 0; dw < 3; ++dw){
          int ew = 2*pw - 1 + dw;
          if ((unsigned)ew >= (unsigned)C1DIM) continue;
          uint4 v = *(const uint4*)(Eb + ((size_t)eh*C1DIM + ew)*64 + g*8);
          mx = pmax8(mx, v);
        }
      }
    }
    *(uint4*)&sD[hp*1152 + g*144 + wp*8] = mx;
  }
  __syncthreads();

  int wave = t >> 6, lane = t & 63;
  int lm = lane & 15, lg = lane >> 4;
  int octile = wave*16;
  const float bneps = rsqrtf(1.f + 1e-5f);
  float4 b4  = *(const float4*)(b2  + octile + lg*4);
  float4 g4  = *(const float4*)(g2  + octile + lg*4);
  float4 bb4 = *(const float4*)(bb2 + octile + lg*4);
  f32x4_t acc[8];
  #pragma unroll
  for (int nt = 0; nt < 8; ++nt){
    acc[nt][0] = b4.x; acc[nt][1] = b4.y; acc[nt][2] = b4.z; acc[nt][3] = b4.w;
  }
  const unsigned short* whp = w2ph + (size_t)(octile + lm)*576;
  const unsigned short* wlp = w2pl + (size_t)(octile + lm)*576;
  #pragma unroll
  for (int ks = 0; ks < 18; ++ks){
    const int tap = ks >> 1, h32 = ks & 1;
    const int dh = tap / 3, dw = tap - 3*(tap/3);
    U16 wh, wl;
    wh.q = *(const uint4*)(whp + ks*32 + lg*8);
    wl.q = *(const uint4*)(wlp + ks*32 + lg*8);
    int base = (h32*4 + lg)*144 + (lm + dw)*8;
    #pragma unroll
    for (int nt = 0; nt < 8; ++nt){
      U16 a;
      a.q = *(const uint4*)&sD[(nt + dh)*1152 + base];
      acc[nt] = __builtin_amdgcn_mfma_f32_16x16x32_bf16(wh.v, a.v, acc[nt], 0, 0, 0);
      acc[nt] = __builtin_amdgcn_mfma_f32_16x16x32_bf16(wl.v, a.v, acc[nt], 0, 0, 0);
    }
  }
  float s0 = 0.f, s1 = 0.f, s2 = 0.f, s3 = 0.f;
  float gx = g4.x*bneps, gy = g4.y*bneps, gz = g4.z*bneps, gw = g4.w*bneps;
  #pragma unroll
  for (int nt = 0; nt < 8; ++nt){
    s0 += fmaxf(fmaf(acc[nt][0], gx, bb4.x), 0.f);
    s1 += fmaxf(fmaf(acc[nt][1], gy, bb4.y), 0.f);
    s2 += fmaxf(fmaf(acc[nt][2], gz, bb4.z), 0.f);
    s3 += fmaxf(fmaf(acc[nt][3], gw, bb4.w), 0.f);
  }
  #pragma unroll
  for (int off = 1; off < 16; off <<= 1){
    s0 += __shfl_xor(s0, off);
    s1 += __shfl_xor(s1, off);
    s2 += __shfl_xor(s2, off);
    s3 += __shfl_xor(s3, off);
  }
  if (lm == 0){
    float* fa = freq_acc + (size_t)b*C2OUT + octile + lg*4;
    atomicAdd(fa + 0, s0); atomicAdd(fa + 1, s1);
    atomicAdd(fa + 2, s2); atomicAdd(fa + 3, s3);
  }
}

// RGB head + concat + 3-layer MLP, one block per batch sample.
__global__ __launch_bounds__(256) void k_mlp(const float* __restrict__ rgbmean,
    const float* __restrict__ freq_acc, const float* __restrict__ w_rgb,
    const float* __restrict__ b_rgb, const float* __restrict__ fc1w,
    const float* __restrict__ fc1b, const float* __restrict__ fc2w,
    const float* __restrict__ fc2b, const float* __restrict__ fc3w,
    const float* __restrict__ fc3b, float* __restrict__ out){
  __shared__ float z[130], z1[256], z2[128];
  int b = blockIdx.x, t = threadIdx.x;
  if (t < 2){
    float s = b_rgb[t];
    #pragma unroll
    for (int c = 0; c < 3; ++c) s += rgbmean[b*3 + c] * w_rgb[c*2 + t];
    z[t] = s;
  }
  if (t < 128) z[2 + t] = freq_acc[b*C2OUT + t] * (1.f/9216.f);
  __syncthreads();
  { float s = fc1b[t];
    for (int k = 0; k < 130; ++k) s = fmaf(z[k], fc1w[k*256 + t], s);
    z1[t] = fmaxf(s, 0.f); }
  __syncthreads();
  if (t < 128){
    float s = fc2b[t];
    for (int k = 0; k < 256; ++k) s = fmaf(z1[k], fc2w[k*128 + t], s);
    z2[t] = fmaxf(s, 0.f); }
  __syncthreads();
  if (t < 2){
    float s = fc3b[t];
    for (int k = 0; k < 128; ++k) s = fmaf(z2[k], fc3w[k*2 + t], s);
    out[b*2 + t] = s; }
}

extern "C" void kernel_launch(void* const* d_in, const int* in_sizes, int n_in,
                              void* d_out, int out_size, void* d_ws, size_t ws_size,
                              hipStream_t stream){
  const float* x     = (const float*)d_in[0];
  const float* w_rgb = (const float*)d_in[1];
  const float* b_rgb = (const float*)d_in[2];
  const float* w1    = (const float*)d_in[3];
  const float* b1    = (const float*)d_in[4];
  const float* g1    = (const float*)d_in[5];
  const float* bb1   = (const float*)d_in[6];
  const float* w2    = (const float*)d_in[7];
  const float* b2    = (const float*)d_in[8];
  const float* g2    = (const float*)d_in[9];
  const float* bb2   = (const float*)d_in[10];
  const float* fc1w  = (const float*)d_in[11];
  const float* fc1b  = (const float*)d_in[12];
  const float* fc2w  = (const float*)d_in[13];
  const float* fc2b  = (const float*)d_in[14];
  const float* fc3w  = (const float*)d_in[15];
  const float* fc3b  = (const float*)d_in[16];

  const bool full = (ws_size >= NEED_F);
  const int dftloop = full ? 1 : 4;
  const int dftCH   = full ? 96 : 24;
  const int cvloop  = full ? 2 : 16;       // E16 fits S exactly in full mode
  const int cvB     = full ? 16 : 2;

  char* ws = (char*)d_ws;
  float2* T  = (float2*)(ws + OFF_T);
  unsigned short* w1p  = (unsigned short*)(ws + OFF_TW1);
  unsigned short* w2ph = (unsigned short*)(ws + OFF_TW2H);
  unsigned short* w2pl = (unsigned short*)(ws + OFF_TW2L);
  float*  Bh   = (float*)(ws + OFF_B);
  float*  col0 = (float*)(ws + OFF_C0);
  float2* A    = (float2*)(ws + OFF_S);
  unsigned short* E = (unsigned short*)(ws + OFF_S);
  float*  sm = (float*)(ws + (full ? OFF_SM_F : OFF_SM_C));
  float* rgbsum = sm;            // 96
  float* stats  = sm + 96;       // 192
  float* freqa  = sm + 288;      // 4096
  float* rgbm   = sm + 4384;     // 96
  float* ssb    = sm + 4480;     // 192

  hipMemsetAsync(sm, 0, 4672*sizeof(float), stream);
  k_prep<<<288, 256, 0, stream>>>(w1, w2, T, w1p, w2ph, w2pl);
  for (int c = 0; c < dftloop; ++c){
    k_dft_rows<<<dftCH*48, 192, 0, stream>>>(x, T, A, rgbsum, c*dftCH);
    k_dft_cols<<<dftCH*25, 192, 0, stream>>>(A, T, Bh, col0, stats, c*dftCH);
  }
  k_finalize<<<1, 128, 0, stream>>>(stats, rgbsum, ssb, rgbm);
  for (int c = 0; c < cvloop; ++c){
    k_conv1mfma<<<cvB*144, 256, 0, stream>>>(Bh, col0, ssb, w1p, b1, g1, bb1, E, c*cvB);
    k_conv2mfma<<<cvB*72, 512, 0, stream>>>(E, w2ph, w2pl, b2, g2, bb2, freqa, c*cvB);
  }
  k_mlp<<<NB, 256, 0, stream>>>(rgbm, freqa, w_rgb, b_rgb, fc1w, fc1b,
                                fc2w, fc2b, fc3w, fc3b, (float*)d_out);
}

// Round 15
// 393.152 us; speedup vs baseline: 23.2076x; 1.0273x over previous
//
#include <hip/hip_runtime.h>
#include <math.h>

// Problem dims
#define NB    32
#define NC    3
#define NIMG  (NB*NC)      // 96 image-channels
#define NS    384
#define HWSZ  (NS*NS)      // 147456
#define C1OUT 64
#define C1DIM 192
#define PDIM  96
#define PHW   (PDIM*PDIM)  // 9216
#define C2OUT 128
#define KWH   193          // stored half-spectrum width in A (kw = 0..192)
#define BHW   192          // stored half-spectrum width in Bh (v = 192..383)
#define PI_F  3.14159265358979323846f

// ---- workspace layout (bytes) ----
// T region @0: twiddle row f2[768], w1p @8192, w2ph @32768, w2pl @180224
// B region @OFF_B: Bh f32[96][384][192] = 28,311,552 + col0 f32[96][384]
// P region @OFF_P: P bf16[16][96][96][64] = 18,874,368 (pooled conv1, chunk-local)
// S region @OFF_S (75,497,472, time-shared): A (dft) / E bf16[16][192][192][64] (conv)
// smalls @OFF_SM
static const size_t OFF_T    = 0;
static const size_t OFF_TW1  = 8192;
static const size_t OFF_TW2H = 32768;
static const size_t OFF_TW2L = 180224;
static const size_t OFF_B    = 1179648;
static const size_t OFF_C0   = 1179648 + 28311552;   // col0
static const size_t OFF_P    = 29638656;             // after col0 (147,456)
static const size_t OFF_S    = 57802752;
static const size_t OFF_SM_F = 133300224;
static const size_t OFF_SM_C = 76677120;
static const size_t NEED_F   = 133318912;

// padded LDS index for FFT work arrays: breaks 2^k-stride bank conflicts
#define WI(i) ((i) + ((i) >> 4))

typedef __attribute__((ext_vector_type(8))) short bf16x8_t;
typedef __attribute__((ext_vector_type(4))) float f32x4_t;
union U16 { unsigned u[4]; uint4 q; bf16x8_t v; };

__device__ __forceinline__ float wave_sum(float v){
  #pragma unroll
  for (int off = 32; off; off >>= 1) v += __shfl_down(v, off);
  return v;
}
__device__ __forceinline__ unsigned short f2bf(float f){
  unsigned u = __float_as_uint(f);
  u += 0x7FFFu + ((u >> 16) & 1u);
  return (unsigned short)(u >> 16);
}
__device__ __forceinline__ float bf2f(unsigned short h){
  return __uint_as_float(((unsigned)h) << 16);
}
__device__ __forceinline__ unsigned pmax16(unsigned a, unsigned b){
  unsigned al = a & 0xffffu, ah = a >> 16, bl = b & 0xffffu, bh = b >> 16;
  unsigned ml = al > bl ? al : bl, mh = ah > bh ? ah : bh;
  return (mh << 16) | ml;
}
__device__ __forceinline__ uint4 pmax8(uint4 a, uint4 b){
  uint4 r;
  r.x = pmax16(a.x, b.x); r.y = pmax16(a.y, b.y);
  r.z = pmax16(a.z, b.z); r.w = pmax16(a.w, b.w);
  return r;
}
// proper mod-384 for v in [0, 768): NOT "& 383" (384 not a power of two).
__device__ __forceinline__ int mod384(int v){ return v >= NS ? v - NS : v; }
__device__ __forceinline__ float2 cmul(float2 a, float2 b){
  return make_float2(a.x*b.x - a.y*b.y, a.x*b.y + a.y*b.x);
}

// Merged prep: twiddle row W384^m + conv1 bf16 weight pack + conv2 hi/lo split.
__global__ void k_prep(const float* __restrict__ w1, const float* __restrict__ w2,
    float2* __restrict__ T, unsigned short* __restrict__ w1p,
    unsigned short* __restrict__ w2ph, unsigned short* __restrict__ w2pl){
  int idx = blockIdx.x*256 + (int)threadIdx.x;
  if (idx < NS){
    float ang = -2.0f*PI_F*(float)idx/(float)NS;
    T[NS + idx] = make_float2(cosf(ang), sinf(ang));
  }
  if (idx < 64*192){
    int oc = idx / 192, k = idx - oc*192;
    int rk = k >> 3, kw = k & 7;
    float val = 0.f;
    if (rk < 21 && kw < 7){
      int ic = rk / 7, kh = rk - 7*ic;
      val = w1[oc*147 + ic*49 + kh*7 + kw];
    }
    w1p[idx] = f2bf(val);
  }
  if (idx < 128*576){
    int oc = idx / 576, k = idx - oc*576;
    int tap = k >> 6, ic = k & 63;
    float w = w2[(size_t)oc*576 + ic*9 + tap];
    unsigned short hi = f2bf(w);
    w2ph[idx] = hi;
    w2pl[idx] = f2bf(w - bf2f(hi));
  }
}

// Row FFT (along W, real input): 8 rows/block as 4 packed complex FFTs.
__global__ __launch_bounds__(192) void k_dft_rows(const float* __restrict__ x,
    const float2* __restrict__ T, float2* __restrict__ A,
    float* __restrict__ rgbsum, int bc0){
  __shared__ float2 work[4][408];          // WI(383)=406 max
  __shared__ float rs[3];
  const float2* Trow = T + NS;             // W384^m
  int blk = blockIdx.x;
  int bcl = blk / 48, rg = blk % 48;
  int bc = bc0 + bcl;
  int t = threadIdx.x;
  const float* xp = x + (size_t)bc*HWSZ + (size_t)rg*8*NS;
  int nA = t,        rA = nA % 3, iA = (rA*128) + (__brev((unsigned)(nA/3)) >> 25);
  int nB = t + 192,  rB = nB % 3, iB = (rB*128) + (__brev((unsigned)(nB/3)) >> 25);
  float lsum = 0.f;
  #pragma unroll
  for (int c = 0; c < 4; ++c){
    float a0 = xp[(2*c)*NS + nA],   b0 = xp[(2*c+1)*NS + nA];
    float a1 = xp[(2*c)*NS + nB],   b1 = xp[(2*c+1)*NS + nB];
    work[c][WI(iA)] = make_float2(a0, b0);
    work[c][WI(iB)] = make_float2(a1, b1);
    lsum += a0 + b0 + a1 + b1;
  }
  float ws = wave_sum(lsum);
  if ((t & 63) == 0) rs[t >> 6] = ws;
  __syncthreads();
  if (t == 0) atomicAdd(&rgbsum[bc], rs[0] + rs[1] + rs[2]);

  int sub = t >> 6, j = t & 63;
  #pragma unroll
  for (int st = 0; st < 7; ++st){
    int half = 1 << st;
    int pos = j & (half - 1);
    int ia = sub*128 + (((j >> st) << (st + 1)) | pos);
    int ib = ia + half;
    float2 tw = Trow[(192 >> st) * pos];
    #pragma unroll
    for (int c = 0; c < 4; ++c){
      float2 a = work[c][WI(ia)], b = cmul(work[c][WI(ib)], tw);
      work[c][WI(ia)] = make_float2(a.x + b.x, a.y + b.y);
      work[c][WI(ib)] = make_float2(a.x - b.x, a.y - b.y);
    }
    __syncthreads();
  }
  int k1a = t & 127, k1b = (t + 192) & 127;
  float2 w1 = Trow[t], w2 = Trow[(2*t) % 384];
  float2 Xa[4], Xb[4];
  #pragma unroll
  for (int c = 0; c < 4; ++c){
    float2 p1 = cmul(w1, work[c][WI(128 + k1a)]);
    float2 p2 = cmul(w2, work[c][WI(256 + k1a)]);
    float2 y0 = work[c][WI(k1a)];
    Xa[c] = make_float2(y0.x + p1.x + p2.x, y0.y + p1.y + p2.y);
    float2 q1 = cmul(w1, work[c][WI(128 + k1b)]);
    float2 q2 = cmul(w2, work[c][WI(256 + k1b)]);
    float2 z0 = work[c][WI(k1b)];
    Xb[c] = make_float2(z0.x - q1.x + q2.x, z0.y - q1.y + q2.y);
  }
  __syncthreads();
  #pragma unroll
  for (int c = 0; c < 4; ++c){ work[c][WI(t)] = Xa[c]; work[c][WI(t + 192)] = Xb[c]; }
  __syncthreads();
  int tm = (t == 0) ? 0 : (384 - t);
  #pragma unroll
  for (int c = 0; c < 4; ++c){
    float2 Zk = Xa[c];
    float2 Zm = work[c][WI(tm)];
    size_t b0r = ((size_t)bcl*NS + rg*8 + 2*c)*KWH;
    size_t b1r = b0r + KWH;
    A[b0r + t] = make_float2(0.5f*(Zk.x + Zm.x), 0.5f*(Zk.y - Zm.y));
    A[b1r + t] = make_float2(0.5f*(Zk.y + Zm.y), 0.5f*(Zm.x - Zk.x));
    if (t == 0){
      float2 Zn = Xb[c];
      A[b0r + 192] = make_float2(Zn.x, 0.f);
      A[b1r + 192] = make_float2(Zn.y, 0.f);
    }
  }
}

// Column FFT for kw in [0,192], 8 columns/block. Half-spectrum output (r13).
__global__ __launch_bounds__(192) void k_dft_cols(const float2* __restrict__ A,
    const float2* __restrict__ T, float* __restrict__ Bh, float* __restrict__ col0,
    float* __restrict__ stats, int bc0){
  __shared__ float2 work[8][408];
  __shared__ float rs[6];
  float* mgp = (float*)work;               // overlay after combine: mg[u][c] = mgp[u*9+c]
  const float2* Trow = T + NS;
  int blk = blockIdx.x;
  int bcl = blk / 25, cg = blk % 25;
  int bc = bc0 + bcl;
  int kw0 = cg*8;
  int cols = (cg == 24) ? 1 : 8;
  int t = threadIdx.x;
  const float2* Al = A + (size_t)bcl*NS*KWH;
  if (cols == 8){
    #pragma unroll
    for (int i = 0; i < 16; ++i){
      int lin = i*192 + t;
      int h = lin >> 3, c = lin & 7;
      int r = h % 3;
      work[c][WI(r*128 + (__brev((unsigned)(h/3)) >> 25))] = Al[(size_t)h*KWH + kw0 + c];
    }
  } else {
    for (int h = t; h < NS; h += 192){
      int r = h % 3;
      work[0][WI(r*128 + (__brev((unsigned)(h/3)) >> 25))] = Al[(size_t)h*KWH + kw0];
    }
  }
  __syncthreads();
  int sub = t >> 6, j = t & 63;
  #pragma unroll
  for (int st = 0; st < 7; ++st){
    int half = 1 << st;
    int pos = j & (half - 1);
    int ia = sub*128 + (((j >> st) << (st + 1)) | pos);
    int ib = ia + half;
    float2 tw = Trow[(192 >> st) * pos];
    #pragma unroll
    for (int c = 0; c < 8; ++c){
      if (c < cols){
        float2 a = work[c][WI(ia)], b = cmul(work[c][WI(ib)], tw);
        work[c][WI(ia)] = make_float2(a.x + b.x, a.y + b.y);
        work[c][WI(ib)] = make_float2(a.x - b.x, a.y - b.y);
      }
    }
    __syncthreads();
  }
  int k1a = t & 127, k1b = (t + 192) & 127;
  float2 w1 = Trow[t], w2 = Trow[(2*t) % 384];
  float s1 = 0.f, s2 = 0.f;
  float ma[8], mb[8];
  #pragma unroll
  for (int c = 0; c < 8; ++c){
    ma[c] = 0.f; mb[c] = 0.f;
    if (c < cols){
      float2 p1 = cmul(w1, work[c][WI(128 + k1a)]);
      float2 p2 = cmul(w2, work[c][WI(256 + k1a)]);
      float2 y0 = work[c][WI(k1a)];
      float2 Xa = make_float2(y0.x + p1.x + p2.x, y0.y + p1.y + p2.y);
      float2 q1 = cmul(w1, work[c][WI(128 + k1b)]);
      float2 q2 = cmul(w2, work[c][WI(256 + k1b)]);
      float2 z0 = work[c][WI(k1b)];
      float2 Xb = make_float2(z0.x - q1.x + q2.x, z0.y - q1.y + q2.y);
      ma[c] = logf(sqrtf(Xa.x*Xa.x + Xa.y*Xa.y) + 1.f);   // kh = t     -> u = t+192
      mb[c] = logf(sqrtf(Xb.x*Xb.x + Xb.y*Xb.y) + 1.f);   // kh = t+192 -> u = t
      int kw = kw0 + c;
      float wgt = (kw >= 1 && kw <= 191) ? 2.f : 1.f;
      s1 += wgt*(ma[c] + mb[c]);
      s2 += wgt*(ma[c]*ma[c] + mb[c]*mb[c]);
    }
  }
  __syncthreads();                         // done reading work
  #pragma unroll
  for (int c = 0; c < 8; ++c){
    if (c < cols){
      mgp[(t + 192)*9 + c] = ma[c];
      mgp[t*9 + c]         = mb[c];
    }
  }
  __syncthreads();
  if (cols == 8){
    float* Bhc = Bh + (size_t)bc*NS*BHW;
    #pragma unroll
    for (int rr = 0; rr < 2; ++rr){
      int u = t + rr*192;
      float* row = Bhc + (size_t)u*BHW + kw0;     // j = kw -> v = kw+192
      *(float4*)(row)     = make_float4(mgp[u*9+0], mgp[u*9+1], mgp[u*9+2], mgp[u*9+3]);
      *(float4*)(row + 4) = make_float4(mgp[u*9+4], mgp[u*9+5], mgp[u*9+6], mgp[u*9+7]);
    }
  } else {                                 // kw = 192 -> shifted col v = 0
    float* c0c = col0 + (size_t)bc*NS;
    #pragma unroll
    for (int rr = 0; rr < 2; ++rr){
      int u = t + rr*192;
      c0c[u] = mgp[u*9];
    }
  }
  float w1s = wave_sum(s1), w2s = wave_sum(s2);
  if ((t & 63) == 0){ rs[t >> 6] = w1s; rs[3 + (t >> 6)] = w2s; }
  __syncthreads();
  if (t == 0){
    atomicAdd(&stats[bc*2],     rs[0] + rs[1] + rs[2]);
    atomicAdd(&stats[bc*2 + 1], rs[3] + rs[4] + rs[5]);
  }
}

__global__ void k_finalize(const float* __restrict__ stats, const float* __restrict__ rgbsum,
                           float* __restrict__ ss, float* __restrict__ rgbmean){
  int t = threadIdx.x;
  if (t < NIMG){
    const float inv_n = 1.f / 147456.f;
    float mean = stats[t*2] * inv_n;
    float var  = fmaxf(stats[t*2 + 1] * inv_n - mean*mean, 0.f);
    float inv  = 1.f / (sqrtf(var) + 1e-8f);
    ss[t*2]     = inv;
    ss[t*2 + 1] = -mean * inv;
    rgbmean[t]  = rgbsum[t] * inv_n;
  }
}

// conv1(7x7,s2,p3)+BN+ReLU via MFMA (unchanged from round 14).
__global__ __launch_bounds__(256) void k_conv1mfma(const float* __restrict__ Bh,
    const float* __restrict__ col0, const float* __restrict__ ss,
    const unsigned short* __restrict__ w1p, const float* __restrict__ b1,
    const float* __restrict__ g1, const float* __restrict__ bb1,
    unsigned short* __restrict__ E, int b0){
  __shared__ unsigned short pt[3*37*40];
  int blk = blockIdx.x;
  int li = blk / 144, rem = blk - li*144;
  int rg = rem / 12, cg = rem - rg*12;
  int r0 = rg*16, c0 = cg*16;
  int b = b0 + li;
  int t = threadIdx.x;
  float sc[3], sh[3];
  #pragma unroll
  for (int ic = 0; ic < 3; ++ic){ sc[ic] = ss[(b*3 + ic)*2]; sh[ic] = ss[(b*3 + ic)*2 + 1]; }
  const int h0 = 2*r0 - 3, w0 = 2*c0 - 3;
  for (int lin = t; lin < 3*37*40; lin += 256){
    int ic = lin / 1480; int r = lin - ic*1480;
    int hr = r / 40, wc = r - hr*40;
    int hg = h0 + hr, wg = w0 + wc;
    bool v = (wc < 38) && ((unsigned)hg < (unsigned)NS) && ((unsigned)wg < (unsigned)NS);
    float raw = 0.f;
    if (v){
      const float* Bc = Bh + (size_t)(b*3 + ic)*NS*BHW;
      if (wg >= 192)      raw = Bc[(size_t)hg*BHW + (wg - 192)];
      else if (wg >= 1)   raw = Bc[(size_t)mod384(NS - hg)*BHW + (192 - wg)];
      else                raw = col0[(size_t)(b*3 + ic)*NS + hg];
    }
    pt[lin] = v ? f2bf(fmaf(raw, sc[ic], sh[ic])) : (unsigned short)0;
  }
  __syncthreads();

  int wave = t >> 6, lane = t & 63;
  int lm = lane & 15, lg = lane >> 4;
  U16 bf[6];
  #pragma unroll
  for (int ks = 0; ks < 6; ++ks)
    bf[ks].q = *(const uint4*)(w1p + (wave*16 + lm)*192 + ks*32 + lg*8);
  int cbase[6];
  #pragma unroll
  for (int ks = 0; ks < 6; ++ks){
    int rk = ks*4 + lg;
    if (rk > 20) rk = 20;
    int ic = rk / 7, kh = rk - 7*ic;
    cbase[ks] = ic*1480 + kh*40 + 2*lm;
  }
  const float bneps = rsqrtf(1.f + 1e-5f);
  float4 b4  = *(const float4*)(b1  + wave*16 + lg*4);
  float4 g4  = *(const float4*)(g1  + wave*16 + lg*4);
  float4 bb4 = *(const float4*)(bb1 + wave*16 + lg*4);
  float4 gs4 = make_float4(g4.x*bneps, g4.y*bneps, g4.z*bneps, g4.w*bneps);
  unsigned short* Eb = E + (((size_t)li*C1DIM + r0)*C1DIM + c0 + lm)*64 + wave*16 + lg*4;

  #pragma unroll 1
  for (int rt = 0; rt < 16; ++rt){
    f32x4_t acc = {b4.x, b4.y, b4.z, b4.w};
    #pragma unroll
    for (int ks = 0; ks < 6; ++ks){
      U16 a;
      const unsigned* pp = (const unsigned*)&pt[cbase[ks] + 80*rt];
      a.u[0] = pp[0]; a.u[1] = pp[1]; a.u[2] = pp[2]; a.u[3] = pp[3];
      acc = __builtin_amdgcn_mfma_f32_16x16x32_bf16(bf[ks].v, a.v, acc, 0, 0, 0);
    }
    ushort4 o;
    o.x = f2bf(fmaxf(fmaf(acc[0], gs4.x, bb4.x), 0.f));
    o.y = f2bf(fmaxf(fmaf(acc[1], gs4.y, bb4.y), 0.f));
    o.z = f2bf(fmaxf(fmaf(acc[2], gs4.z, bb4.z), 0.f));
    o.w = f2bf(fmaxf(fmaf(acc[3], gs4.w, bb4.w), 0.f));
    *(ushort4*)(Eb + (size_t)rt*C1DIM*64) = o;
  }
}

// maxpool 3x3 s2 p1 over E -> P bf16[cvB][96][96][64]. Each pooled value
// computed ONCE by an independent thread (no LDS, no barrier): removes the
// 9x dependent-gather chain that throttled conv2's staging in round 14.
__global__ __launch_bounds__(256) void k_pool(const unsigned short* __restrict__ E,
    unsigned short* __restrict__ P){
  int lin = blockIdx.x*256 + (int)threadIdx.x;   // ((li*96+ph)*96+pw)*8+g
  int g = lin & 7; int rm = lin >> 3;
  int pw = rm % PDIM; int rm2 = rm / PDIM;
  int ph = rm2 % PDIM; int li = rm2 / PDIM;
  const unsigned short* Eb = E + (size_t)li*C1DIM*C1DIM*64 + g*8;
  uint4 mx = make_uint4(0u,0u,0u,0u);
  #pragma unroll
  for (int dh = 0; dh < 3; ++dh){
    int eh = 2*ph - 1 + dh;
    if ((unsigned)eh >= (unsigned)C1DIM) continue;
    #pragma unroll
    for (int dw = 0; dw < 3; ++dw){
      int ew = 2*pw - 1 + dw;
      if ((unsigned)ew >= (unsigned)C1DIM) continue;
      mx = pmax8(mx, *(const uint4*)(Eb + ((size_t)eh*C1DIM + ew)*64));
    }
  }
  *(uint4*)(P + ((size_t)rm)*64 + g*8) = mx;
}

// conv2(3x3,p1)+BN+ReLU + global-avg-pool via MFMA. Stages from pooled P:
// one uint4 load per LDS entry (was 9 gathers fused with maxpool in r14).
__global__ __launch_bounds__(512) void k_conv2mfma(const unsigned short* __restrict__ P,
    const unsigned short* __restrict__ w2ph, const unsigned short* __restrict__ w2pl,
    const float* __restrict__ b2, const float* __restrict__ g2,
    const float* __restrict__ bb2, float* __restrict__ freq_acc, int b0){
  __shared__ unsigned short sD[10*1152];   // [hp(10)][g(8)][wp(18)][8ic]
  int blk = blockIdx.x;
  int li = blk / 72, tile = blk - li*72;
  int rb = tile / 6, cb = tile - rb*6;
  int r0 = rb*8, c0 = cb*16;
  int b = b0 + li;
  int t = threadIdx.x;
  const unsigned short* Pb = P + (size_t)li*PHW*64;
  for (int lin = t; lin < 1440; lin += 512){
    int g = lin & 7; int rm = lin >> 3;
    int wp = rm % 18, hp = rm / 18;
    int ph = r0 + hp - 1, pw = c0 + wp - 1;
    uint4 v = make_uint4(0u,0u,0u,0u);
    if ((unsigned)ph < (unsigned)PDIM && (unsigned)pw < (unsigned)PDIM)
      v = *(const uint4*)(Pb + ((size_t)ph*PDIM + pw)*64 + g*8);
    *(uint4*)&sD[hp*1152 + g*144 + wp*8] = v;
  }
  __syncthreads();

  int wave = t >> 6, lane = t & 63;
  int lm = lane & 15, lg = lane >> 4;
  int octile = wave*16;
  const float bneps = rsqrtf(1.f + 1e-5f);
  float4 b4  = *(const float4*)(b2  + octile + lg*4);
  float4 g4  = *(const float4*)(g2  + octile + lg*4);
  float4 bb4 = *(const float4*)(bb2 + octile + lg*4);
  f32x4_t acc[8];
  #pragma unroll
  for (int nt = 0; nt < 8; ++nt){
    acc[nt][0] = b4.x; acc[nt][1] = b4.y; acc[nt][2] = b4.z; acc[nt][3] = b4.w;
  }
  const unsigned short* whp = w2ph + (size_t)(octile + lm)*576;
  const unsigned short* wlp = w2pl + (size_t)(octile + lm)*576;
  #pragma unroll
  for (int ks = 0; ks < 18; ++ks){
    const int tap = ks >> 1, h32 = ks & 1;
    const int dh = tap / 3, dw = tap - 3*(tap/3);
    U16 wh, wl;
    wh.q = *(const uint4*)(whp + ks*32 + lg*8);
    wl.q = *(const uint4*)(wlp + ks*32 + lg*8);
    int base = (h32*4 + lg)*144 + (lm + dw)*8;
    #pragma unroll
    for (int nt = 0; nt < 8; ++nt){
      U16 a;
      a.q = *(const uint4*)&sD[(nt + dh)*1152 + base];
      acc[nt] = __builtin_amdgcn_mfma_f32_16x16x32_bf16(wh.v, a.v, acc[nt], 0, 0, 0);
      acc[nt] = __builtin_amdgcn_mfma_f32_16x16x32_bf16(wl.v, a.v, acc[nt], 0, 0, 0);
    }
  }
  float s0 = 0.f, s1 = 0.f, s2 = 0.f, s3 = 0.f;
  float gx = g4.x*bneps, gy = g4.y*bneps, gz = g4.z*bneps, gw = g4.w*bneps;
  #pragma unroll
  for (int nt = 0; nt < 8; ++nt){
    s0 += fmaxf(fmaf(acc[nt][0], gx, bb4.x), 0.f);
    s1 += fmaxf(fmaf(acc[nt][1], gy, bb4.y), 0.f);
    s2 += fmaxf(fmaf(acc[nt][2], gz, bb4.z), 0.f);
    s3 += fmaxf(fmaf(acc[nt][3], gw, bb4.w), 0.f);
  }
  #pragma unroll
  for (int off = 1; off < 16; off <<= 1){
    s0 += __shfl_xor(s0, off);
    s1 += __shfl_xor(s1, off);
    s2 += __shfl_xor(s2, off);
    s3 += __shfl_xor(s3, off);
  }
  if (lm == 0){
    float* fa = freq_acc + (size_t)b*C2OUT + octile + lg*4;
    atomicAdd(fa + 0, s0); atomicAdd(fa + 1, s1);
    atomicAdd(fa + 2, s2); atomicAdd(fa + 3, s3);
  }
}

// RGB head + concat + 3-layer MLP, one block per batch sample.
__global__ __launch_bounds__(256) void k_mlp(const float* __restrict__ rgbmean,
    const float* __restrict__ freq_acc, const float* __restrict__ w_rgb,
    const float* __restrict__ b_rgb, const float* __restrict__ fc1w,
    const float* __restrict__ fc1b, const float* __restrict__ fc2w,
    const float* __restrict__ fc2b, const float* __restrict__ fc3w,
    const float* __restrict__ fc3b, float* __restrict__ out){
  __shared__ float z[130], z1[256], z2[128];
  int b = blockIdx.x, t = threadIdx.x;
  if (t < 2){
    float s = b_rgb[t];
    #pragma unroll
    for (int c = 0; c < 3; ++c) s += rgbmean[b*3 + c] * w_rgb[c*2 + t];
    z[t] = s;
  }
  if (t < 128) z[2 + t] = freq_acc[b*C2OUT + t] * (1.f/9216.f);
  __syncthreads();
  { float s = fc1b[t];
    for (int k = 0; k < 130; ++k) s = fmaf(z[k], fc1w[k*256 + t], s);
    z1[t] = fmaxf(s, 0.f); }
  __syncthreads();
  if (t < 128){
    float s = fc2b[t];
    for (int k = 0; k < 256; ++k) s = fmaf(z1[k], fc2w[k*128 + t], s);
    z2[t] = fmaxf(s, 0.f); }
  __syncthreads();
  if (t < 2){
    float s = fc3b[t];
    for (int k = 0; k < 128; ++k) s = fmaf(z2[k], fc3w[k*2 + t], s);
    out[b*2 + t] = s; }
}

extern "C" void kernel_launch(void* const* d_in, const int* in_sizes, int n_in,
                              void* d_out, int out_size, void* d_ws, size_t ws_size,
                              hipStream_t stream){
  const float* x     = (const float*)d_in[0];
  const float* w_rgb = (const float*)d_in[1];
  const float* b_rgb = (const float*)d_in[2];
  const float* w1    = (const float*)d_in[3];
  const float* b1    = (const float*)d_in[4];
  const float* g1    = (const float*)d_in[5];
  const float* bb1   = (const float*)d_in[6];
  const float* w2    = (const float*)d_in[7];
  const float* b2    = (const float*)d_in[8];
  const float* g2    = (const float*)d_in[9];
  const float* bb2   = (const float*)d_in[10];
  const float* fc1w  = (const float*)d_in[11];
  const float* fc1b  = (const float*)d_in[12];
  const float* fc2w  = (const float*)d_in[13];
  const float* fc2b  = (const float*)d_in[14];
  const float* fc3w  = (const float*)d_in[15];
  const float* fc3b  = (const float*)d_in[16];

  const bool full = (ws_size >= NEED_F);
  const int dftloop = full ? 1 : 4;
  const int dftCH   = full ? 96 : 24;
  const int cvloop  = full ? 2 : 16;
  const int cvB     = full ? 16 : 2;

  char* ws = (char*)d_ws;
  float2* T  = (float2*)(ws + OFF_T);
  unsigned short* w1p  = (unsigned short*)(ws + OFF_TW1);
  unsigned short* w2ph = (unsigned short*)(ws + OFF_TW2H);
  unsigned short* w2pl = (unsigned short*)(ws + OFF_TW2L);
  float*  Bh   = (float*)(ws + OFF_B);
  float*  col0 = (float*)(ws + OFF_C0);
  unsigned short* P = (unsigned short*)(ws + OFF_P);
  float2* A    = (float2*)(ws + OFF_S);
  unsigned short* E = (unsigned short*)(ws + OFF_S);
  float*  sm = (float*)(ws + (full ? OFF_SM_F : OFF_SM_C));
  float* rgbsum = sm;            // 96
  float* stats  = sm + 96;       // 192
  float* freqa  = sm + 288;      // 4096
  float* rgbm   = sm + 4384;     // 96
  float* ssb    = sm + 4480;     // 192

  hipMemsetAsync(sm, 0, 4672*sizeof(float), stream);
  k_prep<<<288, 256, 0, stream>>>(w1, w2, T, w1p, w2ph, w2pl);
  for (int c = 0; c < dftloop; ++c){
    k_dft_rows<<<dftCH*48, 192, 0, stream>>>(x, T, A, rgbsum, c*dftCH);
    k_dft_cols<<<dftCH*25, 192, 0, stream>>>(A, T, Bh, col0, stats, c*dftCH);
  }
  k_finalize<<<1, 128, 0, stream>>>(stats, rgbsum, ssb, rgbm);
  for (int c = 0; c < cvloop; ++c){
    k_conv1mfma<<<cvB*144, 256, 0, stream>>>(Bh, col0, ssb, w1p, b1, g1, bb1, E, c*cvB);
    k_pool<<<cvB*288, 256, 0, stream>>>(E, P);
    k_conv2mfma<<<cvB*72, 512, 0, stream>>>(P, w2ph, w2pl, b2, g2, bb2, freqa, c*cvB);
  }
  k_mlp<<<NB, 256, 0, stream>>>(rgbm, freqa, w_rgb, b_rgb, fc1w, fc1b,
                                fc2w, fc2b, fc3w, fc3b, (float*)d_out);
}